// Round 6
// baseline (443.469 us; speedup 1.0000x reference)
//
#include <hip/hip_runtime.h>
#include <math.h>

#define NN 50000
#define EE 400000
#define ETOT 450000
#define INC 128
#define CC 64
#define HC 256
#define ELI_N 200000
#define MPAD 50176   // 784*64

typedef unsigned short u16;
typedef __attribute__((ext_vector_type(8))) short short8v;
typedef __attribute__((ext_vector_type(4))) float f32x4;
typedef __attribute__((ext_vector_type(4))) unsigned short u16x4;

__device__ __forceinline__ u16 f2b(float v){
    unsigned u = __float_as_uint(v);
    u = (u + 0x7fffu + ((u >> 16) & 1u)) >> 16;   // RNE
    return (u16)u;
}
__device__ __forceinline__ float b2f(u16 h){
    return __uint_as_float(((unsigned)h) << 16);
}

// ---------------- CSR build ----------------
__global__ void k_count(const int* __restrict__ ei, int* __restrict__ deg){
    int e = blockIdx.x*256 + threadIdx.x;
    if (e < EE) atomicAdd(&deg[ei[EE + e]], 1);
}

// chunk=1024 per block; deg+1 (self-loop) baked in
__global__ void k_scanA(const int* __restrict__ deg, int* __restrict__ iscan, int* __restrict__ part){
    __shared__ int sh[256];
    int tid = threadIdx.x;
    int base = blockIdx.x*1024 + tid*4;
    int v[4]; int t = 0;
    #pragma unroll
    for (int i = 0; i < 4; i++){ int idx = base + i; v[i] = (idx < NN) ? deg[idx]+1 : 0; t += v[i]; }
    sh[tid] = t; __syncthreads();
    for (int off = 1; off < 256; off <<= 1){
        int u = (tid >= off) ? sh[tid - off] : 0;
        __syncthreads();
        sh[tid] += u;
        __syncthreads();
    }
    int incl = sh[tid];
    int run = incl - t;
    #pragma unroll
    for (int i = 0; i < 4; i++){
        run += v[i];
        int idx = base + i;
        if (idx < NN) iscan[idx] = run;
    }
    if (tid == 255) part[blockIdx.x] = incl;
}

// inline part-prefix (uniform per block: each block lies inside one 1024-chunk)
__global__ void k_scanC(const int* __restrict__ iscan, const int* __restrict__ part,
                        const int* __restrict__ deg, int* __restrict__ rowptr, int* __restrict__ cursor){
    int chunk = blockIdx.x >> 2;
    int ps = 0;
    for (int j = 0; j < chunk; j++) ps += part[j];
    int i = blockIdx.x*256 + threadIdx.x;
    if (i < NN){
        int v = iscan[i] + ps;          // rowptr[i+1]
        rowptr[i+1] = v;
        cursor[i] = v - (deg[i]+1);     // rowptr[i]
    }
    if (i == 0) rowptr[0] = 0;
}

__global__ void k_fill(const int* __restrict__ ei, int* __restrict__ cursor, int* __restrict__ csr_src){
    int idx = blockIdx.x*256 + threadIdx.x;
    if (idx >= ETOT) return;
    int s, d;
    if (idx < EE){ s = ei[idx]; d = ei[EE + idx]; }
    else         { s = idx - EE; d = s; }
    int pos = atomicAdd(&cursor[d], 1);
    csr_src[pos] = s;
}

// ---------------- weights -> transposed bf16 hi/lo [N][K] ----------------
__global__ void k_convW(const float* __restrict__ Wl1, const float* __restrict__ Wr1,
                        const float* __restrict__ Wres, const float* __restrict__ Wl2,
                        const float* __restrict__ Wr2,
                        u16* __restrict__ hl1, u16* __restrict__ ll1,
                        u16* __restrict__ hr1, u16* __restrict__ lr1,
                        u16* __restrict__ hres, u16* __restrict__ lres,
                        u16* __restrict__ hl2, u16* __restrict__ ll2,
                        u16* __restrict__ hr2, u16* __restrict__ lr2){
    int gid = blockIdx.x*256 + threadIdx.x;
    const float* src; u16* dh; u16* dl; int K, N, idx;
    if      (gid <  32768){ src=Wl1;  dh=hl1;  dl=ll1;  K=128; N=256; idx=gid; }
    else if (gid <  65536){ src=Wr1;  dh=hr1;  dl=lr1;  K=128; N=256; idx=gid-32768; }
    else if (gid <  73728){ src=Wres; dh=hres; dl=lres; K=128; N=64;  idx=gid-65536; }
    else if (gid <  90112){ src=Wl2;  dh=hl2;  dl=ll2;  K=64;  N=256; idx=gid-73728; }
    else if (gid < 106496){ src=Wr2;  dh=hr2;  dl=lr2;  K=64;  N=256; idx=gid-90112; }
    else return;
    int k = idx / N, n = idx - k*N;
    float v = src[idx];
    u16 h = f2b(v);
    dh[n*K + k] = h;
    dl[n*K + k] = f2b(v - b2f(h));
}

// ---------------- layer-1 GEMM: one 64-row stripe per block, A staged in LDS once ----------
// 9 column tiles (0-3: xl, 4-7: xr, 8: xres); wave w handles t = w, w+4, w+8
__global__ __launch_bounds__(256) void k_gemm1(const float* __restrict__ A,
        const u16* __restrict__ Whl1, const u16* __restrict__ Wll1,
        const u16* __restrict__ Whr1, const u16* __restrict__ Wlr1,
        const u16* __restrict__ Whres,const u16* __restrict__ Wlres,
        const float* __restrict__ bl1, const float* __restrict__ br1, const float* __restrict__ bres,
        float* __restrict__ xl, float* __restrict__ xr, float* __restrict__ xres)
{
    __shared__ u16 Ah[64][136];
    __shared__ u16 Al[64][136];
    int tid = threadIdx.x;
    int wid = tid >> 6, lane = tid & 63;
    int rm0 = blockIdx.x * 64;

    // stage: 64 rows x 128 cols fp32 -> bf16 hi/lo in LDS (each thread 8 float4)
    #pragma unroll
    for (int i = 0; i < 8; i++){
        int idx = tid + i*256;           // float4 index, 0..2047
        int row = idx >> 5;              // 32 float4 per row
        int c4  = idx & 31;
        int grow = rm0 + row; if (grow >= NN) grow = NN-1;
        float4 v = *(const float4*)(A + (size_t)grow*128 + c4*4);
        float vv[4] = {v.x, v.y, v.z, v.w};
        u16x4 hv, lv;
        #pragma unroll
        for (int j = 0; j < 4; j++){
            u16 h = f2b(vv[j]);
            hv[j] = h;
            lv[j] = f2b(vv[j] - b2f(h));
        }
        *(u16x4*)&Ah[row][c4*4] = hv;
        *(u16x4*)&Al[row][c4*4] = lv;
    }
    __syncthreads();

    int lr = lane & 15;
    int lk8 = (lane >> 4) << 3;
    int rbase = (lane >> 4) << 2;

    for (int t = wid; t < 9; t += 4){
        const u16 *Bh, *Bl; const float* bias; float* Cout; int n0, N;
        if (t < 4)      { Bh=Whl1;  Bl=Wll1;  bias=bl1;  Cout=xl;   n0=t*64;     N=256; }
        else if (t < 8) { Bh=Whr1;  Bl=Wlr1;  bias=br1;  Cout=xr;   n0=(t-4)*64; N=256; }
        else            { Bh=Whres; Bl=Wlres; bias=bres; Cout=xres; n0=0;        N=64;  }
        size_t boff = (size_t)(n0 + lr)*128 + lk8;
        f32x4 acc[4][4] = {};
        #pragma unroll
        for (int ks = 0; ks < 4; ks++){
            short8v ah[4], al[4], bh[4], blo[4];
            #pragma unroll
            for (int mf = 0; mf < 4; mf++){
                ah[mf] = *(const short8v*)&Ah[mf*16 + lr][ks*32 + lk8];
                al[mf] = *(const short8v*)&Al[mf*16 + lr][ks*32 + lk8];
            }
            #pragma unroll
            for (int nf = 0; nf < 4; nf++){
                bh[nf]  = *(const short8v*)(Bh + boff + (size_t)(nf*16)*128 + ks*32);
                blo[nf] = *(const short8v*)(Bl + boff + (size_t)(nf*16)*128 + ks*32);
            }
            #pragma unroll
            for (int mf = 0; mf < 4; mf++)
                #pragma unroll
                for (int nf = 0; nf < 4; nf++){
                    acc[mf][nf] = __builtin_amdgcn_mfma_f32_16x16x32_bf16(ah[mf], bh[nf],  acc[mf][nf], 0, 0, 0);
                    acc[mf][nf] = __builtin_amdgcn_mfma_f32_16x16x32_bf16(al[mf], bh[nf],  acc[mf][nf], 0, 0, 0);
                    acc[mf][nf] = __builtin_amdgcn_mfma_f32_16x16x32_bf16(ah[mf], blo[nf], acc[mf][nf], 0, 0, 0);
                }
        }
        #pragma unroll
        for (int nf = 0; nf < 4; nf++){
            int col = n0 + nf*16 + lr;
            float bv = bias[col];
            #pragma unroll
            for (int mf = 0; mf < 4; mf++){
                #pragma unroll
                for (int r = 0; r < 4; r++){
                    int row = rm0 + mf*16 + rbase + r;
                    if (row < NN) Cout[(size_t)row*N + col] = acc[mf][nf][r] + bv;
                }
            }
        }
    }
}

// ---------------- layer-2 GEMM: K=64, 8 column tiles, A staged in LDS ----------------
__global__ __launch_bounds__(256) void k_gemm2(const float* __restrict__ A,
        const u16* __restrict__ Whl2, const u16* __restrict__ Wll2,
        const u16* __restrict__ Whr2, const u16* __restrict__ Wlr2,
        const float* __restrict__ bl2, const float* __restrict__ br2,
        float* __restrict__ xl, float* __restrict__ xr)
{
    __shared__ u16 Ah[64][72];
    __shared__ u16 Al[64][72];
    int tid = threadIdx.x;
    int wid = tid >> 6, lane = tid & 63;
    int rm0 = blockIdx.x * 64;

    // stage: 64 rows x 64 cols fp32 (each thread 4 float4)
    #pragma unroll
    for (int i = 0; i < 4; i++){
        int idx = tid + i*256;           // float4 index, 0..1023
        int row = idx >> 4;              // 16 float4 per row
        int c4  = idx & 15;
        int grow = rm0 + row; if (grow >= NN) grow = NN-1;
        float4 v = *(const float4*)(A + (size_t)grow*64 + c4*4);
        float vv[4] = {v.x, v.y, v.z, v.w};
        u16x4 hv, lv;
        #pragma unroll
        for (int j = 0; j < 4; j++){
            u16 h = f2b(vv[j]);
            hv[j] = h;
            lv[j] = f2b(vv[j] - b2f(h));
        }
        *(u16x4*)&Ah[row][c4*4] = hv;
        *(u16x4*)&Al[row][c4*4] = lv;
    }
    __syncthreads();

    int lr = lane & 15;
    int lk8 = (lane >> 4) << 3;
    int rbase = (lane >> 4) << 2;

    #pragma unroll
    for (int ti = 0; ti < 2; ti++){
        int t = wid + ti*4;
        const u16 *Bh, *Bl; const float* bias; float* Cout;
        if (t < 4){ Bh=Whl2; Bl=Wll2; bias=bl2; Cout=xl; }
        else      { Bh=Whr2; Bl=Wlr2; bias=br2; Cout=xr; }
        int n0 = (t & 3)*64;
        size_t boff = (size_t)(n0 + lr)*64 + lk8;
        f32x4 acc[4][4] = {};
        #pragma unroll
        for (int ks = 0; ks < 2; ks++){
            short8v ah[4], al[4], bh[4], blo[4];
            #pragma unroll
            for (int mf = 0; mf < 4; mf++){
                ah[mf] = *(const short8v*)&Ah[mf*16 + lr][ks*32 + lk8];
                al[mf] = *(const short8v*)&Al[mf*16 + lr][ks*32 + lk8];
            }
            #pragma unroll
            for (int nf = 0; nf < 4; nf++){
                bh[nf]  = *(const short8v*)(Bh + boff + (size_t)(nf*16)*64 + ks*32);
                blo[nf] = *(const short8v*)(Bl + boff + (size_t)(nf*16)*64 + ks*32);
            }
            #pragma unroll
            for (int mf = 0; mf < 4; mf++)
                #pragma unroll
                for (int nf = 0; nf < 4; nf++){
                    acc[mf][nf] = __builtin_amdgcn_mfma_f32_16x16x32_bf16(ah[mf], bh[nf],  acc[mf][nf], 0, 0, 0);
                    acc[mf][nf] = __builtin_amdgcn_mfma_f32_16x16x32_bf16(al[mf], bh[nf],  acc[mf][nf], 0, 0, 0);
                    acc[mf][nf] = __builtin_amdgcn_mfma_f32_16x16x32_bf16(ah[mf], blo[nf], acc[mf][nf], 0, 0, 0);
                }
        }
        #pragma unroll
        for (int nf = 0; nf < 4; nf++){
            int col = n0 + nf*16 + lr;
            float bv = bias[col];
            #pragma unroll
            for (int mf = 0; mf < 4; mf++){
                #pragma unroll
                for (int r = 0; r < 4; r++){
                    int row = rm0 + mf*16 + rbase + r;
                    if (row < NN) Cout[(size_t)row*256 + col] = acc[mf][nf][r] + bv;
                }
            }
        }
    }
}

// ---------------- fused GATv2 aggregation (no-max softmax, unroll-4) -------------
// wave per node; lane l covers channels 4l..4l+3 of 256-wide row; head = l>>4
__global__ __launch_bounds__(256) void k_gat(const float* __restrict__ xl, const float* __restrict__ xr,
                                             const int* __restrict__ csr_src, const int* __restrict__ rowptr,
                                             const float* __restrict__ att, const float* __restrict__ bias,
                                             float* __restrict__ out)
{
    int wave = threadIdx.x >> 6, lane = threadIdx.x & 63;
    int node = blockIdx.x*4 + wave;
    if (node >= NN) return;
    int p0 = rowptr[node], p1 = rowptr[node+1];
    f32x4 xrf  = *(const f32x4*)(xr + (size_t)node*HC + 4*lane);
    f32x4 attf = *(const f32x4*)(att + 4*lane);
    float s = 0.f;
    f32x4 acc = {0.f, 0.f, 0.f, 0.f};
    int p = p0;
    for (; p + 4 <= p1; p += 4){
        int i0 = csr_src[p], i1 = csr_src[p+1], i2 = csr_src[p+2], i3 = csr_src[p+3];
        f32x4 x0 = *(const f32x4*)(xl + (size_t)i0*HC + 4*lane);
        f32x4 x1 = *(const f32x4*)(xl + (size_t)i1*HC + 4*lane);
        f32x4 x2 = *(const f32x4*)(xl + (size_t)i2*HC + 4*lane);
        f32x4 x3 = *(const f32x4*)(xl + (size_t)i3*HC + 4*lane);
        float t0 = 0.f, t1 = 0.f, t2 = 0.f, t3 = 0.f;
        #pragma unroll
        for (int j = 0; j < 4; j++){
            float e0 = x0[j] + xrf[j]; e0 = (e0 > 0.f) ? e0 : 0.2f*e0; t0 += e0*attf[j];
            float e1 = x1[j] + xrf[j]; e1 = (e1 > 0.f) ? e1 : 0.2f*e1; t1 += e1*attf[j];
            float e2 = x2[j] + xrf[j]; e2 = (e2 > 0.f) ? e2 : 0.2f*e2; t2 += e2*attf[j];
            float e3 = x3[j] + xrf[j]; e3 = (e3 > 0.f) ? e3 : 0.2f*e3; t3 += e3*attf[j];
        }
        #pragma unroll
        for (int off = 1; off < 16; off <<= 1){
            t0 += __shfl_xor(t0, off, 64);
            t1 += __shfl_xor(t1, off, 64);
            t2 += __shfl_xor(t2, off, 64);
            t3 += __shfl_xor(t3, off, 64);
        }
        float w0 = __expf(t0), w1 = __expf(t1), w2 = __expf(t2), w3 = __expf(t3);
        s += (w0 + w1) + (w2 + w3);
        acc = acc + x0*w0 + x1*w1 + x2*w2 + x3*w3;
    }
    for (; p < p1; p++){
        int i0 = csr_src[p];
        f32x4 x0 = *(const f32x4*)(xl + (size_t)i0*HC + 4*lane);
        float t0 = 0.f;
        #pragma unroll
        for (int j = 0; j < 4; j++){ float e0 = x0[j] + xrf[j]; e0 = (e0 > 0.f) ? e0 : 0.2f*e0; t0 += e0*attf[j]; }
        #pragma unroll
        for (int off = 1; off < 16; off <<= 1) t0 += __shfl_xor(t0, off, 64);
        float w0 = __expf(t0);
        s += w0;
        acc = acc + x0*w0;
    }
    float inv = 1.f / s;          // s uniform within each 16-lane head group
    f32x4 o = acc * inv;
    #pragma unroll
    for (int j = 0; j < 4; j++){ o[j] += __shfl_xor(o[j], 16, 64); o[j] += __shfl_xor(o[j], 32, 64); }
    if (lane < 16){
        f32x4 bv = *(const f32x4*)(bias + 4*lane);
        f32x4 res = o*0.25f + bv;
        *(f32x4*)(out + (size_t)node*CC + 4*lane) = res;
    }
}

// ---------------- BatchNorm stats ----------------
__global__ __launch_bounds__(256) void k_bnstats(const float* __restrict__ x, float* __restrict__ sums){
    __shared__ float ls[256], lq[256];
    int tid = threadIdx.x; int c = tid & 63; int g = tid >> 6;
    float s = 0.f, q = 0.f;
    for (int r = blockIdx.x*4 + g; r < NN; r += gridDim.x*4){
        float v = x[(size_t)r*64 + c]; s += v; q += v*v;
    }
    ls[tid] = s; lq[tid] = q; __syncthreads();
    if (tid < 64){
        s = ls[tid] + ls[tid+64] + ls[tid+128] + ls[tid+192];
        q = lq[tid] + lq[tid+64] + lq[tid+128] + lq[tid+192];
        atomicAdd(&sums[c], s); atomicAdd(&sums[64 + c], q);
    }
}

// h = relu(bn(hraw) + xres)  (mean/rstd from raw sums, inline)
__global__ void k_post1(const float* __restrict__ hraw, const float* __restrict__ xres,
                        const float* __restrict__ sums, const float* __restrict__ g,
                        const float* __restrict__ b, float* __restrict__ out){
    int i = blockIdx.x*256 + threadIdx.x;   // float4 index
    if (i >= NN*16) return;
    float4 hv = ((const float4*)hraw)[i];
    float4 rv = ((const float4*)xres)[i];
    int c0 = (i & 15) * 4;
    float hp[4] = {hv.x, hv.y, hv.z, hv.w};
    float rp[4] = {rv.x, rv.y, rv.z, rv.w};
    float res[4];
    const float invN = 1.f / (float)NN;
    #pragma unroll
    for (int k = 0; k < 4; k++){
        int c = c0 + k;
        float mean = sums[c] * invN;
        float var  = sums[64 + c] * invN - mean*mean;
        float rstd = rsqrtf(var + 1e-5f);
        float v = g[c]*(hp[k] - mean)*rstd + b[c] + rp[k];
        res[k] = (v > 0.f) ? v : 0.f;
    }
    ((float4*)out)[i] = make_float4(res[0], res[1], res[2], res[3]);
}

// z = bn(h2raw) + h
__global__ void k_post2(const float* __restrict__ hraw, const float* __restrict__ hprev,
                        const float* __restrict__ sums, const float* __restrict__ g,
                        const float* __restrict__ b, float* __restrict__ out){
    int i = blockIdx.x*256 + threadIdx.x;
    if (i >= NN*16) return;
    float4 hv = ((const float4*)hraw)[i];
    float4 rv = ((const float4*)hprev)[i];
    int c0 = (i & 15) * 4;
    float hp[4] = {hv.x, hv.y, hv.z, hv.w};
    float rp[4] = {rv.x, rv.y, rv.z, rv.w};
    float res[4];
    const float invN = 1.f / (float)NN;
    #pragma unroll
    for (int k = 0; k < 4; k++){
        int c = c0 + k;
        float mean = sums[c] * invN;
        float var  = sums[64 + c] * invN - mean*mean;
        float rstd = rsqrtf(var + 1e-5f);
        res[k] = g[c]*(hp[k] - mean)*rstd + b[c] + rp[k];
    }
    ((float4*)out)[i] = make_float4(res[0], res[1], res[2], res[3]);
}

// ---------------- link-prediction scores ----------------
__global__ __launch_bounds__(256) void k_score(const float* __restrict__ z, const int* __restrict__ eli,
                                               float* __restrict__ out){
    int t = blockIdx.x*256 + threadIdx.x;
    int i = t >> 4; int j = t & 15;
    if (i >= ELI_N) return;
    int a = eli[i], b = eli[ELI_N + i];
    float4 va = ((const float4*)(z + (size_t)a*64))[j];
    float4 vb = ((const float4*)(z + (size_t)b*64))[j];
    float s = va.x*vb.x + va.y*vb.y + va.z*vb.z + va.w*vb.w;
    #pragma unroll
    for (int off = 8; off > 0; off >>= 1) s += __shfl_xor(s, off, 64);
    if (j == 0) out[i] = 1.f / (1.f + __expf(-s));
}

extern "C" void kernel_launch(void* const* d_in, const int* in_sizes, int n_in,
                              void* d_out, int out_size, void* d_ws, size_t ws_size,
                              hipStream_t stream) {
    const float* x    = (const float*)d_in[0];
    const int*   ei   = (const int*)  d_in[1];
    const int*   eli  = (const int*)  d_in[2];
    const float* Wl1  = (const float*)d_in[3];
    const float* bl1  = (const float*)d_in[4];
    const float* Wr1  = (const float*)d_in[5];
    const float* br1  = (const float*)d_in[6];
    const float* att1 = (const float*)d_in[7];
    const float* bias1= (const float*)d_in[8];
    const float* g1   = (const float*)d_in[9];
    const float* b1   = (const float*)d_in[10];
    const float* Wres = (const float*)d_in[11];
    const float* bres = (const float*)d_in[12];
    const float* Wl2  = (const float*)d_in[13];
    const float* bl2  = (const float*)d_in[14];
    const float* Wr2  = (const float*)d_in[15];
    const float* br2  = (const float*)d_in[16];
    const float* att2 = (const float*)d_in[17];
    const float* bias2= (const float*)d_in[18];
    const float* g2   = (const float*)d_in[19];
    const float* b2   = (const float*)d_in[20];
    float* out = (float*)d_out;

    char* w = (char*)d_ws;
    size_t o = 0;
    auto take = [&](size_t bytes)->char*{ char* p = w + o; o += (bytes + 255) & ~(size_t)255; return p; };
    float* xl   = (float*)take((size_t)NN*HC*4);
    float* xr   = (float*)take((size_t)NN*HC*4);
    float* xres = (float*)take((size_t)NN*CC*4);   // later reused as z
    float* hraw = (float*)take((size_t)NN*CC*4);
    float* hbuf = (float*)take((size_t)NN*CC*4);
    u16* whl1 = (u16*)take(256*128*2);  u16* wll1 = (u16*)take(256*128*2);
    u16* whr1 = (u16*)take(256*128*2);  u16* wlr1 = (u16*)take(256*128*2);
    u16* whres= (u16*)take(64*128*2);   u16* wlres= (u16*)take(64*128*2);
    u16* whl2 = (u16*)take(256*64*2);   u16* wll2 = (u16*)take(256*64*2);
    u16* whr2 = (u16*)take(256*64*2);   u16* wlr2 = (u16*)take(256*64*2);
    // stats (256 floats) + deg (NN ints), contiguous for a single memset
    char* zreg  = take(256*4 + (size_t)NN*4);
    float* stats= (float*)zreg;
    int* deg    = (int*)(zreg + 256*4);
    int* rowptr = (int*)take((size_t)(NN+1)*4);
    int* iscan  = (int*)take((size_t)NN*4);
    int* cursor = (int*)take((size_t)NN*4);
    int* csr_src= (int*)take((size_t)ETOT*4);
    int* part   = (int*)take(64*4);

    hipMemsetAsync(zreg, 0, 256*4 + (size_t)NN*4, stream);

    // CSR build
    k_count<<<(EE+255)/256, 256, 0, stream>>>(ei, deg);
    k_scanA<<<49, 256, 0, stream>>>(deg, iscan, part);
    k_scanC<<<196, 256, 0, stream>>>(iscan, part, deg, rowptr, cursor);
    k_fill<<<(ETOT+255)/256, 256, 0, stream>>>(ei, cursor, csr_src);

    // weights
    k_convW<<<(106496+255)/256, 256, 0, stream>>>(Wl1, Wr1, Wres, Wl2, Wr2,
                                                  whl1, wll1, whr1, wlr1, whres, wlres,
                                                  whl2, wll2, whr2, wlr2);

    // layer 1
    k_gemm1<<<784, 256, 0, stream>>>(x, whl1, wll1, whr1, wlr1, whres, wlres,
                                     bl1, br1, bres, xl, xr, xres);
    k_gat<<<(NN+3)/4, 256, 0, stream>>>(xl, xr, csr_src, rowptr, att1, bias1, hraw);
    k_bnstats<<<256, 256, 0, stream>>>(hraw, stats);
    k_post1<<<(NN*16+255)/256, 256, 0, stream>>>(hraw, xres, stats, g1, b1, hbuf);

    // layer 2
    k_gemm2<<<784, 256, 0, stream>>>(hbuf, whl2, wll2, whr2, wlr2, bl2, br2, xl, xr);
    k_gat<<<(NN+3)/4, 256, 0, stream>>>(xl, xr, csr_src, rowptr, att2, bias2, hraw);
    k_bnstats<<<256, 256, 0, stream>>>(hraw, stats + 128);
    k_post2<<<(NN*16+255)/256, 256, 0, stream>>>(hraw, hbuf, stats + 128, g2, b2, xres);

    // scores
    k_score<<<(ELI_N*16+255)/256, 256, 0, stream>>>(xres, eli, out);
}

// Round 7
// 419.095 us; speedup vs baseline: 1.0582x; 1.0582x over previous
//
#include <hip/hip_runtime.h>
#include <math.h>

#define NN 50000
#define EE 400000
#define ETOT 450000
#define INC 128
#define CC 64
#define HC 256
#define ELI_N 200000

typedef unsigned short u16;
typedef __attribute__((ext_vector_type(8))) short short8v;
typedef __attribute__((ext_vector_type(4))) float f32x4;
typedef __attribute__((ext_vector_type(4))) unsigned short u16x4;

__device__ __forceinline__ u16 f2b(float v){
    unsigned u = __float_as_uint(v);
    u = (u + 0x7fffu + ((u >> 16) & 1u)) >> 16;   // RNE
    return (u16)u;
}
__device__ __forceinline__ float b2f(u16 h){
    return __uint_as_float(((unsigned)h) << 16);
}

// ---------------- CSR build ----------------
__global__ void k_count(const int* __restrict__ ei, int* __restrict__ deg){
    int e = blockIdx.x*256 + threadIdx.x;
    if (e < EE) atomicAdd(&deg[ei[EE + e]], 1);
}

// chunk=1024 per block; deg+1 (self-loop) baked in
__global__ void k_scanA(const int* __restrict__ deg, int* __restrict__ iscan, int* __restrict__ part){
    __shared__ int sh[256];
    int tid = threadIdx.x;
    int base = blockIdx.x*1024 + tid*4;
    int v[4]; int t = 0;
    #pragma unroll
    for (int i = 0; i < 4; i++){ int idx = base + i; v[i] = (idx < NN) ? deg[idx]+1 : 0; t += v[i]; }
    sh[tid] = t; __syncthreads();
    for (int off = 1; off < 256; off <<= 1){
        int u = (tid >= off) ? sh[tid - off] : 0;
        __syncthreads();
        sh[tid] += u;
        __syncthreads();
    }
    int incl = sh[tid];
    int run = incl - t;
    #pragma unroll
    for (int i = 0; i < 4; i++){
        run += v[i];
        int idx = base + i;
        if (idx < NN) iscan[idx] = run;
    }
    if (tid == 255) part[blockIdx.x] = incl;
}

// inline part-prefix (uniform per block: each block lies inside one 1024-chunk)
__global__ void k_scanC(const int* __restrict__ iscan, const int* __restrict__ part,
                        const int* __restrict__ deg, int* __restrict__ rowptr, int* __restrict__ cursor){
    int chunk = blockIdx.x >> 2;
    int ps = 0;
    for (int j = 0; j < chunk; j++) ps += part[j];
    int i = blockIdx.x*256 + threadIdx.x;
    if (i < NN){
        int v = iscan[i] + ps;          // rowptr[i+1]
        rowptr[i+1] = v;
        cursor[i] = v - (deg[i]+1);     // rowptr[i]
    }
    if (i == 0) rowptr[0] = 0;
}

__global__ void k_fill(const int* __restrict__ ei, int* __restrict__ cursor, int* __restrict__ csr_src){
    int idx = blockIdx.x*256 + threadIdx.x;
    if (idx >= ETOT) return;
    int s, d;
    if (idx < EE){ s = ei[idx]; d = ei[EE + idx]; }
    else         { s = idx - EE; d = s; }
    int pos = atomicAdd(&cursor[d], 1);
    csr_src[pos] = s;
}

// ---------------- x -> bf16 hi/lo split ----------------
__global__ void k_splitX(const float* __restrict__ src, u16* __restrict__ hi, u16* __restrict__ lo){
    int i = blockIdx.x*256 + threadIdx.x;      // float4 index over NN*INC
    if (i >= NN*INC/4) return;
    float4 v = ((const float4*)src)[i];
    float vv[4] = {v.x, v.y, v.z, v.w};
    u16x4 h4, l4;
    #pragma unroll
    for (int j = 0; j < 4; j++){
        u16 h = f2b(vv[j]);
        h4[j] = h;
        l4[j] = f2b(vv[j] - b2f(h));
    }
    *(u16x4*)(hi + (size_t)i*4) = h4;
    *(u16x4*)(lo + (size_t)i*4) = l4;
}

// ---------------- weights -> transposed bf16 hi/lo [N][K] ----------------
__global__ void k_convW(const float* __restrict__ Wl1, const float* __restrict__ Wr1,
                        const float* __restrict__ Wres, const float* __restrict__ Wl2,
                        const float* __restrict__ Wr2,
                        u16* __restrict__ hl1, u16* __restrict__ ll1,
                        u16* __restrict__ hr1, u16* __restrict__ lr1,
                        u16* __restrict__ hres, u16* __restrict__ lres,
                        u16* __restrict__ hl2, u16* __restrict__ ll2,
                        u16* __restrict__ hr2, u16* __restrict__ lr2){
    int gid = blockIdx.x*256 + threadIdx.x;
    const float* src; u16* dh; u16* dl; int K, N, idx;
    if      (gid <  32768){ src=Wl1;  dh=hl1;  dl=ll1;  K=128; N=256; idx=gid; }
    else if (gid <  65536){ src=Wr1;  dh=hr1;  dl=lr1;  K=128; N=256; idx=gid-32768; }
    else if (gid <  73728){ src=Wres; dh=hres; dl=lres; K=128; N=64;  idx=gid-65536; }
    else if (gid <  90112){ src=Wl2;  dh=hl2;  dl=ll2;  K=64;  N=256; idx=gid-73728; }
    else if (gid < 106496){ src=Wr2;  dh=hr2;  dl=lr2;  K=64;  N=256; idx=gid-90112; }
    else return;
    int k = idx / N, n = idx - k*N;
    float v = src[idx];
    u16 h = f2b(v);
    dh[n*K + k] = h;
    dl[n*K + k] = f2b(v - b2f(h));
}

// ---------------- layer-1 GEMM from pre-split A: grid (196, 9) ----------------
// blockIdx.y = column tile (0-3: xl, 4-7: xr, 8: xres); 4 waves = 4 row-blocks
__global__ __launch_bounds__(256) void k_gemm1(const u16* __restrict__ Ahi, const u16* __restrict__ Alo,
        const u16* __restrict__ Whl1, const u16* __restrict__ Wll1,
        const u16* __restrict__ Whr1, const u16* __restrict__ Wlr1,
        const u16* __restrict__ Whres,const u16* __restrict__ Wlres,
        const float* __restrict__ bl1, const float* __restrict__ br1, const float* __restrict__ bres,
        float* __restrict__ xl, float* __restrict__ xr, float* __restrict__ xres)
{
    int wid = threadIdx.x >> 6, lane = threadIdx.x & 63;
    int tile = blockIdx.y;
    const u16 *Bh, *Bl; const float* bias; float* Cout; int n0, N;
    if (tile < 4)      { Bh=Whl1;  Bl=Wll1;  bias=bl1;  Cout=xl;   n0=tile*64;     N=256; }
    else if (tile < 8) { Bh=Whr1;  Bl=Wlr1;  bias=br1;  Cout=xr;   n0=(tile-4)*64; N=256; }
    else               { Bh=Whres; Bl=Wlres; bias=bres; Cout=xres; n0=0;           N=64;  }
    int rm0 = (blockIdx.x*4 + wid) * 64;
    int lr = lane & 15;
    int lk8 = (lane >> 4) << 3;
    f32x4 acc[4][4] = {};
    int arow[4];
    #pragma unroll
    for (int mf = 0; mf < 4; mf++){ int r = rm0 + mf*16 + lr; arow[mf] = (r < NN) ? r : NN-1; }
    size_t boff = (size_t)(n0 + lr)*128 + lk8;
    #pragma unroll
    for (int ks = 0; ks < 4; ks++){
        short8v ah[4], al[4], bh[4], blo[4];
        #pragma unroll
        for (int mf = 0; mf < 4; mf++){
            ah[mf] = *(const short8v*)(Ahi + (size_t)arow[mf]*128 + ks*32 + lk8);
            al[mf] = *(const short8v*)(Alo + (size_t)arow[mf]*128 + ks*32 + lk8);
        }
        #pragma unroll
        for (int nf = 0; nf < 4; nf++){
            bh[nf]  = *(const short8v*)(Bh + boff + (size_t)(nf*16)*128 + ks*32);
            blo[nf] = *(const short8v*)(Bl + boff + (size_t)(nf*16)*128 + ks*32);
        }
        #pragma unroll
        for (int mf = 0; mf < 4; mf++)
            #pragma unroll
            for (int nf = 0; nf < 4; nf++){
                acc[mf][nf] = __builtin_amdgcn_mfma_f32_16x16x32_bf16(ah[mf], bh[nf],  acc[mf][nf], 0, 0, 0);
                acc[mf][nf] = __builtin_amdgcn_mfma_f32_16x16x32_bf16(al[mf], bh[nf],  acc[mf][nf], 0, 0, 0);
                acc[mf][nf] = __builtin_amdgcn_mfma_f32_16x16x32_bf16(ah[mf], blo[nf], acc[mf][nf], 0, 0, 0);
            }
    }
    int rbase = (lane >> 4) << 2;
    #pragma unroll
    for (int nf = 0; nf < 4; nf++){
        int col = n0 + nf*16 + lr;
        float bv = bias[col];
        #pragma unroll
        for (int mf = 0; mf < 4; mf++){
            #pragma unroll
            for (int r = 0; r < 4; r++){
                int row = rm0 + mf*16 + rbase + r;
                if (row < NN) Cout[(size_t)row*N + col] = acc[mf][nf][r] + bv;
            }
        }
    }
}

// ---------------- layer-2 GEMM from pre-split h: grid (196, 8), K=64 ----------------
__global__ __launch_bounds__(256) void k_gemm2(const u16* __restrict__ Ahi, const u16* __restrict__ Alo,
        const u16* __restrict__ Whl2, const u16* __restrict__ Wll2,
        const u16* __restrict__ Whr2, const u16* __restrict__ Wlr2,
        const float* __restrict__ bl2, const float* __restrict__ br2,
        float* __restrict__ xl, float* __restrict__ xr)
{
    int wid = threadIdx.x >> 6, lane = threadIdx.x & 63;
    int tile = blockIdx.y;
    const u16 *Bh, *Bl; const float* bias; float* Cout;
    if (tile < 4){ Bh=Whl2; Bl=Wll2; bias=bl2; Cout=xl; }
    else         { Bh=Whr2; Bl=Wlr2; bias=br2; Cout=xr; }
    int n0 = (tile & 3)*64;
    int rm0 = (blockIdx.x*4 + wid) * 64;
    int lr = lane & 15;
    int lk8 = (lane >> 4) << 3;
    f32x4 acc[4][4] = {};
    int arow[4];
    #pragma unroll
    for (int mf = 0; mf < 4; mf++){ int r = rm0 + mf*16 + lr; arow[mf] = (r < NN) ? r : NN-1; }
    size_t boff = (size_t)(n0 + lr)*64 + lk8;
    #pragma unroll
    for (int ks = 0; ks < 2; ks++){
        short8v ah[4], al[4], bh[4], blo[4];
        #pragma unroll
        for (int mf = 0; mf < 4; mf++){
            ah[mf] = *(const short8v*)(Ahi + (size_t)arow[mf]*64 + ks*32 + lk8);
            al[mf] = *(const short8v*)(Alo + (size_t)arow[mf]*64 + ks*32 + lk8);
        }
        #pragma unroll
        for (int nf = 0; nf < 4; nf++){
            bh[nf]  = *(const short8v*)(Bh + boff + (size_t)(nf*16)*64 + ks*32);
            blo[nf] = *(const short8v*)(Bl + boff + (size_t)(nf*16)*64 + ks*32);
        }
        #pragma unroll
        for (int mf = 0; mf < 4; mf++)
            #pragma unroll
            for (int nf = 0; nf < 4; nf++){
                acc[mf][nf] = __builtin_amdgcn_mfma_f32_16x16x32_bf16(ah[mf], bh[nf],  acc[mf][nf], 0, 0, 0);
                acc[mf][nf] = __builtin_amdgcn_mfma_f32_16x16x32_bf16(al[mf], bh[nf],  acc[mf][nf], 0, 0, 0);
                acc[mf][nf] = __builtin_amdgcn_mfma_f32_16x16x32_bf16(ah[mf], blo[nf], acc[mf][nf], 0, 0, 0);
            }
    }
    int rbase = (lane >> 4) << 2;
    #pragma unroll
    for (int nf = 0; nf < 4; nf++){
        int col = n0 + nf*16 + lr;
        float bv = bias[col];
        #pragma unroll
        for (int mf = 0; mf < 4; mf++){
            #pragma unroll
            for (int r = 0; r < 4; r++){
                int row = rm0 + mf*16 + rbase + r;
                if (row < NN) Cout[(size_t)row*256 + col] = acc[mf][nf][r] + bv;
            }
        }
    }
}

// ---------------- fused GATv2 aggregation (no-max softmax, unroll-4) -------------
// wave per node; lane l covers channels 4l..4l+3 of 256-wide row; head = l>>4
__global__ __launch_bounds__(256) void k_gat(const float* __restrict__ xl, const float* __restrict__ xr,
                                             const int* __restrict__ csr_src, const int* __restrict__ rowptr,
                                             const float* __restrict__ att, const float* __restrict__ bias,
                                             float* __restrict__ out)
{
    int wave = threadIdx.x >> 6, lane = threadIdx.x & 63;
    int node = blockIdx.x*4 + wave;
    if (node >= NN) return;
    int p0 = rowptr[node], p1 = rowptr[node+1];
    f32x4 xrf  = *(const f32x4*)(xr + (size_t)node*HC + 4*lane);
    f32x4 attf = *(const f32x4*)(att + 4*lane);
    float s = 0.f;
    f32x4 acc = {0.f, 0.f, 0.f, 0.f};
    int p = p0;
    for (; p + 4 <= p1; p += 4){
        int i0 = csr_src[p], i1 = csr_src[p+1], i2 = csr_src[p+2], i3 = csr_src[p+3];
        f32x4 x0 = *(const f32x4*)(xl + (size_t)i0*HC + 4*lane);
        f32x4 x1 = *(const f32x4*)(xl + (size_t)i1*HC + 4*lane);
        f32x4 x2 = *(const f32x4*)(xl + (size_t)i2*HC + 4*lane);
        f32x4 x3 = *(const f32x4*)(xl + (size_t)i3*HC + 4*lane);
        float t0 = 0.f, t1 = 0.f, t2 = 0.f, t3 = 0.f;
        #pragma unroll
        for (int j = 0; j < 4; j++){
            float e0 = x0[j] + xrf[j]; e0 = (e0 > 0.f) ? e0 : 0.2f*e0; t0 += e0*attf[j];
            float e1 = x1[j] + xrf[j]; e1 = (e1 > 0.f) ? e1 : 0.2f*e1; t1 += e1*attf[j];
            float e2 = x2[j] + xrf[j]; e2 = (e2 > 0.f) ? e2 : 0.2f*e2; t2 += e2*attf[j];
            float e3 = x3[j] + xrf[j]; e3 = (e3 > 0.f) ? e3 : 0.2f*e3; t3 += e3*attf[j];
        }
        #pragma unroll
        for (int off = 1; off < 16; off <<= 1){
            t0 += __shfl_xor(t0, off, 64);
            t1 += __shfl_xor(t1, off, 64);
            t2 += __shfl_xor(t2, off, 64);
            t3 += __shfl_xor(t3, off, 64);
        }
        float w0 = __expf(t0), w1 = __expf(t1), w2 = __expf(t2), w3 = __expf(t3);
        s += (w0 + w1) + (w2 + w3);
        acc = acc + x0*w0 + x1*w1 + x2*w2 + x3*w3;
    }
    for (; p < p1; p++){
        int i0 = csr_src[p];
        f32x4 x0 = *(const f32x4*)(xl + (size_t)i0*HC + 4*lane);
        float t0 = 0.f;
        #pragma unroll
        for (int j = 0; j < 4; j++){ float e0 = x0[j] + xrf[j]; e0 = (e0 > 0.f) ? e0 : 0.2f*e0; t0 += e0*attf[j]; }
        #pragma unroll
        for (int off = 1; off < 16; off <<= 1) t0 += __shfl_xor(t0, off, 64);
        float w0 = __expf(t0);
        s += w0;
        acc = acc + x0*w0;
    }
    float inv = 1.f / s;          // s uniform within each 16-lane head group
    f32x4 o = acc * inv;
    #pragma unroll
    for (int j = 0; j < 4; j++){ o[j] += __shfl_xor(o[j], 16, 64); o[j] += __shfl_xor(o[j], 32, 64); }
    if (lane < 16){
        f32x4 bv = *(const f32x4*)(bias + 4*lane);
        f32x4 res = o*0.25f + bv;
        *(f32x4*)(out + (size_t)node*CC + 4*lane) = res;
    }
}

// ---------------- BatchNorm stats ----------------
__global__ __launch_bounds__(256) void k_bnstats(const float* __restrict__ x, float* __restrict__ sums){
    __shared__ float ls[256], lq[256];
    int tid = threadIdx.x; int c = tid & 63; int g = tid >> 6;
    float s = 0.f, q = 0.f;
    for (int r = blockIdx.x*4 + g; r < NN; r += gridDim.x*4){
        float v = x[(size_t)r*64 + c]; s += v; q += v*v;
    }
    ls[tid] = s; lq[tid] = q; __syncthreads();
    if (tid < 64){
        s = ls[tid] + ls[tid+64] + ls[tid+128] + ls[tid+192];
        q = lq[tid] + lq[tid+64] + lq[tid+128] + lq[tid+192];
        atomicAdd(&sums[c], s); atomicAdd(&sums[64 + c], q);
    }
}

// h = relu(bn(hraw) + xres); writes fp32 h plus hi/lo bf16 split for layer-2 GEMMs
__global__ void k_post1(const float* __restrict__ hraw, const float* __restrict__ xres,
                        const float* __restrict__ sums, const float* __restrict__ g,
                        const float* __restrict__ b, float* __restrict__ out,
                        u16* __restrict__ hhi, u16* __restrict__ hlo){
    int i = blockIdx.x*256 + threadIdx.x;   // float4 index
    if (i >= NN*16) return;
    float4 hv = ((const float4*)hraw)[i];
    float4 rv = ((const float4*)xres)[i];
    int c0 = (i & 15) * 4;
    float hp[4] = {hv.x, hv.y, hv.z, hv.w};
    float rp[4] = {rv.x, rv.y, rv.z, rv.w};
    float res[4];
    u16x4 h4, l4;
    const float invN = 1.f / (float)NN;
    #pragma unroll
    for (int k = 0; k < 4; k++){
        int c = c0 + k;
        float mean = sums[c] * invN;
        float var  = sums[64 + c] * invN - mean*mean;
        float rstd = rsqrtf(var + 1e-5f);
        float v = g[c]*(hp[k] - mean)*rstd + b[c] + rp[k];
        v = (v > 0.f) ? v : 0.f;
        res[k] = v;
        u16 h = f2b(v);
        h4[k] = h;
        l4[k] = f2b(v - b2f(h));
    }
    ((float4*)out)[i] = make_float4(res[0], res[1], res[2], res[3]);
    *(u16x4*)(hhi + (size_t)i*4) = h4;
    *(u16x4*)(hlo + (size_t)i*4) = l4;
}

// z = bn(h2raw) + h
__global__ void k_post2(const float* __restrict__ hraw, const float* __restrict__ hprev,
                        const float* __restrict__ sums, const float* __restrict__ g,
                        const float* __restrict__ b, float* __restrict__ out){
    int i = blockIdx.x*256 + threadIdx.x;
    if (i >= NN*16) return;
    float4 hv = ((const float4*)hraw)[i];
    float4 rv = ((const float4*)hprev)[i];
    int c0 = (i & 15) * 4;
    float hp[4] = {hv.x, hv.y, hv.z, hv.w};
    float rp[4] = {rv.x, rv.y, rv.z, rv.w};
    float res[4];
    const float invN = 1.f / (float)NN;
    #pragma unroll
    for (int k = 0; k < 4; k++){
        int c = c0 + k;
        float mean = sums[c] * invN;
        float var  = sums[64 + c] * invN - mean*mean;
        float rstd = rsqrtf(var + 1e-5f);
        res[k] = g[c]*(hp[k] - mean)*rstd + b[c] + rp[k];
    }
    ((float4*)out)[i] = make_float4(res[0], res[1], res[2], res[3]);
}

// ---------------- link-prediction scores ----------------
__global__ __launch_bounds__(256) void k_score(const float* __restrict__ z, const int* __restrict__ eli,
                                               float* __restrict__ out){
    int t = blockIdx.x*256 + threadIdx.x;
    int i = t >> 4; int j = t & 15;
    if (i >= ELI_N) return;
    int a = eli[i], b = eli[ELI_N + i];
    float4 va = ((const float4*)(z + (size_t)a*64))[j];
    float4 vb = ((const float4*)(z + (size_t)b*64))[j];
    float s = va.x*vb.x + va.y*vb.y + va.z*vb.z + va.w*vb.w;
    #pragma unroll
    for (int off = 8; off > 0; off >>= 1) s += __shfl_xor(s, off, 64);
    if (j == 0) out[i] = 1.f / (1.f + __expf(-s));
}

extern "C" void kernel_launch(void* const* d_in, const int* in_sizes, int n_in,
                              void* d_out, int out_size, void* d_ws, size_t ws_size,
                              hipStream_t stream) {
    const float* x    = (const float*)d_in[0];
    const int*   ei   = (const int*)  d_in[1];
    const int*   eli  = (const int*)  d_in[2];
    const float* Wl1  = (const float*)d_in[3];
    const float* bl1  = (const float*)d_in[4];
    const float* Wr1  = (const float*)d_in[5];
    const float* br1  = (const float*)d_in[6];
    const float* att1 = (const float*)d_in[7];
    const float* bias1= (const float*)d_in[8];
    const float* g1   = (const float*)d_in[9];
    const float* b1   = (const float*)d_in[10];
    const float* Wres = (const float*)d_in[11];
    const float* bres = (const float*)d_in[12];
    const float* Wl2  = (const float*)d_in[13];
    const float* bl2  = (const float*)d_in[14];
    const float* Wr2  = (const float*)d_in[15];
    const float* br2  = (const float*)d_in[16];
    const float* att2 = (const float*)d_in[17];
    const float* bias2= (const float*)d_in[18];
    const float* g2   = (const float*)d_in[19];
    const float* b2   = (const float*)d_in[20];
    float* out = (float*)d_out;

    char* w = (char*)d_ws;
    size_t o = 0;
    auto take = [&](size_t bytes)->char*{ char* p = w + o; o += (bytes + 255) & ~(size_t)255; return p; };
    float* xl   = (float*)take((size_t)NN*HC*4);
    float* xr   = (float*)take((size_t)NN*HC*4);
    float* xres = (float*)take((size_t)NN*CC*4);   // later reused as z
    float* hraw = (float*)take((size_t)NN*CC*4);
    float* hbuf = (float*)take((size_t)NN*CC*4);
    u16*  xhi  = (u16*)take((size_t)NN*INC*2);
    u16*  xlo  = (u16*)take((size_t)NN*INC*2);
    u16*  hhi  = (u16*)take((size_t)NN*CC*2);
    u16*  hlo  = (u16*)take((size_t)NN*CC*2);
    u16* whl1 = (u16*)take(256*128*2);  u16* wll1 = (u16*)take(256*128*2);
    u16* whr1 = (u16*)take(256*128*2);  u16* wlr1 = (u16*)take(256*128*2);
    u16* whres= (u16*)take(64*128*2);   u16* wlres= (u16*)take(64*128*2);
    u16* whl2 = (u16*)take(256*64*2);   u16* wll2 = (u16*)take(256*64*2);
    u16* whr2 = (u16*)take(256*64*2);   u16* wlr2 = (u16*)take(256*64*2);
    // stats (256 floats) + deg (NN ints), contiguous for a single memset
    char* zreg  = take(256*4 + (size_t)NN*4);
    float* stats= (float*)zreg;
    int* deg    = (int*)(zreg + 256*4);
    int* rowptr = (int*)take((size_t)(NN+1)*4);
    int* iscan  = (int*)take((size_t)NN*4);
    int* cursor = (int*)take((size_t)NN*4);
    int* csr_src= (int*)take((size_t)ETOT*4);
    int* part   = (int*)take(64*4);

    hipMemsetAsync(zreg, 0, 256*4 + (size_t)NN*4, stream);

    // CSR build
    k_count<<<(EE+255)/256, 256, 0, stream>>>(ei, deg);
    k_scanA<<<49, 256, 0, stream>>>(deg, iscan, part);
    k_scanC<<<196, 256, 0, stream>>>(iscan, part, deg, rowptr, cursor);
    k_fill<<<(ETOT+255)/256, 256, 0, stream>>>(ei, cursor, csr_src);

    // conversions
    k_splitX<<<(NN*INC/4+255)/256, 256, 0, stream>>>(x, xhi, xlo);
    k_convW<<<(106496+255)/256, 256, 0, stream>>>(Wl1, Wr1, Wres, Wl2, Wr2,
                                                  whl1, wll1, whr1, wlr1, whres, wlres,
                                                  whl2, wll2, whr2, wlr2);

    // layer 1
    dim3 g1grid(196, 9);
    k_gemm1<<<g1grid, 256, 0, stream>>>(xhi, xlo, whl1, wll1, whr1, wlr1, whres, wlres,
                                        bl1, br1, bres, xl, xr, xres);
    k_gat<<<(NN+3)/4, 256, 0, stream>>>(xl, xr, csr_src, rowptr, att1, bias1, hraw);
    k_bnstats<<<256, 256, 0, stream>>>(hraw, stats);
    k_post1<<<(NN*16+255)/256, 256, 0, stream>>>(hraw, xres, stats, g1, b1, hbuf, hhi, hlo);

    // layer 2
    dim3 g2grid(196, 8);
    k_gemm2<<<g2grid, 256, 0, stream>>>(hhi, hlo, whl2, wll2, whr2, wlr2, bl2, br2, xl, xr);
    k_gat<<<(NN+3)/4, 256, 0, stream>>>(xl, xr, csr_src, rowptr, att2, bias2, hraw);
    k_bnstats<<<256, 256, 0, stream>>>(hraw, stats + 128);
    k_post2<<<(NN*16+255)/256, 256, 0, stream>>>(hraw, hbuf, stats + 128, g2, b2, xres);

    // scores
    k_score<<<(ELI_N*16+255)/256, 256, 0, stream>>>(xres, eli, out);
}

// Round 8
// 411.621 us; speedup vs baseline: 1.0774x; 1.0182x over previous
//
#include <hip/hip_runtime.h>
#include <math.h>

#define NN 50000
#define EE 400000
#define ETOT 450000
#define INC 128
#define CC 64
#define HC 256
#define ELI_N 200000

typedef unsigned short u16;
typedef __attribute__((ext_vector_type(8))) short short8v;
typedef __attribute__((ext_vector_type(4))) float f32x4;
typedef __attribute__((ext_vector_type(4))) unsigned short u16x4;

__device__ __forceinline__ u16 f2b(float v){
    unsigned u = __float_as_uint(v);
    u = (u + 0x7fffu + ((u >> 16) & 1u)) >> 16;   // RNE
    return (u16)u;
}
__device__ __forceinline__ float b2f(u16 h){
    return __uint_as_float(((unsigned)h) << 16);
}

// ---------------- CSR build ----------------
__global__ void k_count(const int* __restrict__ ei, int* __restrict__ deg){
    int e = blockIdx.x*256 + threadIdx.x;
    if (e < EE) atomicAdd(&deg[ei[EE + e]], 1);
}

// chunk=1024 per block; deg+1 (self-loop) baked in
__global__ void k_scanA(const int* __restrict__ deg, int* __restrict__ iscan, int* __restrict__ part){
    __shared__ int sh[256];
    int tid = threadIdx.x;
    int base = blockIdx.x*1024 + tid*4;
    int v[4]; int t = 0;
    #pragma unroll
    for (int i = 0; i < 4; i++){ int idx = base + i; v[i] = (idx < NN) ? deg[idx]+1 : 0; t += v[i]; }
    sh[tid] = t; __syncthreads();
    for (int off = 1; off < 256; off <<= 1){
        int u = (tid >= off) ? sh[tid - off] : 0;
        __syncthreads();
        sh[tid] += u;
        __syncthreads();
    }
    int incl = sh[tid];
    int run = incl - t;
    #pragma unroll
    for (int i = 0; i < 4; i++){
        run += v[i];
        int idx = base + i;
        if (idx < NN) iscan[idx] = run;
    }
    if (tid == 255) part[blockIdx.x] = incl;
}

// inline part-prefix (uniform per block: each block lies inside one 1024-chunk)
__global__ void k_scanC(const int* __restrict__ iscan, const int* __restrict__ part,
                        const int* __restrict__ deg, int* __restrict__ rowptr, int* __restrict__ cursor){
    int chunk = blockIdx.x >> 2;
    int ps = 0;
    for (int j = 0; j < chunk; j++) ps += part[j];
    int i = blockIdx.x*256 + threadIdx.x;
    if (i < NN){
        int v = iscan[i] + ps;          // rowptr[i+1]
        rowptr[i+1] = v;
        cursor[i] = v - (deg[i]+1);     // rowptr[i]
    }
    if (i == 0) rowptr[0] = 0;
}

__global__ void k_fill(const int* __restrict__ ei, int* __restrict__ cursor, int* __restrict__ csr_src){
    int idx = blockIdx.x*256 + threadIdx.x;
    if (idx >= ETOT) return;
    int s, d;
    if (idx < EE){ s = ei[idx]; d = ei[EE + idx]; }
    else         { s = idx - EE; d = s; }
    int pos = atomicAdd(&cursor[d], 1);
    csr_src[pos] = s;
}

// ---------------- x -> bf16 hi/lo split ----------------
__global__ void k_splitX(const float* __restrict__ src, u16* __restrict__ hi, u16* __restrict__ lo){
    int i = blockIdx.x*256 + threadIdx.x;      // float4 index over NN*INC
    if (i >= NN*INC/4) return;
    float4 v = ((const float4*)src)[i];
    float vv[4] = {v.x, v.y, v.z, v.w};
    u16x4 h4, l4;
    #pragma unroll
    for (int j = 0; j < 4; j++){
        u16 h = f2b(vv[j]);
        h4[j] = h;
        l4[j] = f2b(vv[j] - b2f(h));
    }
    *(u16x4*)(hi + (size_t)i*4) = h4;
    *(u16x4*)(lo + (size_t)i*4) = l4;
}

// ---------------- weights -> transposed bf16 hi/lo [N][K] ----------------
__global__ void k_convW(const float* __restrict__ Wl1, const float* __restrict__ Wr1,
                        const float* __restrict__ Wres, const float* __restrict__ Wl2,
                        const float* __restrict__ Wr2,
                        u16* __restrict__ hl1, u16* __restrict__ ll1,
                        u16* __restrict__ hr1, u16* __restrict__ lr1,
                        u16* __restrict__ hres, u16* __restrict__ lres,
                        u16* __restrict__ hl2, u16* __restrict__ ll2,
                        u16* __restrict__ hr2, u16* __restrict__ lr2){
    int gid = blockIdx.x*256 + threadIdx.x;
    const float* src; u16* dh; u16* dl; int K, N, idx;
    if      (gid <  32768){ src=Wl1;  dh=hl1;  dl=ll1;  K=128; N=256; idx=gid; }
    else if (gid <  65536){ src=Wr1;  dh=hr1;  dl=lr1;  K=128; N=256; idx=gid-32768; }
    else if (gid <  73728){ src=Wres; dh=hres; dl=lres; K=128; N=64;  idx=gid-65536; }
    else if (gid <  90112){ src=Wl2;  dh=hl2;  dl=ll2;  K=64;  N=256; idx=gid-73728; }
    else if (gid < 106496){ src=Wr2;  dh=hr2;  dl=lr2;  K=64;  N=256; idx=gid-90112; }
    else return;
    int k = idx / N, n = idx - k*N;
    float v = src[idx];
    u16 h = f2b(v);
    dh[n*K + k] = h;
    dl[n*K + k] = f2b(v - b2f(h));
}

// ---------------- layer-1 GEMM, XCD-swizzled 1D grid ----------------
// block b: xcd = b%8, k = b/8, tile = k%9, stripe x = (b%8) + 8*(k/9)
// all 9 column tiles of one stripe -> same XCD, adjacent rank => A stripe L2-hits
__global__ __launch_bounds__(256) void k_gemm1(const u16* __restrict__ Ahi, const u16* __restrict__ Alo,
        const u16* __restrict__ Whl1, const u16* __restrict__ Wll1,
        const u16* __restrict__ Whr1, const u16* __restrict__ Wlr1,
        const u16* __restrict__ Whres,const u16* __restrict__ Wlres,
        const float* __restrict__ bl1, const float* __restrict__ br1, const float* __restrict__ bres,
        float* __restrict__ xl, float* __restrict__ xr, float* __restrict__ xres)
{
    int b = blockIdx.x;
    int c = b & 7;
    int k = b >> 3;
    int tile = k % 9;
    int sx = c + 8*(k/9);
    if (sx >= 196) return;
    int wid = threadIdx.x >> 6, lane = threadIdx.x & 63;
    const u16 *Bh, *Bl; const float* bias; float* Cout; int n0, N;
    if (tile < 4)      { Bh=Whl1;  Bl=Wll1;  bias=bl1;  Cout=xl;   n0=tile*64;     N=256; }
    else if (tile < 8) { Bh=Whr1;  Bl=Wlr1;  bias=br1;  Cout=xr;   n0=(tile-4)*64; N=256; }
    else               { Bh=Whres; Bl=Wlres; bias=bres; Cout=xres; n0=0;           N=64;  }
    int rm0 = (sx*4 + wid) * 64;
    int lr = lane & 15;
    int lk8 = (lane >> 4) << 3;
    f32x4 acc[4][4] = {};
    int arow[4];
    #pragma unroll
    for (int mf = 0; mf < 4; mf++){ int r = rm0 + mf*16 + lr; arow[mf] = (r < NN) ? r : NN-1; }
    size_t boff = (size_t)(n0 + lr)*128 + lk8;
    #pragma unroll
    for (int ks = 0; ks < 4; ks++){
        short8v ah[4], al[4], bh[4], blo[4];
        #pragma unroll
        for (int mf = 0; mf < 4; mf++){
            ah[mf] = *(const short8v*)(Ahi + (size_t)arow[mf]*128 + ks*32 + lk8);
            al[mf] = *(const short8v*)(Alo + (size_t)arow[mf]*128 + ks*32 + lk8);
        }
        #pragma unroll
        for (int nf = 0; nf < 4; nf++){
            bh[nf]  = *(const short8v*)(Bh + boff + (size_t)(nf*16)*128 + ks*32);
            blo[nf] = *(const short8v*)(Bl + boff + (size_t)(nf*16)*128 + ks*32);
        }
        #pragma unroll
        for (int mf = 0; mf < 4; mf++)
            #pragma unroll
            for (int nf = 0; nf < 4; nf++){
                acc[mf][nf] = __builtin_amdgcn_mfma_f32_16x16x32_bf16(ah[mf], bh[nf],  acc[mf][nf], 0, 0, 0);
                acc[mf][nf] = __builtin_amdgcn_mfma_f32_16x16x32_bf16(al[mf], bh[nf],  acc[mf][nf], 0, 0, 0);
                acc[mf][nf] = __builtin_amdgcn_mfma_f32_16x16x32_bf16(ah[mf], blo[nf], acc[mf][nf], 0, 0, 0);
            }
    }
    int rbase = (lane >> 4) << 2;
    #pragma unroll
    for (int nf = 0; nf < 4; nf++){
        int col = n0 + nf*16 + lr;
        float bv = bias[col];
        #pragma unroll
        for (int mf = 0; mf < 4; mf++){
            #pragma unroll
            for (int r = 0; r < 4; r++){
                int row = rm0 + mf*16 + rbase + r;
                if (row < NN) Cout[(size_t)row*N + col] = acc[mf][nf][r] + bv;
            }
        }
    }
}

// ---------------- layer-2 GEMM, XCD-swizzled 1D grid, K=64 ----------------
// block b: xcd = b%8, k = b/8, tile = k%8, stripe x = (b%8) + 8*(k/8)
__global__ __launch_bounds__(256) void k_gemm2(const u16* __restrict__ Ahi, const u16* __restrict__ Alo,
        const u16* __restrict__ Whl2, const u16* __restrict__ Wll2,
        const u16* __restrict__ Whr2, const u16* __restrict__ Wlr2,
        const float* __restrict__ bl2, const float* __restrict__ br2,
        float* __restrict__ xl, float* __restrict__ xr)
{
    int b = blockIdx.x;
    int c = b & 7;
    int k = b >> 3;
    int tile = k & 7;
    int sx = c + 8*(k >> 3);
    if (sx >= 196) return;
    int wid = threadIdx.x >> 6, lane = threadIdx.x & 63;
    const u16 *Bh, *Bl; const float* bias; float* Cout;
    if (tile < 4){ Bh=Whl2; Bl=Wll2; bias=bl2; Cout=xl; }
    else         { Bh=Whr2; Bl=Wlr2; bias=br2; Cout=xr; }
    int n0 = (tile & 3)*64;
    int rm0 = (sx*4 + wid) * 64;
    int lr = lane & 15;
    int lk8 = (lane >> 4) << 3;
    f32x4 acc[4][4] = {};
    int arow[4];
    #pragma unroll
    for (int mf = 0; mf < 4; mf++){ int r = rm0 + mf*16 + lr; arow[mf] = (r < NN) ? r : NN-1; }
    size_t boff = (size_t)(n0 + lr)*64 + lk8;
    #pragma unroll
    for (int ks = 0; ks < 2; ks++){
        short8v ah[4], al[4], bh[4], blo[4];
        #pragma unroll
        for (int mf = 0; mf < 4; mf++){
            ah[mf] = *(const short8v*)(Ahi + (size_t)arow[mf]*64 + ks*32 + lk8);
            al[mf] = *(const short8v*)(Alo + (size_t)arow[mf]*64 + ks*32 + lk8);
        }
        #pragma unroll
        for (int nf = 0; nf < 4; nf++){
            bh[nf]  = *(const short8v*)(Bh + boff + (size_t)(nf*16)*64 + ks*32);
            blo[nf] = *(const short8v*)(Bl + boff + (size_t)(nf*16)*64 + ks*32);
        }
        #pragma unroll
        for (int mf = 0; mf < 4; mf++)
            #pragma unroll
            for (int nf = 0; nf < 4; nf++){
                acc[mf][nf] = __builtin_amdgcn_mfma_f32_16x16x32_bf16(ah[mf], bh[nf],  acc[mf][nf], 0, 0, 0);
                acc[mf][nf] = __builtin_amdgcn_mfma_f32_16x16x32_bf16(al[mf], bh[nf],  acc[mf][nf], 0, 0, 0);
                acc[mf][nf] = __builtin_amdgcn_mfma_f32_16x16x32_bf16(ah[mf], blo[nf], acc[mf][nf], 0, 0, 0);
            }
    }
    int rbase = (lane >> 4) << 2;
    #pragma unroll
    for (int nf = 0; nf < 4; nf++){
        int col = n0 + nf*16 + lr;
        float bv = bias[col];
        #pragma unroll
        for (int mf = 0; mf < 4; mf++){
            #pragma unroll
            for (int r = 0; r < 4; r++){
                int row = rm0 + mf*16 + rbase + r;
                if (row < NN) Cout[(size_t)row*256 + col] = acc[mf][nf][r] + bv;
            }
        }
    }
}

// ---------------- fused GATv2 aggregation (no-max softmax, unroll-4) -------------
// wave per node; lane l covers channels 4l..4l+3 of 256-wide row; head = l>>4
__global__ __launch_bounds__(256) void k_gat(const float* __restrict__ xl, const float* __restrict__ xr,
                                             const int* __restrict__ csr_src, const int* __restrict__ rowptr,
                                             const float* __restrict__ att, const float* __restrict__ bias,
                                             float* __restrict__ out)
{
    int wave = threadIdx.x >> 6, lane = threadIdx.x & 63;
    int node = blockIdx.x*4 + wave;
    if (node >= NN) return;
    int p0 = rowptr[node], p1 = rowptr[node+1];
    f32x4 xrf  = *(const f32x4*)(xr + (size_t)node*HC + 4*lane);
    f32x4 attf = *(const f32x4*)(att + 4*lane);
    float s = 0.f;
    f32x4 acc = {0.f, 0.f, 0.f, 0.f};
    int p = p0;
    for (; p + 4 <= p1; p += 4){
        int i0 = csr_src[p], i1 = csr_src[p+1], i2 = csr_src[p+2], i3 = csr_src[p+3];
        f32x4 x0 = *(const f32x4*)(xl + (size_t)i0*HC + 4*lane);
        f32x4 x1 = *(const f32x4*)(xl + (size_t)i1*HC + 4*lane);
        f32x4 x2 = *(const f32x4*)(xl + (size_t)i2*HC + 4*lane);
        f32x4 x3 = *(const f32x4*)(xl + (size_t)i3*HC + 4*lane);
        float t0 = 0.f, t1 = 0.f, t2 = 0.f, t3 = 0.f;
        #pragma unroll
        for (int j = 0; j < 4; j++){
            float e0 = x0[j] + xrf[j]; e0 = (e0 > 0.f) ? e0 : 0.2f*e0; t0 += e0*attf[j];
            float e1 = x1[j] + xrf[j]; e1 = (e1 > 0.f) ? e1 : 0.2f*e1; t1 += e1*attf[j];
            float e2 = x2[j] + xrf[j]; e2 = (e2 > 0.f) ? e2 : 0.2f*e2; t2 += e2*attf[j];
            float e3 = x3[j] + xrf[j]; e3 = (e3 > 0.f) ? e3 : 0.2f*e3; t3 += e3*attf[j];
        }
        #pragma unroll
        for (int off = 1; off < 16; off <<= 1){
            t0 += __shfl_xor(t0, off, 64);
            t1 += __shfl_xor(t1, off, 64);
            t2 += __shfl_xor(t2, off, 64);
            t3 += __shfl_xor(t3, off, 64);
        }
        float w0 = __expf(t0), w1 = __expf(t1), w2 = __expf(t2), w3 = __expf(t3);
        s += (w0 + w1) + (w2 + w3);
        acc = acc + x0*w0 + x1*w1 + x2*w2 + x3*w3;
    }
    for (; p < p1; p++){
        int i0 = csr_src[p];
        f32x4 x0 = *(const f32x4*)(xl + (size_t)i0*HC + 4*lane);
        float t0 = 0.f;
        #pragma unroll
        for (int j = 0; j < 4; j++){ float e0 = x0[j] + xrf[j]; e0 = (e0 > 0.f) ? e0 : 0.2f*e0; t0 += e0*attf[j]; }
        #pragma unroll
        for (int off = 1; off < 16; off <<= 1) t0 += __shfl_xor(t0, off, 64);
        float w0 = __expf(t0);
        s += w0;
        acc = acc + x0*w0;
    }
    float inv = 1.f / s;          // s uniform within each 16-lane head group
    f32x4 o = acc * inv;
    #pragma unroll
    for (int j = 0; j < 4; j++){ o[j] += __shfl_xor(o[j], 16, 64); o[j] += __shfl_xor(o[j], 32, 64); }
    if (lane < 16){
        f32x4 bv = *(const f32x4*)(bias + 4*lane);
        f32x4 res = o*0.25f + bv;
        *(f32x4*)(out + (size_t)node*CC + 4*lane) = res;
    }
}

// ---------------- BatchNorm stats ----------------
__global__ __launch_bounds__(256) void k_bnstats(const float* __restrict__ x, float* __restrict__ sums){
    __shared__ float ls[256], lq[256];
    int tid = threadIdx.x; int c = tid & 63; int g = tid >> 6;
    float s = 0.f, q = 0.f;
    for (int r = blockIdx.x*4 + g; r < NN; r += gridDim.x*4){
        float v = x[(size_t)r*64 + c]; s += v; q += v*v;
    }
    ls[tid] = s; lq[tid] = q; __syncthreads();
    if (tid < 64){
        s = ls[tid] + ls[tid+64] + ls[tid+128] + ls[tid+192];
        q = lq[tid] + lq[tid+64] + lq[tid+128] + lq[tid+192];
        atomicAdd(&sums[c], s); atomicAdd(&sums[64 + c], q);
    }
}

// h = relu(bn(hraw) + xres); writes fp32 h plus hi/lo bf16 split for layer-2 GEMMs
__global__ void k_post1(const float* __restrict__ hraw, const float* __restrict__ xres,
                        const float* __restrict__ sums, const float* __restrict__ g,
                        const float* __restrict__ b, float* __restrict__ out,
                        u16* __restrict__ hhi, u16* __restrict__ hlo){
    int i = blockIdx.x*256 + threadIdx.x;   // float4 index
    if (i >= NN*16) return;
    float4 hv = ((const float4*)hraw)[i];
    float4 rv = ((const float4*)xres)[i];
    int c0 = (i & 15) * 4;
    float hp[4] = {hv.x, hv.y, hv.z, hv.w};
    float rp[4] = {rv.x, rv.y, rv.z, rv.w};
    float res[4];
    u16x4 h4, l4;
    const float invN = 1.f / (float)NN;
    #pragma unroll
    for (int k = 0; k < 4; k++){
        int c = c0 + k;
        float mean = sums[c] * invN;
        float var  = sums[64 + c] * invN - mean*mean;
        float rstd = rsqrtf(var + 1e-5f);
        float v = g[c]*(hp[k] - mean)*rstd + b[c] + rp[k];
        v = (v > 0.f) ? v : 0.f;
        res[k] = v;
        u16 h = f2b(v);
        h4[k] = h;
        l4[k] = f2b(v - b2f(h));
    }
    ((float4*)out)[i] = make_float4(res[0], res[1], res[2], res[3]);
    *(u16x4*)(hhi + (size_t)i*4) = h4;
    *(u16x4*)(hlo + (size_t)i*4) = l4;
}

// z = bn(h2raw) + h
__global__ void k_post2(const float* __restrict__ hraw, const float* __restrict__ hprev,
                        const float* __restrict__ sums, const float* __restrict__ g,
                        const float* __restrict__ b, float* __restrict__ out){
    int i = blockIdx.x*256 + threadIdx.x;
    if (i >= NN*16) return;
    float4 hv = ((const float4*)hraw)[i];
    float4 rv = ((const float4*)hprev)[i];
    int c0 = (i & 15) * 4;
    float hp[4] = {hv.x, hv.y, hv.z, hv.w};
    float rp[4] = {rv.x, rv.y, rv.z, rv.w};
    float res[4];
    const float invN = 1.f / (float)NN;
    #pragma unroll
    for (int k = 0; k < 4; k++){
        int c = c0 + k;
        float mean = sums[c] * invN;
        float var  = sums[64 + c] * invN - mean*mean;
        float rstd = rsqrtf(var + 1e-5f);
        res[k] = g[c]*(hp[k] - mean)*rstd + b[c] + rp[k];
    }
    ((float4*)out)[i] = make_float4(res[0], res[1], res[2], res[3]);
}

// ---------------- link-prediction scores ----------------
__global__ __launch_bounds__(256) void k_score(const float* __restrict__ z, const int* __restrict__ eli,
                                               float* __restrict__ out){
    int t = blockIdx.x*256 + threadIdx.x;
    int i = t >> 4; int j = t & 15;
    if (i >= ELI_N) return;
    int a = eli[i], b = eli[ELI_N + i];
    float4 va = ((const float4*)(z + (size_t)a*64))[j];
    float4 vb = ((const float4*)(z + (size_t)b*64))[j];
    float s = va.x*vb.x + va.y*vb.y + va.z*vb.z + va.w*vb.w;
    #pragma unroll
    for (int off = 8; off > 0; off >>= 1) s += __shfl_xor(s, off, 64);
    if (j == 0) out[i] = 1.f / (1.f + __expf(-s));
}

extern "C" void kernel_launch(void* const* d_in, const int* in_sizes, int n_in,
                              void* d_out, int out_size, void* d_ws, size_t ws_size,
                              hipStream_t stream) {
    const float* x    = (const float*)d_in[0];
    const int*   ei   = (const int*)  d_in[1];
    const int*   eli  = (const int*)  d_in[2];
    const float* Wl1  = (const float*)d_in[3];
    const float* bl1  = (const float*)d_in[4];
    const float* Wr1  = (const float*)d_in[5];
    const float* br1  = (const float*)d_in[6];
    const float* att1 = (const float*)d_in[7];
    const float* bias1= (const float*)d_in[8];
    const float* g1   = (const float*)d_in[9];
    const float* b1   = (const float*)d_in[10];
    const float* Wres = (const float*)d_in[11];
    const float* bres = (const float*)d_in[12];
    const float* Wl2  = (const float*)d_in[13];
    const float* bl2  = (const float*)d_in[14];
    const float* Wr2  = (const float*)d_in[15];
    const float* br2  = (const float*)d_in[16];
    const float* att2 = (const float*)d_in[17];
    const float* bias2= (const float*)d_in[18];
    const float* g2   = (const float*)d_in[19];
    const float* b2   = (const float*)d_in[20];
    float* out = (float*)d_out;

    char* w = (char*)d_ws;
    size_t o = 0;
    auto take = [&](size_t bytes)->char*{ char* p = w + o; o += (bytes + 255) & ~(size_t)255; return p; };
    float* xl   = (float*)take((size_t)NN*HC*4);
    float* xr   = (float*)take((size_t)NN*HC*4);
    float* xres = (float*)take((size_t)NN*CC*4);   // later reused as z
    float* hraw = (float*)take((size_t)NN*CC*4);
    float* hbuf = (float*)take((size_t)NN*CC*4);
    u16*  xhi  = (u16*)take((size_t)NN*INC*2);
    u16*  xlo  = (u16*)take((size_t)NN*INC*2);
    u16*  hhi  = (u16*)take((size_t)NN*CC*2);
    u16*  hlo  = (u16*)take((size_t)NN*CC*2);
    u16* whl1 = (u16*)take(256*128*2);  u16* wll1 = (u16*)take(256*128*2);
    u16* whr1 = (u16*)take(256*128*2);  u16* wlr1 = (u16*)take(256*128*2);
    u16* whres= (u16*)take(64*128*2);   u16* wlres= (u16*)take(64*128*2);
    u16* whl2 = (u16*)take(256*64*2);   u16* wll2 = (u16*)take(256*64*2);
    u16* whr2 = (u16*)take(256*64*2);   u16* wlr2 = (u16*)take(256*64*2);
    // stats (256 floats) + deg (NN ints), contiguous for a single memset
    char* zreg  = take(256*4 + (size_t)NN*4);
    float* stats= (float*)zreg;
    int* deg    = (int*)(zreg + 256*4);
    int* rowptr = (int*)take((size_t)(NN+1)*4);
    int* iscan  = (int*)take((size_t)NN*4);
    int* cursor = (int*)take((size_t)NN*4);
    int* csr_src= (int*)take((size_t)ETOT*4);
    int* part   = (int*)take(64*4);

    hipMemsetAsync(zreg, 0, 256*4 + (size_t)NN*4, stream);

    // CSR build
    k_count<<<(EE+255)/256, 256, 0, stream>>>(ei, deg);
    k_scanA<<<49, 256, 0, stream>>>(deg, iscan, part);
    k_scanC<<<196, 256, 0, stream>>>(iscan, part, deg, rowptr, cursor);
    k_fill<<<(ETOT+255)/256, 256, 0, stream>>>(ei, cursor, csr_src);

    // conversions
    k_splitX<<<(NN*INC/4+255)/256, 256, 0, stream>>>(x, xhi, xlo);
    k_convW<<<(106496+255)/256, 256, 0, stream>>>(Wl1, Wr1, Wres, Wl2, Wr2,
                                                  whl1, wll1, whr1, wlr1, whres, wlres,
                                                  whl2, wll2, whr2, wlr2);

    // layer 1: 25 stripe-groups per XCD x 9 tiles x 8 XCDs = 1800 blocks
    k_gemm1<<<1800, 256, 0, stream>>>(xhi, xlo, whl1, wll1, whr1, wlr1, whres, wlres,
                                      bl1, br1, bres, xl, xr, xres);
    k_gat<<<(NN+3)/4, 256, 0, stream>>>(xl, xr, csr_src, rowptr, att1, bias1, hraw);
    k_bnstats<<<256, 256, 0, stream>>>(hraw, stats);
    k_post1<<<(NN*16+255)/256, 256, 0, stream>>>(hraw, xres, stats, g1, b1, hbuf, hhi, hlo);

    // layer 2: 25 stripe-groups per XCD x 8 tiles x 8 XCDs = 1600 blocks
    k_gemm2<<<1600, 256, 0, stream>>>(hhi, hlo, whl2, wll2, whr2, wlr2, bl2, br2, xl, xr);
    k_gat<<<(NN+3)/4, 256, 0, stream>>>(xl, xr, csr_src, rowptr, att2, bias2, hraw);
    k_bnstats<<<256, 256, 0, stream>>>(hraw, stats + 128);
    k_post2<<<(NN*16+255)/256, 256, 0, stream>>>(hraw, hbuf, stats + 128, g2, b2, xres);

    // scores
    k_score<<<(ELI_N*16+255)/256, 256, 0, stream>>>(xres, eli, out);
}

// Round 9
// 360.579 us; speedup vs baseline: 1.2299x; 1.1416x over previous
//
#include <hip/hip_runtime.h>
#include <math.h>

#define NN 50000
#define EE 400000
#define ETOT 450000
#define INC 128
#define CC 64
#define HC 256
#define ELI_N 200000
#define MPAD 50176   // 196*256; 3136 row-blocks of 16

typedef unsigned short u16;
typedef __attribute__((ext_vector_type(8))) short short8v;
typedef __attribute__((ext_vector_type(8))) unsigned short u16x8;
typedef __attribute__((ext_vector_type(4))) float f32x4;
typedef __attribute__((ext_vector_type(4))) unsigned short u16x4;

__device__ __forceinline__ u16 f2b(float v){
    unsigned u = __float_as_uint(v);
    u = (u + 0x7fffu + ((u >> 16) & 1u)) >> 16;   // RNE
    return (u16)u;
}
__device__ __forceinline__ float b2f(u16 h){
    return __uint_as_float(((unsigned)h) << 16);
}

// ---------------- CSR build ----------------
__global__ void k_count(const int* __restrict__ ei, int* __restrict__ deg){
    int e = blockIdx.x*256 + threadIdx.x;
    if (e < EE) atomicAdd(&deg[ei[EE + e]], 1);
}

__global__ void k_scanA(const int* __restrict__ deg, int* __restrict__ iscan, int* __restrict__ part){
    __shared__ int sh[256];
    int tid = threadIdx.x;
    int base = blockIdx.x*1024 + tid*4;
    int v[4]; int t = 0;
    #pragma unroll
    for (int i = 0; i < 4; i++){ int idx = base + i; v[i] = (idx < NN) ? deg[idx]+1 : 0; t += v[i]; }
    sh[tid] = t; __syncthreads();
    for (int off = 1; off < 256; off <<= 1){
        int u = (tid >= off) ? sh[tid - off] : 0;
        __syncthreads();
        sh[tid] += u;
        __syncthreads();
    }
    int incl = sh[tid];
    int run = incl - t;
    #pragma unroll
    for (int i = 0; i < 4; i++){
        run += v[i];
        int idx = base + i;
        if (idx < NN) iscan[idx] = run;
    }
    if (tid == 255) part[blockIdx.x] = incl;
}

__global__ void k_scanC(const int* __restrict__ iscan, const int* __restrict__ part,
                        const int* __restrict__ deg, int* __restrict__ rowptr, int* __restrict__ cursor){
    int chunk = blockIdx.x >> 2;
    int ps = 0;
    for (int j = 0; j < chunk; j++) ps += part[j];
    int i = blockIdx.x*256 + threadIdx.x;
    if (i < NN){
        int v = iscan[i] + ps;          // rowptr[i+1]
        rowptr[i+1] = v;
        cursor[i] = v - (deg[i]+1);     // rowptr[i]
    }
    if (i == 0) rowptr[0] = 0;
}

__global__ void k_fill(const int* __restrict__ ei, int* __restrict__ cursor, int* __restrict__ csr_src){
    int idx = blockIdx.x*256 + threadIdx.x;
    if (idx >= ETOT) return;
    int s, d;
    if (idx < EE){ s = ei[idx]; d = ei[EE + idx]; }
    else         { s = idx - EE; d = s; }
    int pos = atomicAdd(&cursor[d], 1);
    csr_src[pos] = s;
}

// ---------------- x -> bf16 hi/lo split, packed MFMA-fragment layout ----------------
// packed block = 16 rows x 32 k = 64 lanes x 8 u16 (512 u16 = 1KB)
// blk = (row>>4)*4 + (k>>5); lane = (row&15) + 16*((k>>3)&3); elem = k&7
__global__ void k_splitX(const float* __restrict__ src, u16* __restrict__ hi, u16* __restrict__ lo){
    int t = blockIdx.x*256 + threadIdx.x;      // one thread = 8 consecutive k of one row
    if (t >= NN*16) return;
    int row = t >> 4;
    int k0  = (t & 15) * 8;
    const float* ap = src + (size_t)row*128 + k0;
    float4 v0 = *(const float4*)ap;
    float4 v1 = *(const float4*)(ap + 4);
    float vv[8] = {v0.x, v0.y, v0.z, v0.w, v1.x, v1.y, v1.z, v1.w};
    u16x8 h8, l8;
    #pragma unroll
    for (int j = 0; j < 8; j++){
        u16 h = f2b(vv[j]);
        h8[j] = h;
        l8[j] = f2b(vv[j] - b2f(h));
    }
    size_t blk = (size_t)(row >> 4)*4 + (k0 >> 5);
    size_t addr = blk*512 + (size_t)((row & 15) + 16*((k0 >> 3) & 3))*8;
    *(u16x8*)(hi + addr) = h8;
    *(u16x8*)(lo + addr) = l8;
}

// ---------------- weights -> packed bf16 hi/lo fragment layout ----------------
// source W is [K][N] row-major; packed by (n-block, k-block):
// blk = (n>>4)*(K>>5) + (k>>5); lane = (n&15) + 16*((k>>3)&3); elem = k&7
__global__ void k_convW(const float* __restrict__ Wl1, const float* __restrict__ Wr1,
                        const float* __restrict__ Wres, const float* __restrict__ Wl2,
                        const float* __restrict__ Wr2,
                        u16* __restrict__ hl1, u16* __restrict__ ll1,
                        u16* __restrict__ hr1, u16* __restrict__ lr1,
                        u16* __restrict__ hres, u16* __restrict__ lres,
                        u16* __restrict__ hl2, u16* __restrict__ ll2,
                        u16* __restrict__ hr2, u16* __restrict__ lr2){
    int gid = blockIdx.x*256 + threadIdx.x;
    const float* src; u16* dh; u16* dl; int K, N, idx;
    if      (gid <  32768){ src=Wl1;  dh=hl1;  dl=ll1;  K=128; N=256; idx=gid; }
    else if (gid <  65536){ src=Wr1;  dh=hr1;  dl=lr1;  K=128; N=256; idx=gid-32768; }
    else if (gid <  73728){ src=Wres; dh=hres; dl=lres; K=128; N=64;  idx=gid-65536; }
    else if (gid <  90112){ src=Wl2;  dh=hl2;  dl=ll2;  K=64;  N=256; idx=gid-73728; }
    else if (gid < 106496){ src=Wr2;  dh=hr2;  dl=lr2;  K=64;  N=256; idx=gid-90112; }
    else return;
    int k = idx / N, n = idx - k*N;
    float v = src[idx];
    u16 h = f2b(v);
    size_t blk = (size_t)(n >> 4)*(K >> 5) + (k >> 5);
    size_t addr = blk*512 + (size_t)((n & 15) + 16*((k >> 3) & 3))*8 + (k & 7);
    dh[addr] = h;
    dl[addr] = f2b(v - b2f(h));
}

// ---------------- layer-1 GEMM, packed operands, XCD-swizzled 1D grid ----------------
// block b: xcd = b%8, k = b/8, tile = k%9, stripe = (b%8) + 8*(k/9)
__global__ __launch_bounds__(256) void k_gemm1(const u16* __restrict__ Ahi, const u16* __restrict__ Alo,
        const u16* __restrict__ Whl1, const u16* __restrict__ Wll1,
        const u16* __restrict__ Whr1, const u16* __restrict__ Wlr1,
        const u16* __restrict__ Whres,const u16* __restrict__ Wlres,
        const float* __restrict__ bl1, const float* __restrict__ br1, const float* __restrict__ bres,
        float* __restrict__ xl, float* __restrict__ xr, float* __restrict__ xres)
{
    int b = blockIdx.x;
    int c = b & 7;
    int k = b >> 3;
    int tile = k % 9;
    int sx = c + 8*(k/9);
    if (sx >= 196) return;
    int wid = threadIdx.x >> 6, lane = threadIdx.x & 63;
    const u16 *Bh, *Bl; const float* bias; float* Cout; int n0, N;
    if (tile < 4)      { Bh=Whl1;  Bl=Wll1;  bias=bl1;  Cout=xl;   n0=tile*64;     N=256; }
    else if (tile < 8) { Bh=Whr1;  Bl=Wlr1;  bias=br1;  Cout=xr;   n0=(tile-4)*64; N=256; }
    else               { Bh=Whres; Bl=Wlres; bias=bres; Cout=xres; n0=0;           N=64;  }
    int rm0 = (sx*4 + wid) * 64;
    int rblk0 = rm0 >> 4;          // row-block index
    int nblk0 = n0 >> 4;
    int lr = lane & 15;
    f32x4 acc[4][4] = {};
    #pragma unroll
    for (int ks = 0; ks < 4; ks++){
        short8v ah[4], al[4], bh[4], blo[4];
        #pragma unroll
        for (int mf = 0; mf < 4; mf++){
            size_t addr = ((size_t)(rblk0 + mf)*4 + ks)*512 + (size_t)lane*8;
            ah[mf] = *(const short8v*)(Ahi + addr);
            al[mf] = *(const short8v*)(Alo + addr);
        }
        #pragma unroll
        for (int nf = 0; nf < 4; nf++){
            size_t addr = ((size_t)(nblk0 + nf)*4 + ks)*512 + (size_t)lane*8;
            bh[nf]  = *(const short8v*)(Bh + addr);
            blo[nf] = *(const short8v*)(Bl + addr);
        }
        #pragma unroll
        for (int mf = 0; mf < 4; mf++)
            #pragma unroll
            for (int nf = 0; nf < 4; nf++){
                acc[mf][nf] = __builtin_amdgcn_mfma_f32_16x16x32_bf16(ah[mf], bh[nf],  acc[mf][nf], 0, 0, 0);
                acc[mf][nf] = __builtin_amdgcn_mfma_f32_16x16x32_bf16(al[mf], bh[nf],  acc[mf][nf], 0, 0, 0);
                acc[mf][nf] = __builtin_amdgcn_mfma_f32_16x16x32_bf16(ah[mf], blo[nf], acc[mf][nf], 0, 0, 0);
            }
    }
    int rbase = (lane >> 4) << 2;
    #pragma unroll
    for (int nf = 0; nf < 4; nf++){
        int col = n0 + nf*16 + lr;
        float bv = bias[col];
        #pragma unroll
        for (int mf = 0; mf < 4; mf++){
            #pragma unroll
            for (int r = 0; r < 4; r++){
                int row = rm0 + mf*16 + rbase + r;
                if (row < NN) Cout[(size_t)row*N + col] = acc[mf][nf][r] + bv;
            }
        }
    }
}

// ---------------- layer-2 GEMM, packed operands, K=64 ----------------
// block b: xcd = b%8, k = b/8, tile = k%8, stripe = (b%8) + 8*(k/8)
__global__ __launch_bounds__(256) void k_gemm2(const u16* __restrict__ Ahi, const u16* __restrict__ Alo,
        const u16* __restrict__ Whl2, const u16* __restrict__ Wll2,
        const u16* __restrict__ Whr2, const u16* __restrict__ Wlr2,
        const float* __restrict__ bl2, const float* __restrict__ br2,
        float* __restrict__ xl, float* __restrict__ xr)
{
    int b = blockIdx.x;
    int c = b & 7;
    int k = b >> 3;
    int tile = k & 7;
    int sx = c + 8*(k >> 3);
    if (sx >= 196) return;
    int wid = threadIdx.x >> 6, lane = threadIdx.x & 63;
    const u16 *Bh, *Bl; const float* bias; float* Cout;
    if (tile < 4){ Bh=Whl2; Bl=Wll2; bias=bl2; Cout=xl; }
    else         { Bh=Whr2; Bl=Wlr2; bias=br2; Cout=xr; }
    int n0 = (tile & 3)*64;
    int rm0 = (sx*4 + wid) * 64;
    int rblk0 = rm0 >> 4;
    int nblk0 = n0 >> 4;
    int lr = lane & 15;
    f32x4 acc[4][4] = {};
    #pragma unroll
    for (int ks = 0; ks < 2; ks++){
        short8v ah[4], al[4], bh[4], blo[4];
        #pragma unroll
        for (int mf = 0; mf < 4; mf++){
            size_t addr = ((size_t)(rblk0 + mf)*2 + ks)*512 + (size_t)lane*8;
            ah[mf] = *(const short8v*)(Ahi + addr);
            al[mf] = *(const short8v*)(Alo + addr);
        }
        #pragma unroll
        for (int nf = 0; nf < 4; nf++){
            size_t addr = ((size_t)(nblk0 + nf)*2 + ks)*512 + (size_t)lane*8;
            bh[nf]  = *(const short8v*)(Bh + addr);
            blo[nf] = *(const short8v*)(Bl + addr);
        }
        #pragma unroll
        for (int mf = 0; mf < 4; mf++)
            #pragma unroll
            for (int nf = 0; nf < 4; nf++){
                acc[mf][nf] = __builtin_amdgcn_mfma_f32_16x16x32_bf16(ah[mf], bh[nf],  acc[mf][nf], 0, 0, 0);
                acc[mf][nf] = __builtin_amdgcn_mfma_f32_16x16x32_bf16(al[mf], bh[nf],  acc[mf][nf], 0, 0, 0);
                acc[mf][nf] = __builtin_amdgcn_mfma_f32_16x16x32_bf16(ah[mf], blo[nf], acc[mf][nf], 0, 0, 0);
            }
    }
    int rbase = (lane >> 4) << 2;
    #pragma unroll
    for (int nf = 0; nf < 4; nf++){
        int col = n0 + nf*16 + lr;
        float bv = bias[col];
        #pragma unroll
        for (int mf = 0; mf < 4; mf++){
            #pragma unroll
            for (int r = 0; r < 4; r++){
                int row = rm0 + mf*16 + rbase + r;
                if (row < NN) Cout[(size_t)row*256 + col] = acc[mf][nf][r] + bv;
            }
        }
    }
}

// ---------------- fused GATv2 aggregation (no-max softmax, unroll-4) -------------
__global__ __launch_bounds__(256) void k_gat(const float* __restrict__ xl, const float* __restrict__ xr,
                                             const int* __restrict__ csr_src, const int* __restrict__ rowptr,
                                             const float* __restrict__ att, const float* __restrict__ bias,
                                             float* __restrict__ out)
{
    int wave = threadIdx.x >> 6, lane = threadIdx.x & 63;
    int node = blockIdx.x*4 + wave;
    if (node >= NN) return;
    int p0 = rowptr[node], p1 = rowptr[node+1];
    f32x4 xrf  = *(const f32x4*)(xr + (size_t)node*HC + 4*lane);
    f32x4 attf = *(const f32x4*)(att + 4*lane);
    float s = 0.f;
    f32x4 acc = {0.f, 0.f, 0.f, 0.f};
    int p = p0;
    for (; p + 4 <= p1; p += 4){
        int i0 = csr_src[p], i1 = csr_src[p+1], i2 = csr_src[p+2], i3 = csr_src[p+3];
        f32x4 x0 = *(const f32x4*)(xl + (size_t)i0*HC + 4*lane);
        f32x4 x1 = *(const f32x4*)(xl + (size_t)i1*HC + 4*lane);
        f32x4 x2 = *(const f32x4*)(xl + (size_t)i2*HC + 4*lane);
        f32x4 x3 = *(const f32x4*)(xl + (size_t)i3*HC + 4*lane);
        float t0 = 0.f, t1 = 0.f, t2 = 0.f, t3 = 0.f;
        #pragma unroll
        for (int j = 0; j < 4; j++){
            float e0 = x0[j] + xrf[j]; e0 = (e0 > 0.f) ? e0 : 0.2f*e0; t0 += e0*attf[j];
            float e1 = x1[j] + xrf[j]; e1 = (e1 > 0.f) ? e1 : 0.2f*e1; t1 += e1*attf[j];
            float e2 = x2[j] + xrf[j]; e2 = (e2 > 0.f) ? e2 : 0.2f*e2; t2 += e2*attf[j];
            float e3 = x3[j] + xrf[j]; e3 = (e3 > 0.f) ? e3 : 0.2f*e3; t3 += e3*attf[j];
        }
        #pragma unroll
        for (int off = 1; off < 16; off <<= 1){
            t0 += __shfl_xor(t0, off, 64);
            t1 += __shfl_xor(t1, off, 64);
            t2 += __shfl_xor(t2, off, 64);
            t3 += __shfl_xor(t3, off, 64);
        }
        float w0 = __expf(t0), w1 = __expf(t1), w2 = __expf(t2), w3 = __expf(t3);
        s += (w0 + w1) + (w2 + w3);
        acc = acc + x0*w0 + x1*w1 + x2*w2 + x3*w3;
    }
    for (; p < p1; p++){
        int i0 = csr_src[p];
        f32x4 x0 = *(const f32x4*)(xl + (size_t)i0*HC + 4*lane);
        float t0 = 0.f;
        #pragma unroll
        for (int j = 0; j < 4; j++){ float e0 = x0[j] + xrf[j]; e0 = (e0 > 0.f) ? e0 : 0.2f*e0; t0 += e0*attf[j]; }
        #pragma unroll
        for (int off = 1; off < 16; off <<= 1) t0 += __shfl_xor(t0, off, 64);
        float w0 = __expf(t0);
        s += w0;
        acc = acc + x0*w0;
    }
    float inv = 1.f / s;
    f32x4 o = acc * inv;
    #pragma unroll
    for (int j = 0; j < 4; j++){ o[j] += __shfl_xor(o[j], 16, 64); o[j] += __shfl_xor(o[j], 32, 64); }
    if (lane < 16){
        f32x4 bv = *(const f32x4*)(bias + 4*lane);
        f32x4 res = o*0.25f + bv;
        *(f32x4*)(out + (size_t)node*CC + 4*lane) = res;
    }
}

// ---------------- BatchNorm stats ----------------
__global__ __launch_bounds__(256) void k_bnstats(const float* __restrict__ x, float* __restrict__ sums){
    __shared__ float ls[256], lq[256];
    int tid = threadIdx.x; int c = tid & 63; int g = tid >> 6;
    float s = 0.f, q = 0.f;
    for (int r = blockIdx.x*4 + g; r < NN; r += gridDim.x*4){
        float v = x[(size_t)r*64 + c]; s += v; q += v*v;
    }
    ls[tid] = s; lq[tid] = q; __syncthreads();
    if (tid < 64){
        s = ls[tid] + ls[tid+64] + ls[tid+128] + ls[tid+192];
        q = lq[tid] + lq[tid+64] + lq[tid+128] + lq[tid+192];
        atomicAdd(&sums[c], s); atomicAdd(&sums[64 + c], q);
    }
}

// h = relu(bn(hraw) + xres); writes fp32 h + packed hi/lo bf16 (K=64 layout) for layer-2 A
__global__ void k_post1(const float* __restrict__ hraw, const float* __restrict__ xres,
                        const float* __restrict__ sums, const float* __restrict__ g,
                        const float* __restrict__ b, float* __restrict__ out,
                        u16* __restrict__ hhi, u16* __restrict__ hlo){
    int i = blockIdx.x*256 + threadIdx.x;   // float4 index
    if (i >= NN*16) return;
    float4 hv = ((const float4*)hraw)[i];
    float4 rv = ((const float4*)xres)[i];
    int row = i >> 4;
    int c0 = (i & 15) * 4;
    float hp[4] = {hv.x, hv.y, hv.z, hv.w};
    float rp[4] = {rv.x, rv.y, rv.z, rv.w};
    float res[4];
    u16x4 h4, l4;
    const float invN = 1.f / (float)NN;
    #pragma unroll
    for (int k = 0; k < 4; k++){
        int c = c0 + k;
        float mean = sums[c] * invN;
        float var  = sums[64 + c] * invN - mean*mean;
        float rstd = rsqrtf(var + 1e-5f);
        float v = g[c]*(hp[k] - mean)*rstd + b[c] + rp[k];
        v = (v > 0.f) ? v : 0.f;
        res[k] = v;
        u16 h = f2b(v);
        h4[k] = h;
        l4[k] = f2b(v - b2f(h));
    }
    ((float4*)out)[i] = make_float4(res[0], res[1], res[2], res[3]);
    // packed write: blk = (row>>4)*2 + (c0>>5); lane = (row&15)+16*((c0>>3)&3); elem = c0&7
    size_t blk = (size_t)(row >> 4)*2 + (c0 >> 5);
    size_t addr = blk*512 + (size_t)((row & 15) + 16*((c0 >> 3) & 3))*8 + (c0 & 7);
    *(u16x4*)(hhi + addr) = h4;
    *(u16x4*)(hlo + addr) = l4;
}

// z = bn(h2raw) + h
__global__ void k_post2(const float* __restrict__ hraw, const float* __restrict__ hprev,
                        const float* __restrict__ sums, const float* __restrict__ g,
                        const float* __restrict__ b, float* __restrict__ out){
    int i = blockIdx.x*256 + threadIdx.x;
    if (i >= NN*16) return;
    float4 hv = ((const float4*)hraw)[i];
    float4 rv = ((const float4*)hprev)[i];
    int c0 = (i & 15) * 4;
    float hp[4] = {hv.x, hv.y, hv.z, hv.w};
    float rp[4] = {rv.x, rv.y, rv.z, rv.w};
    float res[4];
    const float invN = 1.f / (float)NN;
    #pragma unroll
    for (int k = 0; k < 4; k++){
        int c = c0 + k;
        float mean = sums[c] * invN;
        float var  = sums[64 + c] * invN - mean*mean;
        float rstd = rsqrtf(var + 1e-5f);
        res[k] = g[c]*(hp[k] - mean)*rstd + b[c] + rp[k];
    }
    ((float4*)out)[i] = make_float4(res[0], res[1], res[2], res[3]);
}

// ---------------- link-prediction scores ----------------
__global__ __launch_bounds__(256) void k_score(const float* __restrict__ z, const int* __restrict__ eli,
                                               float* __restrict__ out){
    int t = blockIdx.x*256 + threadIdx.x;
    int i = t >> 4; int j = t & 15;
    if (i >= ELI_N) return;
    int a = eli[i], b = eli[ELI_N + i];
    float4 va = ((const float4*)(z + (size_t)a*64))[j];
    float4 vb = ((const float4*)(z + (size_t)b*64))[j];
    float s = va.x*vb.x + va.y*vb.y + va.z*vb.z + va.w*vb.w;
    #pragma unroll
    for (int off = 8; off > 0; off >>= 1) s += __shfl_xor(s, off, 64);
    if (j == 0) out[i] = 1.f / (1.f + __expf(-s));
}

extern "C" void kernel_launch(void* const* d_in, const int* in_sizes, int n_in,
                              void* d_out, int out_size, void* d_ws, size_t ws_size,
                              hipStream_t stream) {
    const float* x    = (const float*)d_in[0];
    const int*   ei   = (const int*)  d_in[1];
    const int*   eli  = (const int*)  d_in[2];
    const float* Wl1  = (const float*)d_in[3];
    const float* bl1  = (const float*)d_in[4];
    const float* Wr1  = (const float*)d_in[5];
    const float* br1  = (const float*)d_in[6];
    const float* att1 = (const float*)d_in[7];
    const float* bias1= (const float*)d_in[8];
    const float* g1   = (const float*)d_in[9];
    const float* b1   = (const float*)d_in[10];
    const float* Wres = (const float*)d_in[11];
    const float* bres = (const float*)d_in[12];
    const float* Wl2  = (const float*)d_in[13];
    const float* bl2  = (const float*)d_in[14];
    const float* Wr2  = (const float*)d_in[15];
    const float* br2  = (const float*)d_in[16];
    const float* att2 = (const float*)d_in[17];
    const float* bias2= (const float*)d_in[18];
    const float* g2   = (const float*)d_in[19];
    const float* b2   = (const float*)d_in[20];
    float* out = (float*)d_out;

    char* w = (char*)d_ws;
    size_t o = 0;
    auto take = [&](size_t bytes)->char*{ char* p = w + o; o += (bytes + 255) & ~(size_t)255; return p; };
    float* xl   = (float*)take((size_t)NN*HC*4);
    float* xr   = (float*)take((size_t)NN*HC*4);
    float* xres = (float*)take((size_t)NN*CC*4);   // later reused as z
    float* hraw = (float*)take((size_t)NN*CC*4);
    float* hbuf = (float*)take((size_t)NN*CC*4);
    u16*  xhi  = (u16*)take((size_t)MPAD*INC*2);   // packed fragment layout
    u16*  xlo  = (u16*)take((size_t)MPAD*INC*2);
    u16*  hhi  = (u16*)take((size_t)MPAD*CC*2);
    u16*  hlo  = (u16*)take((size_t)MPAD*CC*2);
    u16* whl1 = (u16*)take(256*128*2);  u16* wll1 = (u16*)take(256*128*2);
    u16* whr1 = (u16*)take(256*128*2);  u16* wlr1 = (u16*)take(256*128*2);
    u16* whres= (u16*)take(64*128*2);   u16* wlres= (u16*)take(64*128*2);
    u16* whl2 = (u16*)take(256*64*2);   u16* wll2 = (u16*)take(256*64*2);
    u16* whr2 = (u16*)take(256*64*2);   u16* wlr2 = (u16*)take(256*64*2);
    char* zreg  = take(256*4 + (size_t)NN*4);
    float* stats= (float*)zreg;
    int* deg    = (int*)(zreg + 256*4);
    int* rowptr = (int*)take((size_t)(NN+1)*4);
    int* iscan  = (int*)take((size_t)NN*4);
    int* cursor = (int*)take((size_t)NN*4);
    int* csr_src= (int*)take((size_t)ETOT*4);
    int* part   = (int*)take(64*4);

    hipMemsetAsync(zreg, 0, 256*4 + (size_t)NN*4, stream);

    // CSR build
    k_count<<<(EE+255)/256, 256, 0, stream>>>(ei, deg);
    k_scanA<<<49, 256, 0, stream>>>(deg, iscan, part);
    k_scanC<<<196, 256, 0, stream>>>(iscan, part, deg, rowptr, cursor);
    k_fill<<<(ETOT+255)/256, 256, 0, stream>>>(ei, cursor, csr_src);

    // conversions (packed layouts)
    k_splitX<<<(NN*16+255)/256, 256, 0, stream>>>(x, xhi, xlo);
    k_convW<<<(106496+255)/256, 256, 0, stream>>>(Wl1, Wr1, Wres, Wl2, Wr2,
                                                  whl1, wll1, whr1, wlr1, whres, wlres,
                                                  whl2, wll2, whr2, wlr2);

    // layer 1
    k_gemm1<<<1800, 256, 0, stream>>>(xhi, xlo, whl1, wll1, whr1, wlr1, whres, wlres,
                                      bl1, br1, bres, xl, xr, xres);
    k_gat<<<(NN+3)/4, 256, 0, stream>>>(xl, xr, csr_src, rowptr, att1, bias1, hraw);
    k_bnstats<<<256, 256, 0, stream>>>(hraw, stats);
    k_post1<<<(NN*16+255)/256, 256, 0, stream>>>(hraw, xres, stats, g1, b1, hbuf, hhi, hlo);

    // layer 2
    k_gemm2<<<1600, 256, 0, stream>>>(hhi, hlo, whl2, wll2, whr2, wlr2, bl2, br2, xl, xr);
    k_gat<<<(NN+3)/4, 256, 0, stream>>>(xl, xr, csr_src, rowptr, att2, bias2, hraw);
    k_bnstats<<<256, 256, 0, stream>>>(hraw, stats + 128);
    k_post2<<<(NN*16+255)/256, 256, 0, stream>>>(hraw, hbuf, stats + 128, g2, b2, xres);

    // scores
    k_score<<<(ELI_N*16+255)/256, 256, 0, stream>>>(xres, eli, out);
}

// Round 10
// 356.988 us; speedup vs baseline: 1.2423x; 1.0101x over previous
//
#include <hip/hip_runtime.h>
#include <math.h>

#define NN 50000
#define EE 400000
#define ETOT 450000
#define INC 128
#define CC 64
#define HC 256
#define ELI_N 200000
#define MPAD 50176   // 196*256; 3136 row-blocks of 16

typedef unsigned short u16;
typedef __attribute__((ext_vector_type(8))) short short8v;
typedef __attribute__((ext_vector_type(8))) unsigned short u16x8;
typedef __attribute__((ext_vector_type(4))) float f32x4;
typedef __attribute__((ext_vector_type(4))) unsigned short u16x4;

__device__ __forceinline__ u16 f2b(float v){
    unsigned u = __float_as_uint(v);
    u = (u + 0x7fffu + ((u >> 16) & 1u)) >> 16;   // RNE
    return (u16)u;
}
__device__ __forceinline__ float b2f(u16 h){
    return __uint_as_float(((unsigned)h) << 16);
}

// ---------------- fused setup: splitX (packed) | convW (packed) | edge count ----------------
// gid < 800000           : x -> bf16 hi/lo packed fragment layout
// 800000 <= gid < 906496 : weights -> packed bf16 hi/lo
// 906496 <= gid < 1306496: degree count (atomics into deg, zeroed by prior memset)
__global__ void k_setup(const float* __restrict__ x, const int* __restrict__ ei,
                        const float* __restrict__ Wl1, const float* __restrict__ Wr1,
                        const float* __restrict__ Wres, const float* __restrict__ Wl2,
                        const float* __restrict__ Wr2,
                        u16* __restrict__ xhi, u16* __restrict__ xlo,
                        u16* __restrict__ hl1, u16* __restrict__ ll1,
                        u16* __restrict__ hr1, u16* __restrict__ lr1,
                        u16* __restrict__ hres, u16* __restrict__ lres,
                        u16* __restrict__ hl2, u16* __restrict__ ll2,
                        u16* __restrict__ hr2, u16* __restrict__ lr2,
                        int* __restrict__ deg){
    int gid = blockIdx.x*256 + threadIdx.x;
    if (gid < 800000){
        // packed block = 16 rows x 32 k; blk=(row>>4)*4+(k>>5); lane=(row&15)+16*((k>>3)&3)
        int row = gid >> 4;
        int k0  = (gid & 15) * 8;
        const float* ap = x + (size_t)row*128 + k0;
        float4 v0 = *(const float4*)ap;
        float4 v1 = *(const float4*)(ap + 4);
        float vv[8] = {v0.x, v0.y, v0.z, v0.w, v1.x, v1.y, v1.z, v1.w};
        u16x8 h8, l8;
        #pragma unroll
        for (int j = 0; j < 8; j++){
            u16 h = f2b(vv[j]);
            h8[j] = h;
            l8[j] = f2b(vv[j] - b2f(h));
        }
        size_t blk = (size_t)(row >> 4)*4 + (k0 >> 5);
        size_t addr = blk*512 + (size_t)((row & 15) + 16*((k0 >> 3) & 3))*8;
        *(u16x8*)(xhi + addr) = h8;
        *(u16x8*)(xlo + addr) = l8;
    } else if (gid < 906496){
        int g = gid - 800000;
        const float* src; u16* dh; u16* dl; int K, N, idx;
        if      (g <  32768){ src=Wl1;  dh=hl1;  dl=ll1;  K=128; N=256; idx=g; }
        else if (g <  65536){ src=Wr1;  dh=hr1;  dl=lr1;  K=128; N=256; idx=g-32768; }
        else if (g <  73728){ src=Wres; dh=hres; dl=lres; K=128; N=64;  idx=g-65536; }
        else if (g <  90112){ src=Wl2;  dh=hl2;  dl=ll2;  K=64;  N=256; idx=g-73728; }
        else                { src=Wr2;  dh=hr2;  dl=lr2;  K=64;  N=256; idx=g-90112; }
        int k = idx / N, n = idx - k*N;
        float v = src[idx];
        u16 h = f2b(v);
        size_t blk = (size_t)(n >> 4)*(K >> 5) + (k >> 5);
        size_t addr = blk*512 + (size_t)((n & 15) + 16*((k >> 3) & 3))*8 + (k & 7);
        dh[addr] = h;
        dl[addr] = f2b(v - b2f(h));
    } else if (gid < 1306496){
        int e = gid - 906496;
        atomicAdd(&deg[ei[EE + e]], 1);
    }
}

// ---------------- CSR build ----------------
__global__ void k_scanA(const int* __restrict__ deg, int* __restrict__ iscan, int* __restrict__ part){
    __shared__ int sh[256];
    int tid = threadIdx.x;
    int base = blockIdx.x*1024 + tid*4;
    int v[4]; int t = 0;
    #pragma unroll
    for (int i = 0; i < 4; i++){ int idx = base + i; v[i] = (idx < NN) ? deg[idx]+1 : 0; t += v[i]; }
    sh[tid] = t; __syncthreads();
    for (int off = 1; off < 256; off <<= 1){
        int u = (tid >= off) ? sh[tid - off] : 0;
        __syncthreads();
        sh[tid] += u;
        __syncthreads();
    }
    int incl = sh[tid];
    int run = incl - t;
    #pragma unroll
    for (int i = 0; i < 4; i++){
        run += v[i];
        int idx = base + i;
        if (idx < NN) iscan[idx] = run;
    }
    if (tid == 255) part[blockIdx.x] = incl;
}

__global__ void k_scanC(const int* __restrict__ iscan, const int* __restrict__ part,
                        const int* __restrict__ deg, int* __restrict__ rowptr, int* __restrict__ cursor){
    int chunk = blockIdx.x >> 2;
    int ps = 0;
    for (int j = 0; j < chunk; j++) ps += part[j];
    int i = blockIdx.x*256 + threadIdx.x;
    if (i < NN){
        int v = iscan[i] + ps;          // rowptr[i+1]
        rowptr[i+1] = v;
        cursor[i] = v - (deg[i]+1);     // rowptr[i]
    }
    if (i == 0) rowptr[0] = 0;
}

__global__ void k_fill(const int* __restrict__ ei, int* __restrict__ cursor, int* __restrict__ csr_src){
    int idx = blockIdx.x*256 + threadIdx.x;
    if (idx >= ETOT) return;
    int s, d;
    if (idx < EE){ s = ei[idx]; d = ei[EE + idx]; }
    else         { s = idx - EE; d = s; }
    int pos = atomicAdd(&cursor[d], 1);
    csr_src[pos] = s;
}

// ---------------- layer-1 GEMM, packed operands, XCD-swizzled 1D grid ----------------
__global__ __launch_bounds__(256) void k_gemm1(const u16* __restrict__ Ahi, const u16* __restrict__ Alo,
        const u16* __restrict__ Whl1, const u16* __restrict__ Wll1,
        const u16* __restrict__ Whr1, const u16* __restrict__ Wlr1,
        const u16* __restrict__ Whres,const u16* __restrict__ Wlres,
        const float* __restrict__ bl1, const float* __restrict__ br1, const float* __restrict__ bres,
        float* __restrict__ xl, float* __restrict__ xr, float* __restrict__ xres)
{
    int b = blockIdx.x;
    int c = b & 7;
    int k = b >> 3;
    int tile = k % 9;
    int sx = c + 8*(k/9);
    if (sx >= 196) return;
    int wid = threadIdx.x >> 6, lane = threadIdx.x & 63;
    const u16 *Bh, *Bl; const float* bias; float* Cout; int n0, N;
    if (tile < 4)      { Bh=Whl1;  Bl=Wll1;  bias=bl1;  Cout=xl;   n0=tile*64;     N=256; }
    else if (tile < 8) { Bh=Whr1;  Bl=Wlr1;  bias=br1;  Cout=xr;   n0=(tile-4)*64; N=256; }
    else               { Bh=Whres; Bl=Wlres; bias=bres; Cout=xres; n0=0;           N=64;  }
    int rm0 = (sx*4 + wid) * 64;
    int rblk0 = rm0 >> 4;
    int nblk0 = n0 >> 4;
    int lr = lane & 15;
    f32x4 acc[4][4] = {};
    #pragma unroll
    for (int ks = 0; ks < 4; ks++){
        short8v ah[4], al[4], bh[4], blo[4];
        #pragma unroll
        for (int mf = 0; mf < 4; mf++){
            size_t addr = ((size_t)(rblk0 + mf)*4 + ks)*512 + (size_t)lane*8;
            ah[mf] = *(const short8v*)(Ahi + addr);
            al[mf] = *(const short8v*)(Alo + addr);
        }
        #pragma unroll
        for (int nf = 0; nf < 4; nf++){
            size_t addr = ((size_t)(nblk0 + nf)*4 + ks)*512 + (size_t)lane*8;
            bh[nf]  = *(const short8v*)(Bh + addr);
            blo[nf] = *(const short8v*)(Bl + addr);
        }
        #pragma unroll
        for (int mf = 0; mf < 4; mf++)
            #pragma unroll
            for (int nf = 0; nf < 4; nf++){
                acc[mf][nf] = __builtin_amdgcn_mfma_f32_16x16x32_bf16(ah[mf], bh[nf],  acc[mf][nf], 0, 0, 0);
                acc[mf][nf] = __builtin_amdgcn_mfma_f32_16x16x32_bf16(al[mf], bh[nf],  acc[mf][nf], 0, 0, 0);
                acc[mf][nf] = __builtin_amdgcn_mfma_f32_16x16x32_bf16(ah[mf], blo[nf], acc[mf][nf], 0, 0, 0);
            }
    }
    int rbase = (lane >> 4) << 2;
    #pragma unroll
    for (int nf = 0; nf < 4; nf++){
        int col = n0 + nf*16 + lr;
        float bv = bias[col];
        #pragma unroll
        for (int mf = 0; mf < 4; mf++){
            #pragma unroll
            for (int r = 0; r < 4; r++){
                int row = rm0 + mf*16 + rbase + r;
                if (row < NN) Cout[(size_t)row*N + col] = acc[mf][nf][r] + bv;
            }
        }
    }
}

// ---------------- layer-2 GEMM, packed operands, K=64 ----------------
__global__ __launch_bounds__(256) void k_gemm2(const u16* __restrict__ Ahi, const u16* __restrict__ Alo,
        const u16* __restrict__ Whl2, const u16* __restrict__ Wll2,
        const u16* __restrict__ Whr2, const u16* __restrict__ Wlr2,
        const float* __restrict__ bl2, const float* __restrict__ br2,
        float* __restrict__ xl, float* __restrict__ xr)
{
    int b = blockIdx.x;
    int c = b & 7;
    int k = b >> 3;
    int tile = k & 7;
    int sx = c + 8*(k >> 3);
    if (sx >= 196) return;
    int wid = threadIdx.x >> 6, lane = threadIdx.x & 63;
    const u16 *Bh, *Bl; const float* bias; float* Cout;
    if (tile < 4){ Bh=Whl2; Bl=Wll2; bias=bl2; Cout=xl; }
    else         { Bh=Whr2; Bl=Wlr2; bias=br2; Cout=xr; }
    int n0 = (tile & 3)*64;
    int rm0 = (sx*4 + wid) * 64;
    int rblk0 = rm0 >> 4;
    int nblk0 = n0 >> 4;
    int lr = lane & 15;
    f32x4 acc[4][4] = {};
    #pragma unroll
    for (int ks = 0; ks < 2; ks++){
        short8v ah[4], al[4], bh[4], blo[4];
        #pragma unroll
        for (int mf = 0; mf < 4; mf++){
            size_t addr = ((size_t)(rblk0 + mf)*2 + ks)*512 + (size_t)lane*8;
            ah[mf] = *(const short8v*)(Ahi + addr);
            al[mf] = *(const short8v*)(Alo + addr);
        }
        #pragma unroll
        for (int nf = 0; nf < 4; nf++){
            size_t addr = ((size_t)(nblk0 + nf)*2 + ks)*512 + (size_t)lane*8;
            bh[nf]  = *(const short8v*)(Bh + addr);
            blo[nf] = *(const short8v*)(Bl + addr);
        }
        #pragma unroll
        for (int mf = 0; mf < 4; mf++)
            #pragma unroll
            for (int nf = 0; nf < 4; nf++){
                acc[mf][nf] = __builtin_amdgcn_mfma_f32_16x16x32_bf16(ah[mf], bh[nf],  acc[mf][nf], 0, 0, 0);
                acc[mf][nf] = __builtin_amdgcn_mfma_f32_16x16x32_bf16(al[mf], bh[nf],  acc[mf][nf], 0, 0, 0);
                acc[mf][nf] = __builtin_amdgcn_mfma_f32_16x16x32_bf16(ah[mf], blo[nf], acc[mf][nf], 0, 0, 0);
            }
    }
    int rbase = (lane >> 4) << 2;
    #pragma unroll
    for (int nf = 0; nf < 4; nf++){
        int col = n0 + nf*16 + lr;
        float bv = bias[col];
        #pragma unroll
        for (int mf = 0; mf < 4; mf++){
            #pragma unroll
            for (int r = 0; r < 4; r++){
                int row = rm0 + mf*16 + rbase + r;
                if (row < NN) Cout[(size_t)row*256 + col] = acc[mf][nf][r] + bv;
            }
        }
    }
}

// ---------------- fused GATv2 aggregation (no-max softmax, unroll-4) -------------
__global__ __launch_bounds__(256) void k_gat(const float* __restrict__ xl, const float* __restrict__ xr,
                                             const int* __restrict__ csr_src, const int* __restrict__ rowptr,
                                             const float* __restrict__ att, const float* __restrict__ bias,
                                             float* __restrict__ out)
{
    int wave = threadIdx.x >> 6, lane = threadIdx.x & 63;
    int node = blockIdx.x*4 + wave;
    if (node >= NN) return;
    int p0 = rowptr[node], p1 = rowptr[node+1];
    f32x4 xrf  = *(const f32x4*)(xr + (size_t)node*HC + 4*lane);
    f32x4 attf = *(const f32x4*)(att + 4*lane);
    float s = 0.f;
    f32x4 acc = {0.f, 0.f, 0.f, 0.f};
    int p = p0;
    for (; p + 4 <= p1; p += 4){
        int i0 = csr_src[p], i1 = csr_src[p+1], i2 = csr_src[p+2], i3 = csr_src[p+3];
        f32x4 x0 = *(const f32x4*)(xl + (size_t)i0*HC + 4*lane);
        f32x4 x1 = *(const f32x4*)(xl + (size_t)i1*HC + 4*lane);
        f32x4 x2 = *(const f32x4*)(xl + (size_t)i2*HC + 4*lane);
        f32x4 x3 = *(const f32x4*)(xl + (size_t)i3*HC + 4*lane);
        float t0 = 0.f, t1 = 0.f, t2 = 0.f, t3 = 0.f;
        #pragma unroll
        for (int j = 0; j < 4; j++){
            float e0 = x0[j] + xrf[j]; e0 = (e0 > 0.f) ? e0 : 0.2f*e0; t0 += e0*attf[j];
            float e1 = x1[j] + xrf[j]; e1 = (e1 > 0.f) ? e1 : 0.2f*e1; t1 += e1*attf[j];
            float e2 = x2[j] + xrf[j]; e2 = (e2 > 0.f) ? e2 : 0.2f*e2; t2 += e2*attf[j];
            float e3 = x3[j] + xrf[j]; e3 = (e3 > 0.f) ? e3 : 0.2f*e3; t3 += e3*attf[j];
        }
        #pragma unroll
        for (int off = 1; off < 16; off <<= 1){
            t0 += __shfl_xor(t0, off, 64);
            t1 += __shfl_xor(t1, off, 64);
            t2 += __shfl_xor(t2, off, 64);
            t3 += __shfl_xor(t3, off, 64);
        }
        float w0 = __expf(t0), w1 = __expf(t1), w2 = __expf(t2), w3 = __expf(t3);
        s += (w0 + w1) + (w2 + w3);
        acc = acc + x0*w0 + x1*w1 + x2*w2 + x3*w3;
    }
    for (; p < p1; p++){
        int i0 = csr_src[p];
        f32x4 x0 = *(const f32x4*)(xl + (size_t)i0*HC + 4*lane);
        float t0 = 0.f;
        #pragma unroll
        for (int j = 0; j < 4; j++){ float e0 = x0[j] + xrf[j]; e0 = (e0 > 0.f) ? e0 : 0.2f*e0; t0 += e0*attf[j]; }
        #pragma unroll
        for (int off = 1; off < 16; off <<= 1) t0 += __shfl_xor(t0, off, 64);
        float w0 = __expf(t0);
        s += w0;
        acc = acc + x0*w0;
    }
    float inv = 1.f / s;
    f32x4 o = acc * inv;
    #pragma unroll
    for (int j = 0; j < 4; j++){ o[j] += __shfl_xor(o[j], 16, 64); o[j] += __shfl_xor(o[j], 32, 64); }
    if (lane < 16){
        f32x4 bv = *(const f32x4*)(bias + 4*lane);
        f32x4 res = o*0.25f + bv;
        *(f32x4*)(out + (size_t)node*CC + 4*lane) = res;
    }
}

// ---------------- BatchNorm stats ----------------
__global__ __launch_bounds__(256) void k_bnstats(const float* __restrict__ x, float* __restrict__ sums){
    __shared__ float ls[256], lq[256];
    int tid = threadIdx.x; int c = tid & 63; int g = tid >> 6;
    float s = 0.f, q = 0.f;
    for (int r = blockIdx.x*4 + g; r < NN; r += gridDim.x*4){
        float v = x[(size_t)r*64 + c]; s += v; q += v*v;
    }
    ls[tid] = s; lq[tid] = q; __syncthreads();
    if (tid < 64){
        s = ls[tid] + ls[tid+64] + ls[tid+128] + ls[tid+192];
        q = lq[tid] + lq[tid+64] + lq[tid+128] + lq[tid+192];
        atomicAdd(&sums[c], s); atomicAdd(&sums[64 + c], q);
    }
}

// h = relu(bn(hraw) + xres); writes fp32 h + packed hi/lo bf16 (K=64 layout) for layer-2 A
__global__ void k_post1(const float* __restrict__ hraw, const float* __restrict__ xres,
                        const float* __restrict__ sums, const float* __restrict__ g,
                        const float* __restrict__ b, float* __restrict__ out,
                        u16* __restrict__ hhi, u16* __restrict__ hlo){
    int i = blockIdx.x*256 + threadIdx.x;   // float4 index
    if (i >= NN*16) return;
    float4 hv = ((const float4*)hraw)[i];
    float4 rv = ((const float4*)xres)[i];
    int row = i >> 4;
    int c0 = (i & 15) * 4;
    float hp[4] = {hv.x, hv.y, hv.z, hv.w};
    float rp[4] = {rv.x, rv.y, rv.z, rv.w};
    float res[4];
    u16x4 h4, l4;
    const float invN = 1.f / (float)NN;
    #pragma unroll
    for (int k = 0; k < 4; k++){
        int c = c0 + k;
        float mean = sums[c] * invN;
        float var  = sums[64 + c] * invN - mean*mean;
        float rstd = rsqrtf(var + 1e-5f);
        float v = g[c]*(hp[k] - mean)*rstd + b[c] + rp[k];
        v = (v > 0.f) ? v : 0.f;
        res[k] = v;
        u16 h = f2b(v);
        h4[k] = h;
        l4[k] = f2b(v - b2f(h));
    }
    ((float4*)out)[i] = make_float4(res[0], res[1], res[2], res[3]);
    size_t blk = (size_t)(row >> 4)*2 + (c0 >> 5);
    size_t addr = blk*512 + (size_t)((row & 15) + 16*((c0 >> 3) & 3))*8 + (c0 & 7);
    *(u16x4*)(hhi + addr) = h4;
    *(u16x4*)(hlo + addr) = l4;
}

// z = bn(h2raw) + h
__global__ void k_post2(const float* __restrict__ hraw, const float* __restrict__ hprev,
                        const float* __restrict__ sums, const float* __restrict__ g,
                        const float* __restrict__ b, float* __restrict__ out){
    int i = blockIdx.x*256 + threadIdx.x;
    if (i >= NN*16) return;
    float4 hv = ((const float4*)hraw)[i];
    float4 rv = ((const float4*)hprev)[i];
    int c0 = (i & 15) * 4;
    float hp[4] = {hv.x, hv.y, hv.z, hv.w};
    float rp[4] = {rv.x, rv.y, rv.z, rv.w};
    float res[4];
    const float invN = 1.f / (float)NN;
    #pragma unroll
    for (int k = 0; k < 4; k++){
        int c = c0 + k;
        float mean = sums[c] * invN;
        float var  = sums[64 + c] * invN - mean*mean;
        float rstd = rsqrtf(var + 1e-5f);
        res[k] = g[c]*(hp[k] - mean)*rstd + b[c] + rp[k];
    }
    ((float4*)out)[i] = make_float4(res[0], res[1], res[2], res[3]);
}

// ---------------- link-prediction scores ----------------
__global__ __launch_bounds__(256) void k_score(const float* __restrict__ z, const int* __restrict__ eli,
                                               float* __restrict__ out){
    int t = blockIdx.x*256 + threadIdx.x;
    int i = t >> 4; int j = t & 15;
    if (i >= ELI_N) return;
    int a = eli[i], b = eli[ELI_N + i];
    float4 va = ((const float4*)(z + (size_t)a*64))[j];
    float4 vb = ((const float4*)(z + (size_t)b*64))[j];
    float s = va.x*vb.x + va.y*vb.y + va.z*vb.z + va.w*vb.w;
    #pragma unroll
    for (int off = 8; off > 0; off >>= 1) s += __shfl_xor(s, off, 64);
    if (j == 0) out[i] = 1.f / (1.f + __expf(-s));
}

extern "C" void kernel_launch(void* const* d_in, const int* in_sizes, int n_in,
                              void* d_out, int out_size, void* d_ws, size_t ws_size,
                              hipStream_t stream) {
    const float* x    = (const float*)d_in[0];
    const int*   ei   = (const int*)  d_in[1];
    const int*   eli  = (const int*)  d_in[2];
    const float* Wl1  = (const float*)d_in[3];
    const float* bl1  = (const float*)d_in[4];
    const float* Wr1  = (const float*)d_in[5];
    const float* br1  = (const float*)d_in[6];
    const float* att1 = (const float*)d_in[7];
    const float* bias1= (const float*)d_in[8];
    const float* g1   = (const float*)d_in[9];
    const float* b1   = (const float*)d_in[10];
    const float* Wres = (const float*)d_in[11];
    const float* bres = (const float*)d_in[12];
    const float* Wl2  = (const float*)d_in[13];
    const float* bl2  = (const float*)d_in[14];
    const float* Wr2  = (const float*)d_in[15];
    const float* br2  = (const float*)d_in[16];
    const float* att2 = (const float*)d_in[17];
    const float* bias2= (const float*)d_in[18];
    const float* g2   = (const float*)d_in[19];
    const float* b2   = (const float*)d_in[20];
    float* out = (float*)d_out;

    char* w = (char*)d_ws;
    size_t o = 0;
    auto take = [&](size_t bytes)->char*{ char* p = w + o; o += (bytes + 255) & ~(size_t)255; return p; };
    float* xl   = (float*)take((size_t)NN*HC*4);
    float* xr   = (float*)take((size_t)NN*HC*4);
    float* xres = (float*)take((size_t)NN*CC*4);   // later reused as z
    float* hraw = (float*)take((size_t)NN*CC*4);
    float* hbuf = (float*)take((size_t)NN*CC*4);
    u16*  xhi  = (u16*)take((size_t)MPAD*INC*2);   // packed fragment layout
    u16*  xlo  = (u16*)take((size_t)MPAD*INC*2);
    u16*  hhi  = (u16*)take((size_t)MPAD*CC*2);
    u16*  hlo  = (u16*)take((size_t)MPAD*CC*2);
    u16* whl1 = (u16*)take(256*128*2);  u16* wll1 = (u16*)take(256*128*2);
    u16* whr1 = (u16*)take(256*128*2);  u16* wlr1 = (u16*)take(256*128*2);
    u16* whres= (u16*)take(64*128*2);   u16* wlres= (u16*)take(64*128*2);
    u16* whl2 = (u16*)take(256*64*2);   u16* wll2 = (u16*)take(256*64*2);
    u16* whr2 = (u16*)take(256*64*2);   u16* wlr2 = (u16*)take(256*64*2);
    char* zreg  = take(256*4 + (size_t)NN*4);
    float* stats= (float*)zreg;
    int* deg    = (int*)(zreg + 256*4);
    int* rowptr = (int*)take((size_t)(NN+1)*4);
    int* iscan  = (int*)take((size_t)NN*4);
    int* cursor = (int*)take((size_t)NN*4);
    int* csr_src= (int*)take((size_t)ETOT*4);
    int* part   = (int*)take(64*4);

    hipMemsetAsync(zreg, 0, 256*4 + (size_t)NN*4, stream);

    // fused setup: x split (packed) | weight conv (packed) | degree count
    k_setup<<<5104, 256, 0, stream>>>(x, ei, Wl1, Wr1, Wres, Wl2, Wr2,
                                      xhi, xlo,
                                      whl1, wll1, whr1, wlr1, whres, wlres,
                                      whl2, wll2, whr2, wlr2, deg);

    // CSR build
    k_scanA<<<49, 256, 0, stream>>>(deg, iscan, part);
    k_scanC<<<196, 256, 0, stream>>>(iscan, part, deg, rowptr, cursor);
    k_fill<<<(ETOT+255)/256, 256, 0, stream>>>(ei, cursor, csr_src);

    // layer 1
    k_gemm1<<<1800, 256, 0, stream>>>(xhi, xlo, whl1, wll1, whr1, wlr1, whres, wlres,
                                      bl1, br1, bres, xl, xr, xres);
    k_gat<<<(NN+3)/4, 256, 0, stream>>>(xl, xr, csr_src, rowptr, att1, bias1, hraw);
    k_bnstats<<<256, 256, 0, stream>>>(hraw, stats);
    k_post1<<<(NN*16+255)/256, 256, 0, stream>>>(hraw, xres, stats, g1, b1, hbuf, hhi, hlo);

    // layer 2
    k_gemm2<<<1600, 256, 0, stream>>>(hhi, hlo, whl2, wll2, whr2, wlr2, bl2, br2, xl, xr);
    k_gat<<<(NN+3)/4, 256, 0, stream>>>(xl, xr, csr_src, rowptr, att2, bias2, hraw);
    k_bnstats<<<256, 256, 0, stream>>>(hraw, stats + 128);
    k_post2<<<(NN*16+255)/256, 256, 0, stream>>>(hraw, hbuf, stats + 128, g2, b2, xres);

    // scores
    k_score<<<(ELI_N*16+255)/256, 256, 0, stream>>>(xres, eli, out);
}

// Round 11
// 311.413 us; speedup vs baseline: 1.4241x; 1.1463x over previous
//
#include <hip/hip_runtime.h>
#include <math.h>

#define NN 50000
#define EE 400000
#define ETOT 450000
#define INC 128
#define CC 64
#define HC 256
#define ELI_N 200000
#define MPAD 50176   // 196*256; 3136 row-blocks of 16

typedef unsigned short u16;
typedef __attribute__((ext_vector_type(8))) short short8v;
typedef __attribute__((ext_vector_type(8))) unsigned short u16x8;
typedef __attribute__((ext_vector_type(4))) float f32x4;
typedef __attribute__((ext_vector_type(4))) unsigned short u16x4;

__device__ __forceinline__ u16 f2b(float v){
    unsigned u = __float_as_uint(v);
    u = (u + 0x7fffu + ((u >> 16) & 1u)) >> 16;   // RNE
    return (u16)u;
}
__device__ __forceinline__ float b2f(u16 h){
    return __uint_as_float(((unsigned)h) << 16);
}
__device__ __forceinline__ u16 f2h(float v){
    _Float16 h = (_Float16)v; u16 r; __builtin_memcpy(&r, &h, 2); return r;
}
__device__ __forceinline__ float h2f(u16 h){
    _Float16 x; __builtin_memcpy(&x, &h, 2); return (float)x;
}
__device__ __forceinline__ f32x4 h2f4(u16x4 r){
    f32x4 o; o[0]=h2f(r[0]); o[1]=h2f(r[1]); o[2]=h2f(r[2]); o[3]=h2f(r[3]); return o;
}

// ---------------- fused setup: splitX (packed) | convW (packed) | edge count ----------------
__global__ void k_setup(const float* __restrict__ x, const int* __restrict__ ei,
                        const float* __restrict__ Wl1, const float* __restrict__ Wr1,
                        const float* __restrict__ Wres, const float* __restrict__ Wl2,
                        const float* __restrict__ Wr2,
                        u16* __restrict__ xhi, u16* __restrict__ xlo,
                        u16* __restrict__ hl1, u16* __restrict__ ll1,
                        u16* __restrict__ hr1, u16* __restrict__ lr1,
                        u16* __restrict__ hres, u16* __restrict__ lres,
                        u16* __restrict__ hl2, u16* __restrict__ ll2,
                        u16* __restrict__ hr2, u16* __restrict__ lr2,
                        int* __restrict__ deg){
    int gid = blockIdx.x*256 + threadIdx.x;
    if (gid < 800000){
        int row = gid >> 4;
        int k0  = (gid & 15) * 8;
        const float* ap = x + (size_t)row*128 + k0;
        float4 v0 = *(const float4*)ap;
        float4 v1 = *(const float4*)(ap + 4);
        float vv[8] = {v0.x, v0.y, v0.z, v0.w, v1.x, v1.y, v1.z, v1.w};
        u16x8 h8, l8;
        #pragma unroll
        for (int j = 0; j < 8; j++){
            u16 h = f2b(vv[j]);
            h8[j] = h;
            l8[j] = f2b(vv[j] - b2f(h));
        }
        size_t blk = (size_t)(row >> 4)*4 + (k0 >> 5);
        size_t addr = blk*512 + (size_t)((row & 15) + 16*((k0 >> 3) & 3))*8;
        *(u16x8*)(xhi + addr) = h8;
        *(u16x8*)(xlo + addr) = l8;
    } else if (gid < 906496){
        int g = gid - 800000;
        const float* src; u16* dh; u16* dl; int K, N, idx;
        if      (g <  32768){ src=Wl1;  dh=hl1;  dl=ll1;  K=128; N=256; idx=g; }
        else if (g <  65536){ src=Wr1;  dh=hr1;  dl=lr1;  K=128; N=256; idx=g-32768; }
        else if (g <  73728){ src=Wres; dh=hres; dl=lres; K=128; N=64;  idx=g-65536; }
        else if (g <  90112){ src=Wl2;  dh=hl2;  dl=ll2;  K=64;  N=256; idx=g-73728; }
        else                { src=Wr2;  dh=hr2;  dl=lr2;  K=64;  N=256; idx=g-90112; }
        int k = idx / N, n = idx - k*N;
        float v = src[idx];
        u16 h = f2b(v);
        size_t blk = (size_t)(n >> 4)*(K >> 5) + (k >> 5);
        size_t addr = blk*512 + (size_t)((n & 15) + 16*((k >> 3) & 3))*8 + (k & 7);
        dh[addr] = h;
        dl[addr] = f2b(v - b2f(h));
    } else if (gid < 1306496){
        int e = gid - 906496;
        atomicAdd(&deg[ei[EE + e]], 1);
    }
}

// ---------------- CSR build ----------------
__global__ void k_scanA(const int* __restrict__ deg, int* __restrict__ iscan, int* __restrict__ part){
    __shared__ int sh[256];
    int tid = threadIdx.x;
    int base = blockIdx.x*1024 + tid*4;
    int v[4]; int t = 0;
    #pragma unroll
    for (int i = 0; i < 4; i++){ int idx = base + i; v[i] = (idx < NN) ? deg[idx]+1 : 0; t += v[i]; }
    sh[tid] = t; __syncthreads();
    for (int off = 1; off < 256; off <<= 1){
        int u = (tid >= off) ? sh[tid - off] : 0;
        __syncthreads();
        sh[tid] += u;
        __syncthreads();
    }
    int incl = sh[tid];
    int run = incl - t;
    #pragma unroll
    for (int i = 0; i < 4; i++){
        run += v[i];
        int idx = base + i;
        if (idx < NN) iscan[idx] = run;
    }
    if (tid == 255) part[blockIdx.x] = incl;
}

__global__ void k_scanC(const int* __restrict__ iscan, const int* __restrict__ part,
                        const int* __restrict__ deg, int* __restrict__ rowptr, int* __restrict__ cursor){
    int chunk = blockIdx.x >> 2;
    int ps = 0;
    for (int j = 0; j < chunk; j++) ps += part[j];
    int i = blockIdx.x*256 + threadIdx.x;
    if (i < NN){
        int v = iscan[i] + ps;          // rowptr[i+1]
        rowptr[i+1] = v;
        cursor[i] = v - (deg[i]+1);     // rowptr[i]
    }
    if (i == 0) rowptr[0] = 0;
}

__global__ void k_fill(const int* __restrict__ ei, int* __restrict__ cursor, int* __restrict__ csr_src){
    int idx = blockIdx.x*256 + threadIdx.x;
    if (idx >= ETOT) return;
    int s, d;
    if (idx < EE){ s = ei[idx]; d = ei[EE + idx]; }
    else         { s = idx - EE; d = s; }
    int pos = atomicAdd(&cursor[d], 1);
    csr_src[pos] = s;
}

// ---------------- layer-1 GEMM, packed operands; xl/xr written fp16, xres fp32 -------------
__global__ __launch_bounds__(256) void k_gemm1(const u16* __restrict__ Ahi, const u16* __restrict__ Alo,
        const u16* __restrict__ Whl1, const u16* __restrict__ Wll1,
        const u16* __restrict__ Whr1, const u16* __restrict__ Wlr1,
        const u16* __restrict__ Whres,const u16* __restrict__ Wlres,
        const float* __restrict__ bl1, const float* __restrict__ br1, const float* __restrict__ bres,
        u16* __restrict__ xl, u16* __restrict__ xr, float* __restrict__ xres)
{
    int b = blockIdx.x;
    int c = b & 7;
    int k = b >> 3;
    int tile = k % 9;
    int sx = c + 8*(k/9);
    if (sx >= 196) return;
    int wid = threadIdx.x >> 6, lane = threadIdx.x & 63;
    const u16 *Bh, *Bl; const float* bias; int n0;
    u16* C16 = 0; float* C32 = 0;
    if (tile < 4)      { Bh=Whl1;  Bl=Wll1;  bias=bl1;  C16=xl;   n0=tile*64; }
    else if (tile < 8) { Bh=Whr1;  Bl=Wlr1;  bias=br1;  C16=xr;   n0=(tile-4)*64; }
    else               { Bh=Whres; Bl=Wlres; bias=bres; C32=xres; n0=0; }
    int rm0 = (sx*4 + wid) * 64;
    int rblk0 = rm0 >> 4;
    int nblk0 = n0 >> 4;
    int lr = lane & 15;
    f32x4 acc[4][4] = {};
    #pragma unroll
    for (int ks = 0; ks < 4; ks++){
        short8v ah[4], al[4], bh[4], blo[4];
        #pragma unroll
        for (int mf = 0; mf < 4; mf++){
            size_t addr = ((size_t)(rblk0 + mf)*4 + ks)*512 + (size_t)lane*8;
            ah[mf] = *(const short8v*)(Ahi + addr);
            al[mf] = *(const short8v*)(Alo + addr);
        }
        #pragma unroll
        for (int nf = 0; nf < 4; nf++){
            size_t addr = ((size_t)(nblk0 + nf)*4 + ks)*512 + (size_t)lane*8;
            bh[nf]  = *(const short8v*)(Bh + addr);
            blo[nf] = *(const short8v*)(Bl + addr);
        }
        #pragma unroll
        for (int mf = 0; mf < 4; mf++)
            #pragma unroll
            for (int nf = 0; nf < 4; nf++){
                acc[mf][nf] = __builtin_amdgcn_mfma_f32_16x16x32_bf16(ah[mf], bh[nf],  acc[mf][nf], 0, 0, 0);
                acc[mf][nf] = __builtin_amdgcn_mfma_f32_16x16x32_bf16(al[mf], bh[nf],  acc[mf][nf], 0, 0, 0);
                acc[mf][nf] = __builtin_amdgcn_mfma_f32_16x16x32_bf16(ah[mf], blo[nf], acc[mf][nf], 0, 0, 0);
            }
    }
    int rbase = (lane >> 4) << 2;
    #pragma unroll
    for (int nf = 0; nf < 4; nf++){
        int col = n0 + nf*16 + lr;
        float bv = bias[col];
        #pragma unroll
        for (int mf = 0; mf < 4; mf++){
            #pragma unroll
            for (int r = 0; r < 4; r++){
                int row = rm0 + mf*16 + rbase + r;
                if (row < NN){
                    float v = acc[mf][nf][r] + bv;
                    if (tile < 8) C16[(size_t)row*256 + col] = f2h(v);
                    else          C32[(size_t)row*64  + col] = v;
                }
            }
        }
    }
}

// ---------------- layer-2 GEMM, packed operands, K=64; outputs fp16 ----------------
__global__ __launch_bounds__(256) void k_gemm2(const u16* __restrict__ Ahi, const u16* __restrict__ Alo,
        const u16* __restrict__ Whl2, const u16* __restrict__ Wll2,
        const u16* __restrict__ Whr2, const u16* __restrict__ Wlr2,
        const float* __restrict__ bl2, const float* __restrict__ br2,
        u16* __restrict__ xl, u16* __restrict__ xr)
{
    int b = blockIdx.x;
    int c = b & 7;
    int k = b >> 3;
    int tile = k & 7;
    int sx = c + 8*(k >> 3);
    if (sx >= 196) return;
    int wid = threadIdx.x >> 6, lane = threadIdx.x & 63;
    const u16 *Bh, *Bl; const float* bias; u16* Cout;
    if (tile < 4){ Bh=Whl2; Bl=Wll2; bias=bl2; Cout=xl; }
    else         { Bh=Whr2; Bl=Wlr2; bias=br2; Cout=xr; }
    int n0 = (tile & 3)*64;
    int rm0 = (sx*4 + wid) * 64;
    int rblk0 = rm0 >> 4;
    int nblk0 = n0 >> 4;
    int lr = lane & 15;
    f32x4 acc[4][4] = {};
    #pragma unroll
    for (int ks = 0; ks < 2; ks++){
        short8v ah[4], al[4], bh[4], blo[4];
        #pragma unroll
        for (int mf = 0; mf < 4; mf++){
            size_t addr = ((size_t)(rblk0 + mf)*2 + ks)*512 + (size_t)lane*8;
            ah[mf] = *(const short8v*)(Ahi + addr);
            al[mf] = *(const short8v*)(Alo + addr);
        }
        #pragma unroll
        for (int nf = 0; nf < 4; nf++){
            size_t addr = ((size_t)(nblk0 + nf)*2 + ks)*512 + (size_t)lane*8;
            bh[nf]  = *(const short8v*)(Bh + addr);
            blo[nf] = *(const short8v*)(Bl + addr);
        }
        #pragma unroll
        for (int mf = 0; mf < 4; mf++)
            #pragma unroll
            for (int nf = 0; nf < 4; nf++){
                acc[mf][nf] = __builtin_amdgcn_mfma_f32_16x16x32_bf16(ah[mf], bh[nf],  acc[mf][nf], 0, 0, 0);
                acc[mf][nf] = __builtin_amdgcn_mfma_f32_16x16x32_bf16(al[mf], bh[nf],  acc[mf][nf], 0, 0, 0);
                acc[mf][nf] = __builtin_amdgcn_mfma_f32_16x16x32_bf16(ah[mf], blo[nf], acc[mf][nf], 0, 0, 0);
            }
    }
    int rbase = (lane >> 4) << 2;
    #pragma unroll
    for (int nf = 0; nf < 4; nf++){
        int col = n0 + nf*16 + lr;
        float bv = bias[col];
        #pragma unroll
        for (int mf = 0; mf < 4; mf++){
            #pragma unroll
            for (int r = 0; r < 4; r++){
                int row = rm0 + mf*16 + rbase + r;
                if (row < NN) Cout[(size_t)row*256 + col] = f2h(acc[mf][nf][r] + bv);
            }
        }
    }
}

// ---------------- fused GATv2 aggregation (fp16 gather, no-max softmax, unroll-4) ----------
__global__ __launch_bounds__(256) void k_gat(const u16* __restrict__ xl, const u16* __restrict__ xr,
                                             const int* __restrict__ csr_src, const int* __restrict__ rowptr,
                                             const float* __restrict__ att, const float* __restrict__ bias,
                                             float* __restrict__ out)
{
    int wave = threadIdx.x >> 6, lane = threadIdx.x & 63;
    int node = blockIdx.x*4 + wave;
    if (node >= NN) return;
    int p0 = rowptr[node], p1 = rowptr[node+1];
    f32x4 xrf  = h2f4(*(const u16x4*)(xr + (size_t)node*HC + 4*lane));
    f32x4 attf = *(const f32x4*)(att + 4*lane);
    float s = 0.f;
    f32x4 acc = {0.f, 0.f, 0.f, 0.f};
    int p = p0;
    for (; p + 4 <= p1; p += 4){
        int i0 = csr_src[p], i1 = csr_src[p+1], i2 = csr_src[p+2], i3 = csr_src[p+3];
        f32x4 x0 = h2f4(*(const u16x4*)(xl + (size_t)i0*HC + 4*lane));
        f32x4 x1 = h2f4(*(const u16x4*)(xl + (size_t)i1*HC + 4*lane));
        f32x4 x2 = h2f4(*(const u16x4*)(xl + (size_t)i2*HC + 4*lane));
        f32x4 x3 = h2f4(*(const u16x4*)(xl + (size_t)i3*HC + 4*lane));
        float t0 = 0.f, t1 = 0.f, t2 = 0.f, t3 = 0.f;
        #pragma unroll
        for (int j = 0; j < 4; j++){
            float e0 = x0[j] + xrf[j]; e0 = (e0 > 0.f) ? e0 : 0.2f*e0; t0 += e0*attf[j];
            float e1 = x1[j] + xrf[j]; e1 = (e1 > 0.f) ? e1 : 0.2f*e1; t1 += e1*attf[j];
            float e2 = x2[j] + xrf[j]; e2 = (e2 > 0.f) ? e2 : 0.2f*e2; t2 += e2*attf[j];
            float e3 = x3[j] + xrf[j]; e3 = (e3 > 0.f) ? e3 : 0.2f*e3; t3 += e3*attf[j];
        }
        #pragma unroll
        for (int off = 1; off < 16; off <<= 1){
            t0 += __shfl_xor(t0, off, 64);
            t1 += __shfl_xor(t1, off, 64);
            t2 += __shfl_xor(t2, off, 64);
            t3 += __shfl_xor(t3, off, 64);
        }
        float w0 = __expf(t0), w1 = __expf(t1), w2 = __expf(t2), w3 = __expf(t3);
        s += (w0 + w1) + (w2 + w3);
        acc = acc + x0*w0 + x1*w1 + x2*w2 + x3*w3;
    }
    for (; p < p1; p++){
        int i0 = csr_src[p];
        f32x4 x0 = h2f4(*(const u16x4*)(xl + (size_t)i0*HC + 4*lane));
        float t0 = 0.f;
        #pragma unroll
        for (int j = 0; j < 4; j++){ float e0 = x0[j] + xrf[j]; e0 = (e0 > 0.f) ? e0 : 0.2f*e0; t0 += e0*attf[j]; }
        #pragma unroll
        for (int off = 1; off < 16; off <<= 1) t0 += __shfl_xor(t0, off, 64);
        float w0 = __expf(t0);
        s += w0;
        acc = acc + x0*w0;
    }
    float inv = 1.f / s;
    f32x4 o = acc * inv;
    #pragma unroll
    for (int j = 0; j < 4; j++){ o[j] += __shfl_xor(o[j], 16, 64); o[j] += __shfl_xor(o[j], 32, 64); }
    if (lane < 16){
        f32x4 bv = *(const f32x4*)(bias + 4*lane);
        f32x4 res = o*0.25f + bv;
        *(f32x4*)(out + (size_t)node*CC + 4*lane) = res;
    }
}

// ---------------- BatchNorm stats ----------------
__global__ __launch_bounds__(256) void k_bnstats(const float* __restrict__ x, float* __restrict__ sums){
    __shared__ float ls[256], lq[256];
    int tid = threadIdx.x; int c = tid & 63; int g = tid >> 6;
    float s = 0.f, q = 0.f;
    for (int r = blockIdx.x*4 + g; r < NN; r += gridDim.x*4){
        float v = x[(size_t)r*64 + c]; s += v; q += v*v;
    }
    ls[tid] = s; lq[tid] = q; __syncthreads();
    if (tid < 64){
        s = ls[tid] + ls[tid+64] + ls[tid+128] + ls[tid+192];
        q = lq[tid] + lq[tid+64] + lq[tid+128] + lq[tid+192];
        atomicAdd(&sums[c], s); atomicAdd(&sums[64 + c], q);
    }
}

// h = relu(bn(hraw) + xres); writes fp32 h + packed hi/lo bf16 (K=64 layout) for layer-2 A
__global__ void k_post1(const float* __restrict__ hraw, const float* __restrict__ xres,
                        const float* __restrict__ sums, const float* __restrict__ g,
                        const float* __restrict__ b, float* __restrict__ out,
                        u16* __restrict__ hhi, u16* __restrict__ hlo){
    int i = blockIdx.x*256 + threadIdx.x;   // float4 index
    if (i >= NN*16) return;
    float4 hv = ((const float4*)hraw)[i];
    float4 rv = ((const float4*)xres)[i];
    int row = i >> 4;
    int c0 = (i & 15) * 4;
    float hp[4] = {hv.x, hv.y, hv.z, hv.w};
    float rp[4] = {rv.x, rv.y, rv.z, rv.w};
    float res[4];
    u16x4 h4, l4;
    const float invN = 1.f / (float)NN;
    #pragma unroll
    for (int k = 0; k < 4; k++){
        int c = c0 + k;
        float mean = sums[c] * invN;
        float var  = sums[64 + c] * invN - mean*mean;
        float rstd = rsqrtf(var + 1e-5f);
        float v = g[c]*(hp[k] - mean)*rstd + b[c] + rp[k];
        v = (v > 0.f) ? v : 0.f;
        res[k] = v;
        u16 h = f2b(v);
        h4[k] = h;
        l4[k] = f2b(v - b2f(h));
    }
    ((float4*)out)[i] = make_float4(res[0], res[1], res[2], res[3]);
    size_t blk = (size_t)(row >> 4)*2 + (c0 >> 5);
    size_t addr = blk*512 + (size_t)((row & 15) + 16*((c0 >> 3) & 3))*8 + (c0 & 7);
    *(u16x4*)(hhi + addr) = h4;
    *(u16x4*)(hlo + addr) = l4;
}

// z = bn(h2raw) + h, written fp16 (consumed only by k_score)
__global__ void k_post2(const float* __restrict__ hraw, const float* __restrict__ hprev,
                        const float* __restrict__ sums, const float* __restrict__ g,
                        const float* __restrict__ b, u16* __restrict__ zout){
    int i = blockIdx.x*256 + threadIdx.x;
    if (i >= NN*16) return;
    float4 hv = ((const float4*)hraw)[i];
    float4 rv = ((const float4*)hprev)[i];
    int c0 = (i & 15) * 4;
    float hp[4] = {hv.x, hv.y, hv.z, hv.w};
    float rp[4] = {rv.x, rv.y, rv.z, rv.w};
    u16x4 res;
    const float invN = 1.f / (float)NN;
    #pragma unroll
    for (int k = 0; k < 4; k++){
        int c = c0 + k;
        float mean = sums[c] * invN;
        float var  = sums[64 + c] * invN - mean*mean;
        float rstd = rsqrtf(var + 1e-5f);
        res[k] = f2h(g[c]*(hp[k] - mean)*rstd + b[c] + rp[k]);
    }
    *(u16x4*)(zout + (size_t)i*4) = res;
}

// ---------------- link-prediction scores (fp16 z gather) ----------------
__global__ __launch_bounds__(256) void k_score(const u16* __restrict__ z, const int* __restrict__ eli,
                                               float* __restrict__ out){
    int t = blockIdx.x*256 + threadIdx.x;
    int i = t >> 4; int j = t & 15;
    if (i >= ELI_N) return;
    int a = eli[i], b = eli[ELI_N + i];
    f32x4 va = h2f4(*(const u16x4*)(z + (size_t)a*64 + j*4));
    f32x4 vb = h2f4(*(const u16x4*)(z + (size_t)b*64 + j*4));
    float s = va[0]*vb[0] + va[1]*vb[1] + va[2]*vb[2] + va[3]*vb[3];
    #pragma unroll
    for (int off = 8; off > 0; off >>= 1) s += __shfl_xor(s, off, 64);
    if (j == 0) out[i] = 1.f / (1.f + __expf(-s));
}

extern "C" void kernel_launch(void* const* d_in, const int* in_sizes, int n_in,
                              void* d_out, int out_size, void* d_ws, size_t ws_size,
                              hipStream_t stream) {
    const float* x    = (const float*)d_in[0];
    const int*   ei   = (const int*)  d_in[1];
    const int*   eli  = (const int*)  d_in[2];
    const float* Wl1  = (const float*)d_in[3];
    const float* bl1  = (const float*)d_in[4];
    const float* Wr1  = (const float*)d_in[5];
    const float* br1  = (const float*)d_in[6];
    const float* att1 = (const float*)d_in[7];
    const float* bias1= (const float*)d_in[8];
    const float* g1   = (const float*)d_in[9];
    const float* b1   = (const float*)d_in[10];
    const float* Wres = (const float*)d_in[11];
    const float* bres = (const float*)d_in[12];
    const float* Wl2  = (const float*)d_in[13];
    const float* bl2  = (const float*)d_in[14];
    const float* Wr2  = (const float*)d_in[15];
    const float* br2  = (const float*)d_in[16];
    const float* att2 = (const float*)d_in[17];
    const float* bias2= (const float*)d_in[18];
    const float* g2   = (const float*)d_in[19];
    const float* b2   = (const float*)d_in[20];
    float* out = (float*)d_out;

    char* w = (char*)d_ws;
    size_t o = 0;
    auto take = [&](size_t bytes)->char*{ char* p = w + o; o += (bytes + 255) & ~(size_t)255; return p; };
    u16*  xl   = (u16*) take((size_t)NN*HC*2);     // fp16 gather tables
    u16*  xr   = (u16*) take((size_t)NN*HC*2);
    float* xres = (float*)take((size_t)NN*CC*4);
    float* hraw = (float*)take((size_t)NN*CC*4);
    float* hbuf = (float*)take((size_t)NN*CC*4);
    u16*  z16  = (u16*) take((size_t)NN*CC*2);     // fp16 z for score
    u16*  xhi  = (u16*)take((size_t)MPAD*INC*2);   // packed fragment layout
    u16*  xlo  = (u16*)take((size_t)MPAD*INC*2);
    u16*  hhi  = (u16*)take((size_t)MPAD*CC*2);
    u16*  hlo  = (u16*)take((size_t)MPAD*CC*2);
    u16* whl1 = (u16*)take(256*128*2);  u16* wll1 = (u16*)take(256*128*2);
    u16* whr1 = (u16*)take(256*128*2);  u16* wlr1 = (u16*)take(256*128*2);
    u16* whres= (u16*)take(64*128*2);   u16* wlres= (u16*)take(64*128*2);
    u16* whl2 = (u16*)take(256*64*2);   u16* wll2 = (u16*)take(256*64*2);
    u16* whr2 = (u16*)take(256*64*2);   u16* wlr2 = (u16*)take(256*64*2);
    char* zreg  = take(256*4 + (size_t)NN*4);
    float* stats= (float*)zreg;
    int* deg    = (int*)(zreg + 256*4);
    int* rowptr = (int*)take((size_t)(NN+1)*4);
    int* iscan  = (int*)take((size_t)NN*4);
    int* cursor = (int*)take((size_t)NN*4);
    int* csr_src= (int*)take((size_t)ETOT*4);
    int* part   = (int*)take(64*4);

    hipMemsetAsync(zreg, 0, 256*4 + (size_t)NN*4, stream);

    // fused setup: x split (packed) | weight conv (packed) | degree count
    k_setup<<<5104, 256, 0, stream>>>(x, ei, Wl1, Wr1, Wres, Wl2, Wr2,
                                      xhi, xlo,
                                      whl1, wll1, whr1, wlr1, whres, wlres,
                                      whl2, wll2, whr2, wlr2, deg);

    // CSR build
    k_scanA<<<49, 256, 0, stream>>>(deg, iscan, part);
    k_scanC<<<196, 256, 0, stream>>>(iscan, part, deg, rowptr, cursor);
    k_fill<<<(ETOT+255)/256, 256, 0, stream>>>(ei, cursor, csr_src);

    // layer 1
    k_gemm1<<<1800, 256, 0, stream>>>(xhi, xlo, whl1, wll1, whr1, wlr1, whres, wlres,
                                      bl1, br1, bres, xl, xr, xres);
    k_gat<<<(NN+3)/4, 256, 0, stream>>>(xl, xr, csr_src, rowptr, att1, bias1, hraw);
    k_bnstats<<<256, 256, 0, stream>>>(hraw, stats);
    k_post1<<<(NN*16+255)/256, 256, 0, stream>>>(hraw, xres, stats, g1, b1, hbuf, hhi, hlo);

    // layer 2
    k_gemm2<<<1600, 256, 0, stream>>>(hhi, hlo, whl2, wll2, whr2, wlr2, bl2, br2, xl, xr);
    k_gat<<<(NN+3)/4, 256, 0, stream>>>(xl, xr, csr_src, rowptr, att2, bias2, hraw);
    k_bnstats<<<256, 256, 0, stream>>>(hraw, stats + 128);
    k_post2<<<(NN*16+255)/256, 256, 0, stream>>>(hraw, hbuf, stats + 128, g2, b2, z16);

    // scores
    k_score<<<(ELI_N*16+255)/256, 256, 0, stream>>>(z16, eli, out);
}

// Round 12
// 291.642 us; speedup vs baseline: 1.5206x; 1.0678x over previous
//
#include <hip/hip_runtime.h>
#include <math.h>

#define NN 50000
#define EE 400000
#define ETOT 450000
#define INC 128
#define CC 64
#define HC 256
#define ELI_N 200000
#define MPAD 50176   // 196*256; 3136 row-blocks of 16
#define GB1 1800     // gemm1 GEMM blocks; fill blocks appended after
#define FILLB ((ETOT + 255) / 256)

typedef unsigned short u16;
typedef __attribute__((ext_vector_type(8))) short short8v;
typedef __attribute__((ext_vector_type(8))) unsigned short u16x8;
typedef __attribute__((ext_vector_type(4))) float f32x4;
typedef __attribute__((ext_vector_type(4))) unsigned short u16x4;

__device__ __forceinline__ u16 f2b(float v){
    unsigned u = __float_as_uint(v);
    u = (u + 0x7fffu + ((u >> 16) & 1u)) >> 16;   // RNE
    return (u16)u;
}
__device__ __forceinline__ float b2f(u16 h){
    return __uint_as_float(((unsigned)h) << 16);
}
__device__ __forceinline__ u16 f2h(float v){
    _Float16 h = (_Float16)v; u16 r; __builtin_memcpy(&r, &h, 2); return r;
}
__device__ __forceinline__ float h2f(u16 h){
    _Float16 x; __builtin_memcpy(&x, &h, 2); return (float)x;
}
__device__ __forceinline__ f32x4 h2f4(u16x4 r){
    f32x4 o; o[0]=h2f(r[0]); o[1]=h2f(r[1]); o[2]=h2f(r[2]); o[3]=h2f(r[3]); return o;
}

// ---------------- fused setup: splitX (packed) | convW (packed) | edge count ----------------
__global__ void k_setup(const float* __restrict__ x, const int* __restrict__ ei,
                        const float* __restrict__ Wl1, const float* __restrict__ Wr1,
                        const float* __restrict__ Wres, const float* __restrict__ Wl2,
                        const float* __restrict__ Wr2,
                        u16* __restrict__ xhi, u16* __restrict__ xlo,
                        u16* __restrict__ hl1, u16* __restrict__ ll1,
                        u16* __restrict__ hr1, u16* __restrict__ lr1,
                        u16* __restrict__ hres, u16* __restrict__ lres,
                        u16* __restrict__ hl2, u16* __restrict__ ll2,
                        u16* __restrict__ hr2, u16* __restrict__ lr2,
                        int* __restrict__ deg){
    int gid = blockIdx.x*256 + threadIdx.x;
    if (gid < 800000){
        int row = gid >> 4;
        int k0  = (gid & 15) * 8;
        const float* ap = x + (size_t)row*128 + k0;
        float4 v0 = *(const float4*)ap;
        float4 v1 = *(const float4*)(ap + 4);
        float vv[8] = {v0.x, v0.y, v0.z, v0.w, v1.x, v1.y, v1.z, v1.w};
        u16x8 h8, l8;
        #pragma unroll
        for (int j = 0; j < 8; j++){
            u16 h = f2b(vv[j]);
            h8[j] = h;
            l8[j] = f2b(vv[j] - b2f(h));
        }
        size_t blk = (size_t)(row >> 4)*4 + (k0 >> 5);
        size_t addr = blk*512 + (size_t)((row & 15) + 16*((k0 >> 3) & 3))*8;
        *(u16x8*)(xhi + addr) = h8;
        *(u16x8*)(xlo + addr) = l8;
    } else if (gid < 906496){
        int g = gid - 800000;
        const float* src; u16* dh; u16* dl; int K, N, idx;
        if      (g <  32768){ src=Wl1;  dh=hl1;  dl=ll1;  K=128; N=256; idx=g; }
        else if (g <  65536){ src=Wr1;  dh=hr1;  dl=lr1;  K=128; N=256; idx=g-32768; }
        else if (g <  73728){ src=Wres; dh=hres; dl=lres; K=128; N=64;  idx=g-65536; }
        else if (g <  90112){ src=Wl2;  dh=hl2;  dl=ll2;  K=64;  N=256; idx=g-73728; }
        else                { src=Wr2;  dh=hr2;  dl=lr2;  K=64;  N=256; idx=g-90112; }
        int k = idx / N, n = idx - k*N;
        float v = src[idx];
        u16 h = f2b(v);
        size_t blk = (size_t)(n >> 4)*(K >> 5) + (k >> 5);
        size_t addr = blk*512 + (size_t)((n & 15) + 16*((k >> 3) & 3))*8 + (k & 7);
        dh[addr] = h;
        dl[addr] = f2b(v - b2f(h));
    } else if (gid < 1306496){
        int e = gid - 906496;
        atomicAdd(&deg[ei[EE + e]], 1);
    }
}

// ---------------- CSR build ----------------
__global__ void k_scanA(const int* __restrict__ deg, int* __restrict__ iscan, int* __restrict__ part){
    __shared__ int sh[256];
    int tid = threadIdx.x;
    int base = blockIdx.x*1024 + tid*4;
    int v[4]; int t = 0;
    #pragma unroll
    for (int i = 0; i < 4; i++){ int idx = base + i; v[i] = (idx < NN) ? deg[idx]+1 : 0; t += v[i]; }
    sh[tid] = t; __syncthreads();
    for (int off = 1; off < 256; off <<= 1){
        int u = (tid >= off) ? sh[tid - off] : 0;
        __syncthreads();
        sh[tid] += u;
        __syncthreads();
    }
    int incl = sh[tid];
    int run = incl - t;
    #pragma unroll
    for (int i = 0; i < 4; i++){
        run += v[i];
        int idx = base + i;
        if (idx < NN) iscan[idx] = run;
    }
    if (tid == 255) part[blockIdx.x] = incl;
}

__global__ void k_scanC(const int* __restrict__ iscan, const int* __restrict__ part,
                        const int* __restrict__ deg, int* __restrict__ rowptr, int* __restrict__ cursor){
    int chunk = blockIdx.x >> 2;
    int ps = 0;
    for (int j = 0; j < chunk; j++) ps += part[j];
    int i = blockIdx.x*256 + threadIdx.x;
    if (i < NN){
        int v = iscan[i] + ps;          // rowptr[i+1]
        rowptr[i+1] = v;
        cursor[i] = v - (deg[i]+1);     // rowptr[i]
    }
    if (i == 0) rowptr[0] = 0;
}

// ---------------- layer-1 GEMM (+appended CSR-fill blocks) ----------------
__global__ __launch_bounds__(256) void k_gemm1(const u16* __restrict__ Ahi, const u16* __restrict__ Alo,
        const u16* __restrict__ Whl1, const u16* __restrict__ Wll1,
        const u16* __restrict__ Whr1, const u16* __restrict__ Wlr1,
        const u16* __restrict__ Whres,const u16* __restrict__ Wlres,
        const float* __restrict__ bl1, const float* __restrict__ br1, const float* __restrict__ bres,
        u16* __restrict__ xl, u16* __restrict__ xr, float* __restrict__ xres,
        const int* __restrict__ ei, int* __restrict__ cursor, int* __restrict__ csr_src)
{
    int b = blockIdx.x;
    if (b >= GB1){
        // CSR fill
        int idx = (b - GB1)*256 + threadIdx.x;
        if (idx < ETOT){
            int s, d;
            if (idx < EE){ s = ei[idx]; d = ei[EE + idx]; }
            else         { s = idx - EE; d = s; }
            int pos = atomicAdd(&cursor[d], 1);
            csr_src[pos] = s;
        }
        return;
    }
    int c = b & 7;
    int k = b >> 3;
    int tile = k % 9;
    int sx = c + 8*(k/9);
    if (sx >= 196) return;
    int wid = threadIdx.x >> 6, lane = threadIdx.x & 63;
    const u16 *Bh, *Bl; const float* bias; int n0;
    u16* C16 = 0; float* C32 = 0;
    if (tile < 4)      { Bh=Whl1;  Bl=Wll1;  bias=bl1;  C16=xl;   n0=tile*64; }
    else if (tile < 8) { Bh=Whr1;  Bl=Wlr1;  bias=br1;  C16=xr;   n0=(tile-4)*64; }
    else               { Bh=Whres; Bl=Wlres; bias=bres; C32=xres; n0=0; }
    int rm0 = (sx*4 + wid) * 64;
    int rblk0 = rm0 >> 4;
    int nblk0 = n0 >> 4;
    int lr = lane & 15;
    f32x4 acc[4][4] = {};
    #pragma unroll
    for (int ks = 0; ks < 4; ks++){
        short8v ah[4], al[4], bh[4], blo[4];
        #pragma unroll
        for (int mf = 0; mf < 4; mf++){
            size_t addr = ((size_t)(rblk0 + mf)*4 + ks)*512 + (size_t)lane*8;
            ah[mf] = *(const short8v*)(Ahi + addr);
            al[mf] = *(const short8v*)(Alo + addr);
        }
        #pragma unroll
        for (int nf = 0; nf < 4; nf++){
            size_t addr = ((size_t)(nblk0 + nf)*4 + ks)*512 + (size_t)lane*8;
            bh[nf]  = *(const short8v*)(Bh + addr);
            blo[nf] = *(const short8v*)(Bl + addr);
        }
        #pragma unroll
        for (int mf = 0; mf < 4; mf++)
            #pragma unroll
            for (int nf = 0; nf < 4; nf++){
                acc[mf][nf] = __builtin_amdgcn_mfma_f32_16x16x32_bf16(ah[mf], bh[nf],  acc[mf][nf], 0, 0, 0);
                acc[mf][nf] = __builtin_amdgcn_mfma_f32_16x16x32_bf16(al[mf], bh[nf],  acc[mf][nf], 0, 0, 0);
                acc[mf][nf] = __builtin_amdgcn_mfma_f32_16x16x32_bf16(ah[mf], blo[nf], acc[mf][nf], 0, 0, 0);
            }
    }
    int rbase = (lane >> 4) << 2;
    #pragma unroll
    for (int nf = 0; nf < 4; nf++){
        int col = n0 + nf*16 + lr;
        float bv = bias[col];
        #pragma unroll
        for (int mf = 0; mf < 4; mf++){
            #pragma unroll
            for (int r = 0; r < 4; r++){
                int row = rm0 + mf*16 + rbase + r;
                if (row < NN){
                    float v = acc[mf][nf][r] + bv;
                    if (tile < 8) C16[(size_t)row*256 + col] = f2h(v);
                    else          C32[(size_t)row*64  + col] = v;
                }
            }
        }
    }
}

// ---------------- layer-2 GEMM, packed operands, K=64; outputs fp16 ----------------
__global__ __launch_bounds__(256) void k_gemm2(const u16* __restrict__ Ahi, const u16* __restrict__ Alo,
        const u16* __restrict__ Whl2, const u16* __restrict__ Wll2,
        const u16* __restrict__ Whr2, const u16* __restrict__ Wlr2,
        const float* __restrict__ bl2, const float* __restrict__ br2,
        u16* __restrict__ xl, u16* __restrict__ xr)
{
    int b = blockIdx.x;
    int c = b & 7;
    int k = b >> 3;
    int tile = k & 7;
    int sx = c + 8*(k >> 3);
    if (sx >= 196) return;
    int wid = threadIdx.x >> 6, lane = threadIdx.x & 63;
    const u16 *Bh, *Bl; const float* bias; u16* Cout;
    if (tile < 4){ Bh=Whl2; Bl=Wll2; bias=bl2; Cout=xl; }
    else         { Bh=Whr2; Bl=Wlr2; bias=br2; Cout=xr; }
    int n0 = (tile & 3)*64;
    int rm0 = (sx*4 + wid) * 64;
    int rblk0 = rm0 >> 4;
    int nblk0 = n0 >> 4;
    int lr = lane & 15;
    f32x4 acc[4][4] = {};
    #pragma unroll
    for (int ks = 0; ks < 2; ks++){
        short8v ah[4], al[4], bh[4], blo[4];
        #pragma unroll
        for (int mf = 0; mf < 4; mf++){
            size_t addr = ((size_t)(rblk0 + mf)*2 + ks)*512 + (size_t)lane*8;
            ah[mf] = *(const short8v*)(Ahi + addr);
            al[mf] = *(const short8v*)(Alo + addr);
        }
        #pragma unroll
        for (int nf = 0; nf < 4; nf++){
            size_t addr = ((size_t)(nblk0 + nf)*2 + ks)*512 + (size_t)lane*8;
            bh[nf]  = *(const short8v*)(Bh + addr);
            blo[nf] = *(const short8v*)(Bl + addr);
        }
        #pragma unroll
        for (int mf = 0; mf < 4; mf++)
            #pragma unroll
            for (int nf = 0; nf < 4; nf++){
                acc[mf][nf] = __builtin_amdgcn_mfma_f32_16x16x32_bf16(ah[mf], bh[nf],  acc[mf][nf], 0, 0, 0);
                acc[mf][nf] = __builtin_amdgcn_mfma_f32_16x16x32_bf16(al[mf], bh[nf],  acc[mf][nf], 0, 0, 0);
                acc[mf][nf] = __builtin_amdgcn_mfma_f32_16x16x32_bf16(ah[mf], blo[nf], acc[mf][nf], 0, 0, 0);
            }
    }
    int rbase = (lane >> 4) << 2;
    #pragma unroll
    for (int nf = 0; nf < 4; nf++){
        int col = n0 + nf*16 + lr;
        float bv = bias[col];
        #pragma unroll
        for (int mf = 0; mf < 4; mf++){
            #pragma unroll
            for (int r = 0; r < 4; r++){
                int row = rm0 + mf*16 + rbase + r;
                if (row < NN) Cout[(size_t)row*256 + col] = f2h(acc[mf][nf][r] + bv);
            }
        }
    }
}

// ---------------- fused GATv2 aggregation + BN partial stats ----------------
// grid = NN/4 exactly (12500); 64 partial stat buffers [64][64]
__global__ __launch_bounds__(256) void k_gat(const u16* __restrict__ xl, const u16* __restrict__ xr,
                                             const int* __restrict__ csr_src, const int* __restrict__ rowptr,
                                             const float* __restrict__ att, const float* __restrict__ bias,
                                             float* __restrict__ out,
                                             float* __restrict__ part_s, float* __restrict__ part_q)
{
    __shared__ float ls[4][64];
    __shared__ float lq[4][64];
    int wave = threadIdx.x >> 6, lane = threadIdx.x & 63;
    int node = blockIdx.x*4 + wave;
    int p0 = rowptr[node], p1 = rowptr[node+1];
    f32x4 xrf  = h2f4(*(const u16x4*)(xr + (size_t)node*HC + 4*lane));
    f32x4 attf = *(const f32x4*)(att + 4*lane);
    float s = 0.f;
    f32x4 acc = {0.f, 0.f, 0.f, 0.f};
    int p = p0;
    for (; p + 4 <= p1; p += 4){
        int i0 = csr_src[p], i1 = csr_src[p+1], i2 = csr_src[p+2], i3 = csr_src[p+3];
        f32x4 x0 = h2f4(*(const u16x4*)(xl + (size_t)i0*HC + 4*lane));
        f32x4 x1 = h2f4(*(const u16x4*)(xl + (size_t)i1*HC + 4*lane));
        f32x4 x2 = h2f4(*(const u16x4*)(xl + (size_t)i2*HC + 4*lane));
        f32x4 x3 = h2f4(*(const u16x4*)(xl + (size_t)i3*HC + 4*lane));
        float t0 = 0.f, t1 = 0.f, t2 = 0.f, t3 = 0.f;
        #pragma unroll
        for (int j = 0; j < 4; j++){
            float e0 = x0[j] + xrf[j]; e0 = (e0 > 0.f) ? e0 : 0.2f*e0; t0 += e0*attf[j];
            float e1 = x1[j] + xrf[j]; e1 = (e1 > 0.f) ? e1 : 0.2f*e1; t1 += e1*attf[j];
            float e2 = x2[j] + xrf[j]; e2 = (e2 > 0.f) ? e2 : 0.2f*e2; t2 += e2*attf[j];
            float e3 = x3[j] + xrf[j]; e3 = (e3 > 0.f) ? e3 : 0.2f*e3; t3 += e3*attf[j];
        }
        #pragma unroll
        for (int off = 1; off < 16; off <<= 1){
            t0 += __shfl_xor(t0, off, 64);
            t1 += __shfl_xor(t1, off, 64);
            t2 += __shfl_xor(t2, off, 64);
            t3 += __shfl_xor(t3, off, 64);
        }
        float w0 = __expf(t0), w1 = __expf(t1), w2 = __expf(t2), w3 = __expf(t3);
        s += (w0 + w1) + (w2 + w3);
        acc = acc + x0*w0 + x1*w1 + x2*w2 + x3*w3;
    }
    for (; p < p1; p++){
        int i0 = csr_src[p];
        f32x4 x0 = h2f4(*(const u16x4*)(xl + (size_t)i0*HC + 4*lane));
        float t0 = 0.f;
        #pragma unroll
        for (int j = 0; j < 4; j++){ float e0 = x0[j] + xrf[j]; e0 = (e0 > 0.f) ? e0 : 0.2f*e0; t0 += e0*attf[j]; }
        #pragma unroll
        for (int off = 1; off < 16; off <<= 1) t0 += __shfl_xor(t0, off, 64);
        float w0 = __expf(t0);
        s += w0;
        acc = acc + x0*w0;
    }
    float inv = 1.f / s;
    f32x4 o = acc * inv;
    #pragma unroll
    for (int j = 0; j < 4; j++){ o[j] += __shfl_xor(o[j], 16, 64); o[j] += __shfl_xor(o[j], 32, 64); }
    if (lane < 16){
        f32x4 bv = *(const f32x4*)(bias + 4*lane);
        f32x4 res = o*0.25f + bv;
        *(f32x4*)(out + (size_t)node*CC + 4*lane) = res;
        #pragma unroll
        for (int j = 0; j < 4; j++){
            ls[wave][4*lane + j] = res[j];
            lq[wave][4*lane + j] = res[j]*res[j];
        }
    }
    __syncthreads();
    int tid = threadIdx.x;
    if (tid < 128){
        int c = tid & 63;
        if (tid < 64){
            float v = (ls[0][c] + ls[1][c]) + (ls[2][c] + ls[3][c]);
            atomicAdd(&part_s[(blockIdx.x & 63)*64 + c], v);
        } else {
            float v = (lq[0][c] + lq[1][c]) + (lq[2][c] + lq[3][c]);
            atomicAdd(&part_q[(blockIdx.x & 63)*64 + c], v);
        }
    }
}

// h = relu(bn(hraw) + xres); inline 64-buffer stat reduce; writes fp32 h + packed bf16 hi/lo
__global__ __launch_bounds__(256) void k_post1(const float* __restrict__ hraw, const float* __restrict__ xres,
                        const float* __restrict__ part_s, const float* __restrict__ part_q,
                        const float* __restrict__ g, const float* __restrict__ b,
                        float* __restrict__ out, u16* __restrict__ hhi, u16* __restrict__ hlo){
    __shared__ float red[128];
    int tid = threadIdx.x;
    if (tid < 128){
        const float* base = (tid < 64) ? part_s : part_q;
        int c = tid & 63;
        float sv = 0.f;
        for (int bb = 0; bb < 64; bb++) sv += base[bb*64 + c];
        red[tid] = sv;
    }
    __syncthreads();
    int i = blockIdx.x*256 + tid;   // float4 index
    if (i >= NN*16) return;
    float4 hv = ((const float4*)hraw)[i];
    float4 rv = ((const float4*)xres)[i];
    int row = i >> 4;
    int c0 = (i & 15) * 4;
    float hp[4] = {hv.x, hv.y, hv.z, hv.w};
    float rp[4] = {rv.x, rv.y, rv.z, rv.w};
    float res[4];
    u16x4 h4, l4;
    const float invN = 1.f / (float)NN;
    #pragma unroll
    for (int k = 0; k < 4; k++){
        int c = c0 + k;
        float mean = red[c] * invN;
        float var  = red[64 + c] * invN - mean*mean;
        float rstd = rsqrtf(var + 1e-5f);
        float v = g[c]*(hp[k] - mean)*rstd + b[c] + rp[k];
        v = (v > 0.f) ? v : 0.f;
        res[k] = v;
        u16 h = f2b(v);
        h4[k] = h;
        l4[k] = f2b(v - b2f(h));
    }
    ((float4*)out)[i] = make_float4(res[0], res[1], res[2], res[3]);
    size_t blk = (size_t)(row >> 4)*2 + (c0 >> 5);
    size_t addr = blk*512 + (size_t)((row & 15) + 16*((c0 >> 3) & 3))*8 + (c0 & 7);
    *(u16x4*)(hhi + addr) = h4;
    *(u16x4*)(hlo + addr) = l4;
}

// z = bn(h2raw) + h, fp16; inline stat reduce
__global__ __launch_bounds__(256) void k_post2(const float* __restrict__ hraw, const float* __restrict__ hprev,
                        const float* __restrict__ part_s, const float* __restrict__ part_q,
                        const float* __restrict__ g, const float* __restrict__ b,
                        u16* __restrict__ zout){
    __shared__ float red[128];
    int tid = threadIdx.x;
    if (tid < 128){
        const float* base = (tid < 64) ? part_s : part_q;
        int c = tid & 63;
        float sv = 0.f;
        for (int bb = 0; bb < 64; bb++) sv += base[bb*64 + c];
        red[tid] = sv;
    }
    __syncthreads();
    int i = blockIdx.x*256 + tid;
    if (i >= NN*16) return;
    float4 hv = ((const float4*)hraw)[i];
    float4 rv = ((const float4*)hprev)[i];
    int c0 = (i & 15) * 4;
    float hp[4] = {hv.x, hv.y, hv.z, hv.w};
    float rp[4] = {rv.x, rv.y, rv.z, rv.w};
    u16x4 res;
    const float invN = 1.f / (float)NN;
    #pragma unroll
    for (int k = 0; k < 4; k++){
        int c = c0 + k;
        float mean = red[c] * invN;
        float var  = red[64 + c] * invN - mean*mean;
        float rstd = rsqrtf(var + 1e-5f);
        res[k] = f2h(g[c]*(hp[k] - mean)*rstd + b[c] + rp[k]);
    }
    *(u16x4*)(zout + (size_t)i*4) = res;
}

// ---------------- link-prediction scores (fp16 z gather) ----------------
__global__ __launch_bounds__(256) void k_score(const u16* __restrict__ z, const int* __restrict__ eli,
                                               float* __restrict__ out){
    int t = blockIdx.x*256 + threadIdx.x;
    int i = t >> 4; int j = t & 15;
    if (i >= ELI_N) return;
    int a = eli[i], b = eli[ELI_N + i];
    f32x4 va = h2f4(*(const u16x4*)(z + (size_t)a*64 + j*4));
    f32x4 vb = h2f4(*(const u16x4*)(z + (size_t)b*64 + j*4));
    float s = va[0]*vb[0] + va[1]*vb[1] + va[2]*vb[2] + va[3]*vb[3];
    #pragma unroll
    for (int off = 8; off > 0; off >>= 1) s += __shfl_xor(s, off, 64);
    if (j == 0) out[i] = 1.f / (1.f + __expf(-s));
}

extern "C" void kernel_launch(void* const* d_in, const int* in_sizes, int n_in,
                              void* d_out, int out_size, void* d_ws, size_t ws_size,
                              hipStream_t stream) {
    const float* x    = (const float*)d_in[0];
    const int*   ei   = (const int*)  d_in[1];
    const int*   eli  = (const int*)  d_in[2];
    const float* Wl1  = (const float*)d_in[3];
    const float* bl1  = (const float*)d_in[4];
    const float* Wr1  = (const float*)d_in[5];
    const float* br1  = (const float*)d_in[6];
    const float* att1 = (const float*)d_in[7];
    const float* bias1= (const float*)d_in[8];
    const float* g1   = (const float*)d_in[9];
    const float* b1   = (const float*)d_in[10];
    const float* Wres = (const float*)d_in[11];
    const float* bres = (const float*)d_in[12];
    const float* Wl2  = (const float*)d_in[13];
    const float* bl2  = (const float*)d_in[14];
    const float* Wr2  = (const float*)d_in[15];
    const float* br2  = (const float*)d_in[16];
    const float* att2 = (const float*)d_in[17];
    const float* bias2= (const float*)d_in[18];
    const float* g2   = (const float*)d_in[19];
    const float* b2   = (const float*)d_in[20];
    float* out = (float*)d_out;

    char* w = (char*)d_ws;
    size_t o = 0;
    auto take = [&](size_t bytes)->char*{ char* p = w + o; o += (bytes + 255) & ~(size_t)255; return p; };
    u16*  xl   = (u16*) take((size_t)NN*HC*2);     // fp16 gather tables
    u16*  xr   = (u16*) take((size_t)NN*HC*2);
    float* xres = (float*)take((size_t)NN*CC*4);
    float* hraw = (float*)take((size_t)NN*CC*4);
    float* hbuf = (float*)take((size_t)NN*CC*4);
    u16*  z16  = (u16*) take((size_t)NN*CC*2);     // fp16 z for score
    u16*  xhi  = (u16*)take((size_t)MPAD*INC*2);   // packed fragment layout
    u16*  xlo  = (u16*)take((size_t)MPAD*INC*2);
    u16*  hhi  = (u16*)take((size_t)MPAD*CC*2);
    u16*  hlo  = (u16*)take((size_t)MPAD*CC*2);
    u16* whl1 = (u16*)take(256*128*2);  u16* wll1 = (u16*)take(256*128*2);
    u16* whr1 = (u16*)take(256*128*2);  u16* wlr1 = (u16*)take(256*128*2);
    u16* whres= (u16*)take(64*128*2);   u16* wlres= (u16*)take(64*128*2);
    u16* whl2 = (u16*)take(256*64*2);   u16* wll2 = (u16*)take(256*64*2);
    u16* whr2 = (u16*)take(256*64*2);   u16* wlr2 = (u16*)take(256*64*2);
    // zeroed region: 4 partial-stat buffers (64x64 each) + deg
    char* zreg  = take(4*64*64*4 + (size_t)NN*4);
    float* ps1  = (float*)zreg;
    float* pq1  = ps1 + 4096;
    float* ps2  = ps1 + 8192;
    float* pq2  = ps1 + 12288;
    int* deg    = (int*)(zreg + 4*64*64*4);
    int* rowptr = (int*)take((size_t)(NN+1)*4);
    int* iscan  = (int*)take((size_t)NN*4);
    int* cursor = (int*)take((size_t)NN*4);
    int* csr_src= (int*)take((size_t)ETOT*4);
    int* part   = (int*)take(64*4);

    hipMemsetAsync(zreg, 0, 4*64*64*4 + (size_t)NN*4, stream);

    // fused setup: x split (packed) | weight conv (packed) | degree count
    k_setup<<<5104, 256, 0, stream>>>(x, ei, Wl1, Wr1, Wres, Wl2, Wr2,
                                      xhi, xlo,
                                      whl1, wll1, whr1, wlr1, whres, wlres,
                                      whl2, wll2, whr2, wlr2, deg);

    // CSR scan
    k_scanA<<<49, 256, 0, stream>>>(deg, iscan, part);
    k_scanC<<<196, 256, 0, stream>>>(iscan, part, deg, rowptr, cursor);

    // layer 1 GEMM + CSR fill (appended blocks)
    k_gemm1<<<GB1 + FILLB, 256, 0, stream>>>(xhi, xlo, whl1, wll1, whr1, wlr1, whres, wlres,
                                             bl1, br1, bres, xl, xr, xres,
                                             ei, cursor, csr_src);
    k_gat<<<NN/4, 256, 0, stream>>>(xl, xr, csr_src, rowptr, att1, bias1, hraw, ps1, pq1);
    k_post1<<<(NN*16+255)/256, 256, 0, stream>>>(hraw, xres, ps1, pq1, g1, b1, hbuf, hhi, hlo);

    // layer 2
    k_gemm2<<<1600, 256, 0, stream>>>(hhi, hlo, whl2, wll2, whr2, wlr2, bl2, br2, xl, xr);
    k_gat<<<NN/4, 256, 0, stream>>>(xl, xr, csr_src, rowptr, att2, bias2, hraw, ps2, pq2);
    k_post2<<<(NN*16+255)/256, 256, 0, stream>>>(hraw, hbuf, ps2, pq2, g2, b2, z16);

    // scores
    k_score<<<(ELI_N*16+255)/256, 256, 0, stream>>>(z16, eli, out);
}

// Round 13
// 289.079 us; speedup vs baseline: 1.5341x; 1.0089x over previous
//
#include <hip/hip_runtime.h>
#include <math.h>

#define NN 50000
#define EE 400000
#define ETOT 450000
#define INC 128
#define CC 64
#define HC 256
#define ELI_N 200000
#define MPAD 50176   // 196*256; 3136 row-blocks of 16

typedef unsigned short u16;
typedef __attribute__((ext_vector_type(8))) short short8v;
typedef __attribute__((ext_vector_type(8))) unsigned short u16x8;
typedef __attribute__((ext_vector_type(4))) float f32x4;
typedef __attribute__((ext_vector_type(4))) unsigned short u16x4;

__device__ __forceinline__ u16 f2b(float v){
    unsigned u = __float_as_uint(v);
    u = (u + 0x7fffu + ((u >> 16) & 1u)) >> 16;   // RNE
    return (u16)u;
}
__device__ __forceinline__ float b2f(u16 h){
    return __uint_as_float(((unsigned)h) << 16);
}
__device__ __forceinline__ u16 f2h(float v){
    _Float16 h = (_Float16)v; u16 r; __builtin_memcpy(&r, &h, 2); return r;
}
__device__ __forceinline__ float h2f(u16 h){
    _Float16 x; __builtin_memcpy(&x, &h, 2); return (float)x;
}
__device__ __forceinline__ f32x4 h2f4(u16x4 r){
    f32x4 o; o[0]=h2f(r[0]); o[1]=h2f(r[1]); o[2]=h2f(r[2]); o[3]=h2f(r[3]); return o;
}

// ---------------- fused setup: splitX (packed) | convW (packed) | edge count ----------------
__global__ void k_setup(const float* __restrict__ x, const int* __restrict__ ei,
                        const float* __restrict__ Wl1, const float* __restrict__ Wr1,
                        const float* __restrict__ Wres, const float* __restrict__ Wl2,
                        const float* __restrict__ Wr2,
                        u16* __restrict__ xhi, u16* __restrict__ xlo,
                        u16* __restrict__ hl1, u16* __restrict__ ll1,
                        u16* __restrict__ hr1, u16* __restrict__ lr1,
                        u16* __restrict__ hres, u16* __restrict__ lres,
                        u16* __restrict__ hl2, u16* __restrict__ ll2,
                        u16* __restrict__ hr2, u16* __restrict__ lr2,
                        int* __restrict__ deg){
    int gid = blockIdx.x*256 + threadIdx.x;
    if (gid < 800000){
        int row = gid >> 4;
        int k0  = (gid & 15) * 8;
        const float* ap = x + (size_t)row*128 + k0;
        float4 v0 = *(const float4*)ap;
        float4 v1 = *(const float4*)(ap + 4);
        float vv[8] = {v0.x, v0.y, v0.z, v0.w, v1.x, v1.y, v1.z, v1.w};
        u16x8 h8, l8;
        #pragma unroll
        for (int j = 0; j < 8; j++){
            u16 h = f2b(vv[j]);
            h8[j] = h;
            l8[j] = f2b(vv[j] - b2f(h));
        }
        size_t blk = (size_t)(row >> 4)*4 + (k0 >> 5);
        size_t addr = blk*512 + (size_t)((row & 15) + 16*((k0 >> 3) & 3))*8;
        *(u16x8*)(xhi + addr) = h8;
        *(u16x8*)(xlo + addr) = l8;
    } else if (gid < 906496){
        int g = gid - 800000;
        const float* src; u16* dh; u16* dl; int K, N, idx;
        if      (g <  32768){ src=Wl1;  dh=hl1;  dl=ll1;  K=128; N=256; idx=g; }
        else if (g <  65536){ src=Wr1;  dh=hr1;  dl=lr1;  K=128; N=256; idx=g-32768; }
        else if (g <  73728){ src=Wres; dh=hres; dl=lres; K=128; N=64;  idx=g-65536; }
        else if (g <  90112){ src=Wl2;  dh=hl2;  dl=ll2;  K=64;  N=256; idx=g-73728; }
        else                { src=Wr2;  dh=hr2;  dl=lr2;  K=64;  N=256; idx=g-90112; }
        int k = idx / N, n = idx - k*N;
        float v = src[idx];
        u16 h = f2b(v);
        size_t blk = (size_t)(n >> 4)*(K >> 5) + (k >> 5);
        size_t addr = blk*512 + (size_t)((n & 15) + 16*((k >> 3) & 3))*8 + (k & 7);
        dh[addr] = h;
        dl[addr] = f2b(v - b2f(h));
    } else if (gid < 1306496){
        int e = gid - 906496;
        atomicAdd(&deg[ei[EE + e]], 1);
    }
}

// ---------------- CSR build ----------------
__global__ void k_scanA(const int* __restrict__ deg, int* __restrict__ iscan, int* __restrict__ part){
    __shared__ int sh[256];
    int tid = threadIdx.x;
    int base = blockIdx.x*1024 + tid*4;
    int v[4]; int t = 0;
    #pragma unroll
    for (int i = 0; i < 4; i++){ int idx = base + i; v[i] = (idx < NN) ? deg[idx]+1 : 0; t += v[i]; }
    sh[tid] = t; __syncthreads();
    for (int off = 1; off < 256; off <<= 1){
        int u = (tid >= off) ? sh[tid - off] : 0;
        __syncthreads();
        sh[tid] += u;
        __syncthreads();
    }
    int incl = sh[tid];
    int run = incl - t;
    #pragma unroll
    for (int i = 0; i < 4; i++){
        run += v[i];
        int idx = base + i;
        if (idx < NN) iscan[idx] = run;
    }
    if (tid == 255) part[blockIdx.x] = incl;
}

__global__ void k_scanC(const int* __restrict__ iscan, const int* __restrict__ part,
                        const int* __restrict__ deg, int* __restrict__ rowptr, int* __restrict__ cursor){
    int chunk = blockIdx.x >> 2;
    int ps = 0;
    for (int j = 0; j < chunk; j++) ps += part[j];
    int i = blockIdx.x*256 + threadIdx.x;
    if (i < NN){
        int v = iscan[i] + ps;          // rowptr[i+1]
        rowptr[i+1] = v;
        cursor[i] = v - (deg[i]+1);     // rowptr[i]
    }
    if (i == 0) rowptr[0] = 0;
}

__global__ void k_fill(const int* __restrict__ ei, int* __restrict__ cursor, int* __restrict__ csr_src){
    int idx = blockIdx.x*256 + threadIdx.x;
    if (idx >= ETOT) return;
    int s, d;
    if (idx < EE){ s = ei[idx]; d = ei[EE + idx]; }
    else         { s = idx - EE; d = s; }
    int pos = atomicAdd(&cursor[d], 1);
    csr_src[pos] = s;
}

// ---------------- layer-1 GEMM, packed operands; xl/xr/xres written fp16 ----------------
__global__ __launch_bounds__(256) void k_gemm1(const u16* __restrict__ Ahi, const u16* __restrict__ Alo,
        const u16* __restrict__ Whl1, const u16* __restrict__ Wll1,
        const u16* __restrict__ Whr1, const u16* __restrict__ Wlr1,
        const u16* __restrict__ Whres,const u16* __restrict__ Wlres,
        const float* __restrict__ bl1, const float* __restrict__ br1, const float* __restrict__ bres,
        u16* __restrict__ xl, u16* __restrict__ xr, u16* __restrict__ xres)
{
    int b = blockIdx.x;
    int c = b & 7;
    int k = b >> 3;
    int tile = k % 9;
    int sx = c + 8*(k/9);
    if (sx >= 196) return;
    int wid = threadIdx.x >> 6, lane = threadIdx.x & 63;
    const u16 *Bh, *Bl; const float* bias; u16* Cout; int n0, N;
    if (tile < 4)      { Bh=Whl1;  Bl=Wll1;  bias=bl1;  Cout=xl;   n0=tile*64;     N=256; }
    else if (tile < 8) { Bh=Whr1;  Bl=Wlr1;  bias=br1;  Cout=xr;   n0=(tile-4)*64; N=256; }
    else               { Bh=Whres; Bl=Wlres; bias=bres; Cout=xres; n0=0;           N=64;  }
    int rm0 = (sx*4 + wid) * 64;
    int rblk0 = rm0 >> 4;
    int nblk0 = n0 >> 4;
    int lr = lane & 15;
    f32x4 acc[4][4] = {};
    #pragma unroll
    for (int ks = 0; ks < 4; ks++){
        short8v ah[4], al[4], bh[4], blo[4];
        #pragma unroll
        for (int mf = 0; mf < 4; mf++){
            size_t addr = ((size_t)(rblk0 + mf)*4 + ks)*512 + (size_t)lane*8;
            ah[mf] = *(const short8v*)(Ahi + addr);
            al[mf] = *(const short8v*)(Alo + addr);
        }
        #pragma unroll
        for (int nf = 0; nf < 4; nf++){
            size_t addr = ((size_t)(nblk0 + nf)*4 + ks)*512 + (size_t)lane*8;
            bh[nf]  = *(const short8v*)(Bh + addr);
            blo[nf] = *(const short8v*)(Bl + addr);
        }
        #pragma unroll
        for (int mf = 0; mf < 4; mf++)
            #pragma unroll
            for (int nf = 0; nf < 4; nf++){
                acc[mf][nf] = __builtin_amdgcn_mfma_f32_16x16x32_bf16(ah[mf], bh[nf],  acc[mf][nf], 0, 0, 0);
                acc[mf][nf] = __builtin_amdgcn_mfma_f32_16x16x32_bf16(al[mf], bh[nf],  acc[mf][nf], 0, 0, 0);
                acc[mf][nf] = __builtin_amdgcn_mfma_f32_16x16x32_bf16(ah[mf], blo[nf], acc[mf][nf], 0, 0, 0);
            }
    }
    int rbase = (lane >> 4) << 2;
    #pragma unroll
    for (int nf = 0; nf < 4; nf++){
        int col = n0 + nf*16 + lr;
        float bv = bias[col];
        #pragma unroll
        for (int mf = 0; mf < 4; mf++){
            #pragma unroll
            for (int r = 0; r < 4; r++){
                int row = rm0 + mf*16 + rbase + r;
                if (row < NN) Cout[(size_t)row*N + col] = f2h(acc[mf][nf][r] + bv);
            }
        }
    }
}

// ---------------- layer-2 GEMM, packed operands, K=64; outputs fp16 ----------------
__global__ __launch_bounds__(256) void k_gemm2(const u16* __restrict__ Ahi, const u16* __restrict__ Alo,
        const u16* __restrict__ Whl2, const u16* __restrict__ Wll2,
        const u16* __restrict__ Whr2, const u16* __restrict__ Wlr2,
        const float* __restrict__ bl2, const float* __restrict__ br2,
        u16* __restrict__ xl, u16* __restrict__ xr)
{
    int b = blockIdx.x;
    int c = b & 7;
    int k = b >> 3;
    int tile = k & 7;
    int sx = c + 8*(k >> 3);
    if (sx >= 196) return;
    int wid = threadIdx.x >> 6, lane = threadIdx.x & 63;
    const u16 *Bh, *Bl; const float* bias; u16* Cout;
    if (tile < 4){ Bh=Whl2; Bl=Wll2; bias=bl2; Cout=xl; }
    else         { Bh=Whr2; Bl=Wlr2; bias=br2; Cout=xr; }
    int n0 = (tile & 3)*64;
    int rm0 = (sx*4 + wid) * 64;
    int rblk0 = rm0 >> 4;
    int nblk0 = n0 >> 4;
    int lr = lane & 15;
    f32x4 acc[4][4] = {};
    #pragma unroll
    for (int ks = 0; ks < 2; ks++){
        short8v ah[4], al[4], bh[4], blo[4];
        #pragma unroll
        for (int mf = 0; mf < 4; mf++){
            size_t addr = ((size_t)(rblk0 + mf)*2 + ks)*512 + (size_t)lane*8;
            ah[mf] = *(const short8v*)(Ahi + addr);
            al[mf] = *(const short8v*)(Alo + addr);
        }
        #pragma unroll
        for (int nf = 0; nf < 4; nf++){
            size_t addr = ((size_t)(nblk0 + nf)*2 + ks)*512 + (size_t)lane*8;
            bh[nf]  = *(const short8v*)(Bh + addr);
            blo[nf] = *(const short8v*)(Bl + addr);
        }
        #pragma unroll
        for (int mf = 0; mf < 4; mf++)
            #pragma unroll
            for (int nf = 0; nf < 4; nf++){
                acc[mf][nf] = __builtin_amdgcn_mfma_f32_16x16x32_bf16(ah[mf], bh[nf],  acc[mf][nf], 0, 0, 0);
                acc[mf][nf] = __builtin_amdgcn_mfma_f32_16x16x32_bf16(al[mf], bh[nf],  acc[mf][nf], 0, 0, 0);
                acc[mf][nf] = __builtin_amdgcn_mfma_f32_16x16x32_bf16(ah[mf], blo[nf], acc[mf][nf], 0, 0, 0);
            }
    }
    int rbase = (lane >> 4) << 2;
    #pragma unroll
    for (int nf = 0; nf < 4; nf++){
        int col = n0 + nf*16 + lr;
        float bv = bias[col];
        #pragma unroll
        for (int mf = 0; mf < 4; mf++){
            #pragma unroll
            for (int r = 0; r < 4; r++){
                int row = rm0 + mf*16 + rbase + r;
                if (row < NN) Cout[(size_t)row*256 + col] = f2h(acc[mf][nf][r] + bv);
            }
        }
    }
}

// ---------------- fused GATv2 aggregation + BN partial stats ----------------
__global__ __launch_bounds__(256) void k_gat(const u16* __restrict__ xl, const u16* __restrict__ xr,
                                             const int* __restrict__ csr_src, const int* __restrict__ rowptr,
                                             const float* __restrict__ att, const float* __restrict__ bias,
                                             float* __restrict__ out,
                                             float* __restrict__ part_s, float* __restrict__ part_q)
{
    __shared__ float ls[4][64];
    __shared__ float lq[4][64];
    int wave = threadIdx.x >> 6, lane = threadIdx.x & 63;
    int node = blockIdx.x*4 + wave;
    int p0 = rowptr[node], p1 = rowptr[node+1];
    f32x4 xrf  = h2f4(*(const u16x4*)(xr + (size_t)node*HC + 4*lane));
    f32x4 attf = *(const f32x4*)(att + 4*lane);
    float s = 0.f;
    f32x4 acc = {0.f, 0.f, 0.f, 0.f};
    int p = p0;
    for (; p + 4 <= p1; p += 4){
        int i0 = csr_src[p], i1 = csr_src[p+1], i2 = csr_src[p+2], i3 = csr_src[p+3];
        f32x4 x0 = h2f4(*(const u16x4*)(xl + (size_t)i0*HC + 4*lane));
        f32x4 x1 = h2f4(*(const u16x4*)(xl + (size_t)i1*HC + 4*lane));
        f32x4 x2 = h2f4(*(const u16x4*)(xl + (size_t)i2*HC + 4*lane));
        f32x4 x3 = h2f4(*(const u16x4*)(xl + (size_t)i3*HC + 4*lane));
        float t0 = 0.f, t1 = 0.f, t2 = 0.f, t3 = 0.f;
        #pragma unroll
        for (int j = 0; j < 4; j++){
            float e0 = x0[j] + xrf[j]; e0 = (e0 > 0.f) ? e0 : 0.2f*e0; t0 += e0*attf[j];
            float e1 = x1[j] + xrf[j]; e1 = (e1 > 0.f) ? e1 : 0.2f*e1; t1 += e1*attf[j];
            float e2 = x2[j] + xrf[j]; e2 = (e2 > 0.f) ? e2 : 0.2f*e2; t2 += e2*attf[j];
            float e3 = x3[j] + xrf[j]; e3 = (e3 > 0.f) ? e3 : 0.2f*e3; t3 += e3*attf[j];
        }
        #pragma unroll
        for (int off = 1; off < 16; off <<= 1){
            t0 += __shfl_xor(t0, off, 64);
            t1 += __shfl_xor(t1, off, 64);
            t2 += __shfl_xor(t2, off, 64);
            t3 += __shfl_xor(t3, off, 64);
        }
        float w0 = __expf(t0), w1 = __expf(t1), w2 = __expf(t2), w3 = __expf(t3);
        s += (w0 + w1) + (w2 + w3);
        acc = acc + x0*w0 + x1*w1 + x2*w2 + x3*w3;
    }
    for (; p < p1; p++){
        int i0 = csr_src[p];
        f32x4 x0 = h2f4(*(const u16x4*)(xl + (size_t)i0*HC + 4*lane));
        float t0 = 0.f;
        #pragma unroll
        for (int j = 0; j < 4; j++){ float e0 = x0[j] + xrf[j]; e0 = (e0 > 0.f) ? e0 : 0.2f*e0; t0 += e0*attf[j]; }
        #pragma unroll
        for (int off = 1; off < 16; off <<= 1) t0 += __shfl_xor(t0, off, 64);
        float w0 = __expf(t0);
        s += w0;
        acc = acc + x0*w0;
    }
    float inv = 1.f / s;
    f32x4 o = acc * inv;
    #pragma unroll
    for (int j = 0; j < 4; j++){ o[j] += __shfl_xor(o[j], 16, 64); o[j] += __shfl_xor(o[j], 32, 64); }
    if (lane < 16){
        f32x4 bv = *(const f32x4*)(bias + 4*lane);
        f32x4 res = o*0.25f + bv;
        *(f32x4*)(out + (size_t)node*CC + 4*lane) = res;
        #pragma unroll
        for (int j = 0; j < 4; j++){
            ls[wave][4*lane + j] = res[j];
            lq[wave][4*lane + j] = res[j]*res[j];
        }
    }
    __syncthreads();
    int tid = threadIdx.x;
    if (tid < 128){
        int c = tid & 63;
        if (tid < 64){
            float v = (ls[0][c] + ls[1][c]) + (ls[2][c] + ls[3][c]);
            atomicAdd(&part_s[(blockIdx.x & 63)*64 + c], v);
        } else {
            float v = (lq[0][c] + lq[1][c]) + (lq[2][c] + lq[3][c]);
            atomicAdd(&part_q[(blockIdx.x & 63)*64 + c], v);
        }
    }
}

// h = relu(bn(hraw) + xres); inline 64-buffer stat reduce; writes fp32 h + packed bf16 hi/lo
__global__ __launch_bounds__(256) void k_post1(const float* __restrict__ hraw, const u16* __restrict__ xres,
                        const float* __restrict__ part_s, const float* __restrict__ part_q,
                        const float* __restrict__ g, const float* __restrict__ b,
                        float* __restrict__ out, u16* __restrict__ hhi, u16* __restrict__ hlo){
    __shared__ float red[128];
    int tid = threadIdx.x;
    if (tid < 128){
        const float* base = (tid < 64) ? part_s : part_q;
        int c = tid & 63;
        float sv = 0.f;
        for (int bb = 0; bb < 64; bb++) sv += base[bb*64 + c];
        red[tid] = sv;
    }
    __syncthreads();
    int i = blockIdx.x*256 + tid;   // float4 index
    if (i >= NN*16) return;
    float4 hv = ((const float4*)hraw)[i];
    f32x4 rp = h2f4(*(const u16x4*)(xres + (size_t)i*4));
    int row = i >> 4;
    int c0 = (i & 15) * 4;
    float hp[4] = {hv.x, hv.y, hv.z, hv.w};
    float res[4];
    u16x4 h4, l4;
    const float invN = 1.f / (float)NN;
    #pragma unroll
    for (int k = 0; k < 4; k++){
        int c = c0 + k;
        float mean = red[c] * invN;
        float var  = red[64 + c] * invN - mean*mean;
        float rstd = rsqrtf(var + 1e-5f);
        float v = g[c]*(hp[k] - mean)*rstd + b[c] + rp[k];
        v = (v > 0.f) ? v : 0.f;
        res[k] = v;
        u16 h = f2b(v);
        h4[k] = h;
        l4[k] = f2b(v - b2f(h));
    }
    ((float4*)out)[i] = make_float4(res[0], res[1], res[2], res[3]);
    size_t blk = (size_t)(row >> 4)*2 + (c0 >> 5);
    size_t addr = blk*512 + (size_t)((row & 15) + 16*((c0 >> 3) & 3))*8 + (c0 & 7);
    *(u16x4*)(hhi + addr) = h4;
    *(u16x4*)(hlo + addr) = l4;
}

// z = bn(h2raw) + h, fp16; inline stat reduce
__global__ __launch_bounds__(256) void k_post2(const float* __restrict__ hraw, const float* __restrict__ hprev,
                        const float* __restrict__ part_s, const float* __restrict__ part_q,
                        const float* __restrict__ g, const float* __restrict__ b,
                        u16* __restrict__ zout){
    __shared__ float red[128];
    int tid = threadIdx.x;
    if (tid < 128){
        const float* base = (tid < 64) ? part_s : part_q;
        int c = tid & 63;
        float sv = 0.f;
        for (int bb = 0; bb < 64; bb++) sv += base[bb*64 + c];
        red[tid] = sv;
    }
    __syncthreads();
    int i = blockIdx.x*256 + tid;
    if (i >= NN*16) return;
    float4 hv = ((const float4*)hraw)[i];
    float4 rv = ((const float4*)hprev)[i];
    int c0 = (i & 15) * 4;
    float hp[4] = {hv.x, hv.y, hv.z, hv.w};
    float rp[4] = {rv.x, rv.y, rv.z, rv.w};
    u16x4 res;
    const float invN = 1.f / (float)NN;
    #pragma unroll
    for (int k = 0; k < 4; k++){
        int c = c0 + k;
        float mean = red[c] * invN;
        float var  = red[64 + c] * invN - mean*mean;
        float rstd = rsqrtf(var + 1e-5f);
        res[k] = f2h(g[c]*(hp[k] - mean)*rstd + b[c] + rp[k]);
    }
    *(u16x4*)(zout + (size_t)i*4) = res;
}

// ---------------- link-prediction scores (fp16 z gather) ----------------
__global__ __launch_bounds__(256) void k_score(const u16* __restrict__ z, const int* __restrict__ eli,
                                               float* __restrict__ out){
    int t = blockIdx.x*256 + threadIdx.x;
    int i = t >> 4; int j = t & 15;
    if (i >= ELI_N) return;
    int a = eli[i], b = eli[ELI_N + i];
    f32x4 va = h2f4(*(const u16x4*)(z + (size_t)a*64 + j*4));
    f32x4 vb = h2f4(*(const u16x4*)(z + (size_t)b*64 + j*4));
    float s = va[0]*vb[0] + va[1]*vb[1] + va[2]*vb[2] + va[3]*vb[3];
    #pragma unroll
    for (int off = 8; off > 0; off >>= 1) s += __shfl_xor(s, off, 64);
    if (j == 0) out[i] = 1.f / (1.f + __expf(-s));
}

extern "C" void kernel_launch(void* const* d_in, const int* in_sizes, int n_in,
                              void* d_out, int out_size, void* d_ws, size_t ws_size,
                              hipStream_t stream) {
    const float* x    = (const float*)d_in[0];
    const int*   ei   = (const int*)  d_in[1];
    const int*   eli  = (const int*)  d_in[2];
    const float* Wl1  = (const float*)d_in[3];
    const float* bl1  = (const float*)d_in[4];
    const float* Wr1  = (const float*)d_in[5];
    const float* br1  = (const float*)d_in[6];
    const float* att1 = (const float*)d_in[7];
    const float* bias1= (const float*)d_in[8];
    const float* g1   = (const float*)d_in[9];
    const float* b1   = (const float*)d_in[10];
    const float* Wres = (const float*)d_in[11];
    const float* bres = (const float*)d_in[12];
    const float* Wl2  = (const float*)d_in[13];
    const float* bl2  = (const float*)d_in[14];
    const float* Wr2  = (const float*)d_in[15];
    const float* br2  = (const float*)d_in[16];
    const float* att2 = (const float*)d_in[17];
    const float* bias2= (const float*)d_in[18];
    const float* g2   = (const float*)d_in[19];
    const float* b2   = (const float*)d_in[20];
    float* out = (float*)d_out;

    char* w = (char*)d_ws;
    size_t o = 0;
    auto take = [&](size_t bytes)->char*{ char* p = w + o; o += (bytes + 255) & ~(size_t)255; return p; };
    u16*  xl   = (u16*) take((size_t)NN*HC*2);     // fp16 gather tables
    u16*  xr   = (u16*) take((size_t)NN*HC*2);
    u16*  xres = (u16*) take((size_t)NN*CC*2);     // fp16 residual
    float* hraw = (float*)take((size_t)NN*CC*4);
    float* hbuf = (float*)take((size_t)NN*CC*4);
    u16*  z16  = (u16*) take((size_t)NN*CC*2);     // fp16 z for score
    u16*  xhi  = (u16*)take((size_t)MPAD*INC*2);   // packed fragment layout
    u16*  xlo  = (u16*)take((size_t)MPAD*INC*2);
    u16*  hhi  = (u16*)take((size_t)MPAD*CC*2);
    u16*  hlo  = (u16*)take((size_t)MPAD*CC*2);
    u16* whl1 = (u16*)take(256*128*2);  u16* wll1 = (u16*)take(256*128*2);
    u16* whr1 = (u16*)take(256*128*2);  u16* wlr1 = (u16*)take(256*128*2);
    u16* whres= (u16*)take(64*128*2);   u16* wlres= (u16*)take(64*128*2);
    u16* whl2 = (u16*)take(256*64*2);   u16* wll2 = (u16*)take(256*64*2);
    u16* whr2 = (u16*)take(256*64*2);   u16* wlr2 = (u16*)take(256*64*2);
    // zeroed region: 4 partial-stat buffers (64x64 each) + deg
    char* zreg  = take(4*64*64*4 + (size_t)NN*4);
    float* ps1  = (float*)zreg;
    float* pq1  = ps1 + 4096;
    float* ps2  = ps1 + 8192;
    float* pq2  = ps1 + 12288;
    int* deg    = (int*)(zreg + 4*64*64*4);
    int* rowptr = (int*)take((size_t)(NN+1)*4);
    int* iscan  = (int*)take((size_t)NN*4);
    int* cursor = (int*)take((size_t)NN*4);
    int* csr_src= (int*)take((size_t)ETOT*4);
    int* part   = (int*)take(64*4);

    hipMemsetAsync(zreg, 0, 4*64*64*4 + (size_t)NN*4, stream);

    // fused setup: x split (packed) | weight conv (packed) | degree count
    k_setup<<<5104, 256, 0, stream>>>(x, ei, Wl1, Wr1, Wres, Wl2, Wr2,
                                      xhi, xlo,
                                      whl1, wll1, whr1, wlr1, whres, wlres,
                                      whl2, wll2, whr2, wlr2, deg);

    // CSR build
    k_scanA<<<49, 256, 0, stream>>>(deg, iscan, part);
    k_scanC<<<196, 256, 0, stream>>>(iscan, part, deg, rowptr, cursor);
    k_fill<<<(ETOT+255)/256, 256, 0, stream>>>(ei, cursor, csr_src);

    // layer 1
    k_gemm1<<<1800, 256, 0, stream>>>(xhi, xlo, whl1, wll1, whr1, wlr1, whres, wlres,
                                      bl1, br1, bres, xl, xr, xres);
    k_gat<<<NN/4, 256, 0, stream>>>(xl, xr, csr_src, rowptr, att1, bias1, hraw, ps1, pq1);
    k_post1<<<(NN*16+255)/256, 256, 0, stream>>>(hraw, xres, ps1, pq1, g1, b1, hbuf, hhi, hlo);

    // layer 2
    k_gemm2<<<1600, 256, 0, stream>>>(hhi, hlo, whl2, wll2, whr2, wlr2, bl2, br2, xl, xr);
    k_gat<<<NN/4, 256, 0, stream>>>(xl, xr, csr_src, rowptr, att2, bias2, hraw, ps2, pq2);
    k_post2<<<(NN*16+255)/256, 256, 0, stream>>>(hraw, hbuf, ps2, pq2, g2, b2, z16);

    // scores
    k_score<<<(ELI_N*16+255)/256, 256, 0, stream>>>(z16, eli, out);
}

// Round 14
// 248.500 us; speedup vs baseline: 1.7846x; 1.1633x over previous
//
#include <hip/hip_runtime.h>
#include <math.h>

#define NN 50000
#define EE 400000
#define ETOT 450000
#define INC 128
#define CC 64
#define HC 256
#define ELI_N 200000
#define MPAD 50176   // 196*256; 3136 row-blocks of 16

typedef unsigned short u16;
typedef __attribute__((ext_vector_type(8))) short short8v;
typedef __attribute__((ext_vector_type(8))) unsigned short u16x8;
typedef __attribute__((ext_vector_type(4))) float f32x4;
typedef __attribute__((ext_vector_type(4))) unsigned short u16x4;

__device__ __forceinline__ u16 f2b(float v){
    unsigned u = __float_as_uint(v);
    u = (u + 0x7fffu + ((u >> 16) & 1u)) >> 16;   // RNE
    return (u16)u;
}
__device__ __forceinline__ float b2f(u16 h){
    return __uint_as_float(((unsigned)h) << 16);
}
__device__ __forceinline__ u16 f2h(float v){
    _Float16 h = (_Float16)v; u16 r; __builtin_memcpy(&r, &h, 2); return r;
}
__device__ __forceinline__ float h2f(u16 h){
    _Float16 x; __builtin_memcpy(&x, &h, 2); return (float)x;
}
__device__ __forceinline__ f32x4 h2f4(u16x4 r){
    f32x4 o; o[0]=h2f(r[0]); o[1]=h2f(r[1]); o[2]=h2f(r[2]); o[3]=h2f(r[3]); return o;
}

// ---------------- fused setup: splitX (packed) | convW (packed) | edge count ----------------
__global__ void k_setup(const float* __restrict__ x, const int* __restrict__ ei,
                        const float* __restrict__ Wl1, const float* __restrict__ Wr1,
                        const float* __restrict__ Wres, const float* __restrict__ Wl2,
                        const float* __restrict__ Wr2,
                        u16* __restrict__ xhi, u16* __restrict__ xlo,
                        u16* __restrict__ hl1, u16* __restrict__ ll1,
                        u16* __restrict__ hr1, u16* __restrict__ lr1,
                        u16* __restrict__ hres, u16* __restrict__ lres,
                        u16* __restrict__ hl2, u16* __restrict__ ll2,
                        u16* __restrict__ hr2, u16* __restrict__ lr2,
                        int* __restrict__ deg){
    int gid = blockIdx.x*256 + threadIdx.x;
    if (gid < 800000){
        int row = gid >> 4;
        int k0  = (gid & 15) * 8;
        const float* ap = x + (size_t)row*128 + k0;
        float4 v0 = *(const float4*)ap;
        float4 v1 = *(const float4*)(ap + 4);
        float vv[8] = {v0.x, v0.y, v0.z, v0.w, v1.x, v1.y, v1.z, v1.w};
        u16x8 h8, l8;
        #pragma unroll
        for (int j = 0; j < 8; j++){
            u16 h = f2b(vv[j]);
            h8[j] = h;
            l8[j] = f2b(vv[j] - b2f(h));
        }
        size_t blk = (size_t)(row >> 4)*4 + (k0 >> 5);
        size_t addr = blk*512 + (size_t)((row & 15) + 16*((k0 >> 3) & 3))*8;
        *(u16x8*)(xhi + addr) = h8;
        *(u16x8*)(xlo + addr) = l8;
    } else if (gid < 906496){
        int g = gid - 800000;
        const float* src; u16* dh; u16* dl; int K, N, idx;
        if      (g <  32768){ src=Wl1;  dh=hl1;  dl=ll1;  K=128; N=256; idx=g; }
        else if (g <  65536){ src=Wr1;  dh=hr1;  dl=lr1;  K=128; N=256; idx=g-32768; }
        else if (g <  73728){ src=Wres; dh=hres; dl=lres; K=128; N=64;  idx=g-65536; }
        else if (g <  90112){ src=Wl2;  dh=hl2;  dl=ll2;  K=64;  N=256; idx=g-73728; }
        else                { src=Wr2;  dh=hr2;  dl=lr2;  K=64;  N=256; idx=g-90112; }
        int k = idx / N, n = idx - k*N;
        float v = src[idx];
        u16 h = f2b(v);
        size_t blk = (size_t)(n >> 4)*(K >> 5) + (k >> 5);
        size_t addr = blk*512 + (size_t)((n & 15) + 16*((k >> 3) & 3))*8 + (k & 7);
        dh[addr] = h;
        dl[addr] = f2b(v - b2f(h));
    } else if (gid < 1306496){
        int e = gid - 906496;
        atomicAdd(&deg[ei[EE + e]], 1);
    }
}

// ---------------- CSR build ----------------
__global__ void k_scanA(const int* __restrict__ deg, int* __restrict__ iscan, int* __restrict__ part){
    __shared__ int sh[256];
    int tid = threadIdx.x;
    int base = blockIdx.x*1024 + tid*4;
    int v[4]; int t = 0;
    #pragma unroll
    for (int i = 0; i < 4; i++){ int idx = base + i; v[i] = (idx < NN) ? deg[idx]+1 : 0; t += v[i]; }
    sh[tid] = t; __syncthreads();
    for (int off = 1; off < 256; off <<= 1){
        int u = (tid >= off) ? sh[tid - off] : 0;
        __syncthreads();
        sh[tid] += u;
        __syncthreads();
    }
    int incl = sh[tid];
    int run = incl - t;
    #pragma unroll
    for (int i = 0; i < 4; i++){
        run += v[i];
        int idx = base + i;
        if (idx < NN) iscan[idx] = run;
    }
    if (tid == 255) part[blockIdx.x] = incl;
}

__global__ void k_scanC(const int* __restrict__ iscan, const int* __restrict__ part,
                        const int* __restrict__ deg, int* __restrict__ rowptr, int* __restrict__ cursor){
    int chunk = blockIdx.x >> 2;
    int ps = 0;
    for (int j = 0; j < chunk; j++) ps += part[j];
    int i = blockIdx.x*256 + threadIdx.x;
    if (i < NN){
        int v = iscan[i] + ps;          // rowptr[i+1]
        rowptr[i+1] = v;
        cursor[i] = v - (deg[i]+1);     // rowptr[i]
    }
    if (i == 0) rowptr[0] = 0;
}

__global__ void k_fill(const int* __restrict__ ei, int* __restrict__ cursor, int* __restrict__ csr_src){
    int idx = blockIdx.x*256 + threadIdx.x;
    if (idx >= ETOT) return;
    int s, d;
    if (idx < EE){ s = ei[idx]; d = ei[EE + idx]; }
    else         { s = idx - EE; d = s; }
    int pos = atomicAdd(&cursor[d], 1);
    csr_src[pos] = s;
}

#define LSTR 80   // LDS row stride in u16 (160B): fragment-write banks spread, 16B-aligned reads

// ---------------- layer-1 GEMM, packed operands; LDS-staged coalesced fp16 epilogue --------
__global__ __launch_bounds__(256) void k_gemm1(const u16* __restrict__ Ahi, const u16* __restrict__ Alo,
        const u16* __restrict__ Whl1, const u16* __restrict__ Wll1,
        const u16* __restrict__ Whr1, const u16* __restrict__ Wlr1,
        const u16* __restrict__ Whres,const u16* __restrict__ Wlres,
        const float* __restrict__ bl1, const float* __restrict__ br1, const float* __restrict__ bres,
        u16* __restrict__ xl, u16* __restrict__ xr, u16* __restrict__ xres)
{
    __shared__ u16 stg[4][64*LSTR];
    int b = blockIdx.x;
    int c = b & 7;
    int k = b >> 3;
    int tile = k % 9;
    int sx = c + 8*(k/9);
    if (sx >= 196) return;
    int wid = threadIdx.x >> 6, lane = threadIdx.x & 63;
    const u16 *Bh, *Bl; const float* bias; u16* Cout; int n0, N;
    if (tile < 4)      { Bh=Whl1;  Bl=Wll1;  bias=bl1;  Cout=xl;   n0=tile*64;     N=256; }
    else if (tile < 8) { Bh=Whr1;  Bl=Wlr1;  bias=br1;  Cout=xr;   n0=(tile-4)*64; N=256; }
    else               { Bh=Whres; Bl=Wlres; bias=bres; Cout=xres; n0=0;           N=64;  }
    int rm0 = (sx*4 + wid) * 64;
    int rblk0 = rm0 >> 4;
    int nblk0 = n0 >> 4;
    int lr = lane & 15;
    f32x4 acc[4][4] = {};
    #pragma unroll
    for (int ks = 0; ks < 4; ks++){
        short8v ah[4], al[4], bh[4], blo[4];
        #pragma unroll
        for (int mf = 0; mf < 4; mf++){
            size_t addr = ((size_t)(rblk0 + mf)*4 + ks)*512 + (size_t)lane*8;
            ah[mf] = *(const short8v*)(Ahi + addr);
            al[mf] = *(const short8v*)(Alo + addr);
        }
        #pragma unroll
        for (int nf = 0; nf < 4; nf++){
            size_t addr = ((size_t)(nblk0 + nf)*4 + ks)*512 + (size_t)lane*8;
            bh[nf]  = *(const short8v*)(Bh + addr);
            blo[nf] = *(const short8v*)(Bl + addr);
        }
        #pragma unroll
        for (int mf = 0; mf < 4; mf++)
            #pragma unroll
            for (int nf = 0; nf < 4; nf++){
                acc[mf][nf] = __builtin_amdgcn_mfma_f32_16x16x32_bf16(ah[mf], bh[nf],  acc[mf][nf], 0, 0, 0);
                acc[mf][nf] = __builtin_amdgcn_mfma_f32_16x16x32_bf16(al[mf], bh[nf],  acc[mf][nf], 0, 0, 0);
                acc[mf][nf] = __builtin_amdgcn_mfma_f32_16x16x32_bf16(ah[mf], blo[nf], acc[mf][nf], 0, 0, 0);
            }
    }
    int rbase = (lane >> 4) << 2;
    u16* my = &stg[wid][0];
    #pragma unroll
    for (int nf = 0; nf < 4; nf++){
        int col = nf*16 + lr;
        float bv = bias[n0 + col];
        #pragma unroll
        for (int mf = 0; mf < 4; mf++){
            #pragma unroll
            for (int r = 0; r < 4; r++){
                int row = mf*16 + rbase + r;
                my[row*LSTR + col] = f2h(acc[mf][nf][r] + bv);
            }
        }
    }
    __syncthreads();
    int rl = lane >> 3, cl = lane & 7;
    #pragma unroll
    for (int it = 0; it < 8; it++){
        int row = it*8 + rl;
        u16x8 v = *(u16x8*)&my[row*LSTR + cl*8];
        int grow = rm0 + row;
        if (grow < NN) *(u16x8*)(Cout + (size_t)grow*N + n0 + cl*8) = v;
    }
}

// ---------------- layer-2 GEMM, K=64; LDS-staged coalesced fp16 epilogue ----------------
__global__ __launch_bounds__(256) void k_gemm2(const u16* __restrict__ Ahi, const u16* __restrict__ Alo,
        const u16* __restrict__ Whl2, const u16* __restrict__ Wll2,
        const u16* __restrict__ Whr2, const u16* __restrict__ Wlr2,
        const float* __restrict__ bl2, const float* __restrict__ br2,
        u16* __restrict__ xl, u16* __restrict__ xr)
{
    __shared__ u16 stg[4][64*LSTR];
    int b = blockIdx.x;
    int c = b & 7;
    int k = b >> 3;
    int tile = k & 7;
    int sx = c + 8*(k >> 3);
    if (sx >= 196) return;
    int wid = threadIdx.x >> 6, lane = threadIdx.x & 63;
    const u16 *Bh, *Bl; const float* bias; u16* Cout;
    if (tile < 4){ Bh=Whl2; Bl=Wll2; bias=bl2; Cout=xl; }
    else         { Bh=Whr2; Bl=Wlr2; bias=br2; Cout=xr; }
    int n0 = (tile & 3)*64;
    int rm0 = (sx*4 + wid) * 64;
    int rblk0 = rm0 >> 4;
    int nblk0 = n0 >> 4;
    int lr = lane & 15;
    f32x4 acc[4][4] = {};
    #pragma unroll
    for (int ks = 0; ks < 2; ks++){
        short8v ah[4], al[4], bh[4], blo[4];
        #pragma unroll
        for (int mf = 0; mf < 4; mf++){
            size_t addr = ((size_t)(rblk0 + mf)*2 + ks)*512 + (size_t)lane*8;
            ah[mf] = *(const short8v*)(Ahi + addr);
            al[mf] = *(const short8v*)(Alo + addr);
        }
        #pragma unroll
        for (int nf = 0; nf < 4; nf++){
            size_t addr = ((size_t)(nblk0 + nf)*2 + ks)*512 + (size_t)lane*8;
            bh[nf]  = *(const short8v*)(Bh + addr);
            blo[nf] = *(const short8v*)(Bl + addr);
        }
        #pragma unroll
        for (int mf = 0; mf < 4; mf++)
            #pragma unroll
            for (int nf = 0; nf < 4; nf++){
                acc[mf][nf] = __builtin_amdgcn_mfma_f32_16x16x32_bf16(ah[mf], bh[nf],  acc[mf][nf], 0, 0, 0);
                acc[mf][nf] = __builtin_amdgcn_mfma_f32_16x16x32_bf16(al[mf], bh[nf],  acc[mf][nf], 0, 0, 0);
                acc[mf][nf] = __builtin_amdgcn_mfma_f32_16x16x32_bf16(ah[mf], blo[nf], acc[mf][nf], 0, 0, 0);
            }
    }
    int rbase = (lane >> 4) << 2;
    u16* my = &stg[wid][0];
    #pragma unroll
    for (int nf = 0; nf < 4; nf++){
        int col = nf*16 + lr;
        float bv = bias[n0 + col];
        #pragma unroll
        for (int mf = 0; mf < 4; mf++){
            #pragma unroll
            for (int r = 0; r < 4; r++){
                int row = mf*16 + rbase + r;
                my[row*LSTR + col] = f2h(acc[mf][nf][r] + bv);
            }
        }
    }
    __syncthreads();
    int rl = lane >> 3, cl = lane & 7;
    #pragma unroll
    for (int it = 0; it < 8; it++){
        int row = it*8 + rl;
        u16x8 v = *(u16x8*)&my[row*LSTR + cl*8];
        int grow = rm0 + row;
        if (grow < NN) *(u16x8*)(Cout + (size_t)grow*256 + n0 + cl*8) = v;
    }
}

// ---------------- fused GATv2 aggregation + BN partial stats ----------------
__global__ __launch_bounds__(256) void k_gat(const u16* __restrict__ xl, const u16* __restrict__ xr,
                                             const int* __restrict__ csr_src, const int* __restrict__ rowptr,
                                             const float* __restrict__ att, const float* __restrict__ bias,
                                             float* __restrict__ out,
                                             float* __restrict__ part_s, float* __restrict__ part_q)
{
    __shared__ float ls[4][64];
    __shared__ float lq[4][64];
    int wave = threadIdx.x >> 6, lane = threadIdx.x & 63;
    int node = blockIdx.x*4 + wave;
    int p0 = rowptr[node], p1 = rowptr[node+1];
    f32x4 xrf  = h2f4(*(const u16x4*)(xr + (size_t)node*HC + 4*lane));
    f32x4 attf = *(const f32x4*)(att + 4*lane);
    float s = 0.f;
    f32x4 acc = {0.f, 0.f, 0.f, 0.f};
    int p = p0;
    for (; p + 4 <= p1; p += 4){
        int i0 = csr_src[p], i1 = csr_src[p+1], i2 = csr_src[p+2], i3 = csr_src[p+3];
        f32x4 x0 = h2f4(*(const u16x4*)(xl + (size_t)i0*HC + 4*lane));
        f32x4 x1 = h2f4(*(const u16x4*)(xl + (size_t)i1*HC + 4*lane));
        f32x4 x2 = h2f4(*(const u16x4*)(xl + (size_t)i2*HC + 4*lane));
        f32x4 x3 = h2f4(*(const u16x4*)(xl + (size_t)i3*HC + 4*lane));
        float t0 = 0.f, t1 = 0.f, t2 = 0.f, t3 = 0.f;
        #pragma unroll
        for (int j = 0; j < 4; j++){
            float e0 = x0[j] + xrf[j]; e0 = (e0 > 0.f) ? e0 : 0.2f*e0; t0 += e0*attf[j];
            float e1 = x1[j] + xrf[j]; e1 = (e1 > 0.f) ? e1 : 0.2f*e1; t1 += e1*attf[j];
            float e2 = x2[j] + xrf[j]; e2 = (e2 > 0.f) ? e2 : 0.2f*e2; t2 += e2*attf[j];
            float e3 = x3[j] + xrf[j]; e3 = (e3 > 0.f) ? e3 : 0.2f*e3; t3 += e3*attf[j];
        }
        #pragma unroll
        for (int off = 1; off < 16; off <<= 1){
            t0 += __shfl_xor(t0, off, 64);
            t1 += __shfl_xor(t1, off, 64);
            t2 += __shfl_xor(t2, off, 64);
            t3 += __shfl_xor(t3, off, 64);
        }
        float w0 = __expf(t0), w1 = __expf(t1), w2 = __expf(t2), w3 = __expf(t3);
        s += (w0 + w1) + (w2 + w3);
        acc = acc + x0*w0 + x1*w1 + x2*w2 + x3*w3;
    }
    for (; p < p1; p++){
        int i0 = csr_src[p];
        f32x4 x0 = h2f4(*(const u16x4*)(xl + (size_t)i0*HC + 4*lane));
        float t0 = 0.f;
        #pragma unroll
        for (int j = 0; j < 4; j++){ float e0 = x0[j] + xrf[j]; e0 = (e0 > 0.f) ? e0 : 0.2f*e0; t0 += e0*attf[j]; }
        #pragma unroll
        for (int off = 1; off < 16; off <<= 1) t0 += __shfl_xor(t0, off, 64);
        float w0 = __expf(t0);
        s += w0;
        acc = acc + x0*w0;
    }
    float inv = 1.f / s;
    f32x4 o = acc * inv;
    #pragma unroll
    for (int j = 0; j < 4; j++){ o[j] += __shfl_xor(o[j], 16, 64); o[j] += __shfl_xor(o[j], 32, 64); }
    if (lane < 16){
        f32x4 bv = *(const f32x4*)(bias + 4*lane);
        f32x4 res = o*0.25f + bv;
        *(f32x4*)(out + (size_t)node*CC + 4*lane) = res;
        #pragma unroll
        for (int j = 0; j < 4; j++){
            ls[wave][4*lane + j] = res[j];
            lq[wave][4*lane + j] = res[j]*res[j];
        }
    }
    __syncthreads();
    int tid = threadIdx.x;
    if (tid < 128){
        int c = tid & 63;
        if (tid < 64){
            float v = (ls[0][c] + ls[1][c]) + (ls[2][c] + ls[3][c]);
            atomicAdd(&part_s[(blockIdx.x & 63)*64 + c], v);
        } else {
            float v = (lq[0][c] + lq[1][c]) + (lq[2][c] + lq[3][c]);
            atomicAdd(&part_q[(blockIdx.x & 63)*64 + c], v);
        }
    }
}

// h = relu(bn(hraw) + xres); inline stat reduce; writes fp16 h-residual + packed bf16 hi/lo
__global__ __launch_bounds__(256) void k_post1(const float* __restrict__ hraw, const u16* __restrict__ xres,
                        const float* __restrict__ part_s, const float* __restrict__ part_q,
                        const float* __restrict__ g, const float* __restrict__ b,
                        u16* __restrict__ h16, u16* __restrict__ hhi, u16* __restrict__ hlo){
    __shared__ float red[128];
    int tid = threadIdx.x;
    if (tid < 128){
        const float* base = (tid < 64) ? part_s : part_q;
        int c = tid & 63;
        float sv = 0.f;
        for (int bb = 0; bb < 64; bb++) sv += base[bb*64 + c];
        red[tid] = sv;
    }
    __syncthreads();
    int i = blockIdx.x*256 + tid;   // float4 index
    if (i >= NN*16) return;
    float4 hv = ((const float4*)hraw)[i];
    f32x4 rp = h2f4(*(const u16x4*)(xres + (size_t)i*4));
    int row = i >> 4;
    int c0 = (i & 15) * 4;
    float hp[4] = {hv.x, hv.y, hv.z, hv.w};
    u16x4 h4, l4, hh4;
    const float invN = 1.f / (float)NN;
    #pragma unroll
    for (int k = 0; k < 4; k++){
        int c = c0 + k;
        float mean = red[c] * invN;
        float var  = red[64 + c] * invN - mean*mean;
        float rstd = rsqrtf(var + 1e-5f);
        float v = g[c]*(hp[k] - mean)*rstd + b[c] + rp[k];
        v = (v > 0.f) ? v : 0.f;
        hh4[k] = f2h(v);
        u16 h = f2b(v);
        h4[k] = h;
        l4[k] = f2b(v - b2f(h));
    }
    *(u16x4*)(h16 + (size_t)i*4) = hh4;
    size_t blk = (size_t)(row >> 4)*2 + (c0 >> 5);
    size_t addr = blk*512 + (size_t)((row & 15) + 16*((c0 >> 3) & 3))*8 + (c0 & 7);
    *(u16x4*)(hhi + addr) = h4;
    *(u16x4*)(hlo + addr) = l4;
}

// z = bn(h2raw) + h, fp16; inline stat reduce
__global__ __launch_bounds__(256) void k_post2(const float* __restrict__ hraw, const u16* __restrict__ h16,
                        const float* __restrict__ part_s, const float* __restrict__ part_q,
                        const float* __restrict__ g, const float* __restrict__ b,
                        u16* __restrict__ zout){
    __shared__ float red[128];
    int tid = threadIdx.x;
    if (tid < 128){
        const float* base = (tid < 64) ? part_s : part_q;
        int c = tid & 63;
        float sv = 0.f;
        for (int bb = 0; bb < 64; bb++) sv += base[bb*64 + c];
        red[tid] = sv;
    }
    __syncthreads();
    int i = blockIdx.x*256 + tid;
    if (i >= NN*16) return;
    float4 hv = ((const float4*)hraw)[i];
    f32x4 rp = h2f4(*(const u16x4*)(h16 + (size_t)i*4));
    int c0 = (i & 15) * 4;
    float hp[4] = {hv.x, hv.y, hv.z, hv.w};
    u16x4 res;
    const float invN = 1.f / (float)NN;
    #pragma unroll
    for (int k = 0; k < 4; k++){
        int c = c0 + k;
        float mean = red[c] * invN;
        float var  = red[64 + c] * invN - mean*mean;
        float rstd = rsqrtf(var + 1e-5f);
        res[k] = f2h(g[c]*(hp[k] - mean)*rstd + b[c] + rp[k]);
    }
    *(u16x4*)(zout + (size_t)i*4) = res;
}

// ---------------- link-prediction scores (fp16 z gather) ----------------
__global__ __launch_bounds__(256) void k_score(const u16* __restrict__ z, const int* __restrict__ eli,
                                               float* __restrict__ out){
    int t = blockIdx.x*256 + threadIdx.x;
    int i = t >> 4; int j = t & 15;
    if (i >= ELI_N) return;
    int a = eli[i], b = eli[ELI_N + i];
    f32x4 va = h2f4(*(const u16x4*)(z + (size_t)a*64 + j*4));
    f32x4 vb = h2f4(*(const u16x4*)(z + (size_t)b*64 + j*4));
    float s = va[0]*vb[0] + va[1]*vb[1] + va[2]*vb[2] + va[3]*vb[3];
    #pragma unroll
    for (int off = 8; off > 0; off >>= 1) s += __shfl_xor(s, off, 64);
    if (j == 0) out[i] = 1.f / (1.f + __expf(-s));
}

extern "C" void kernel_launch(void* const* d_in, const int* in_sizes, int n_in,
                              void* d_out, int out_size, void* d_ws, size_t ws_size,
                              hipStream_t stream) {
    const float* x    = (const float*)d_in[0];
    const int*   ei   = (const int*)  d_in[1];
    const int*   eli  = (const int*)  d_in[2];
    const float* Wl1  = (const float*)d_in[3];
    const float* bl1  = (const float*)d_in[4];
    const float* Wr1  = (const float*)d_in[5];
    const float* br1  = (const float*)d_in[6];
    const float* att1 = (const float*)d_in[7];
    const float* bias1= (const float*)d_in[8];
    const float* g1   = (const float*)d_in[9];
    const float* b1   = (const float*)d_in[10];
    const float* Wres = (const float*)d_in[11];
    const float* bres = (const float*)d_in[12];
    const float* Wl2  = (const float*)d_in[13];
    const float* bl2  = (const float*)d_in[14];
    const float* Wr2  = (const float*)d_in[15];
    const float* br2  = (const float*)d_in[16];
    const float* att2 = (const float*)d_in[17];
    const float* bias2= (const float*)d_in[18];
    const float* g2   = (const float*)d_in[19];
    const float* b2   = (const float*)d_in[20];
    float* out = (float*)d_out;

    char* w = (char*)d_ws;
    size_t o = 0;
    auto take = [&](size_t bytes)->char*{ char* p = w + o; o += (bytes + 255) & ~(size_t)255; return p; };
    u16*  xl   = (u16*) take((size_t)NN*HC*2);     // fp16 gather tables
    u16*  xr   = (u16*) take((size_t)NN*HC*2);
    u16*  xres = (u16*) take((size_t)NN*CC*2);     // fp16 residual
    float* hraw = (float*)take((size_t)NN*CC*4);
    u16*  h16  = (u16*) take((size_t)NN*CC*2);     // fp16 h residual
    u16*  z16  = (u16*) take((size_t)NN*CC*2);     // fp16 z for score
    u16*  xhi  = (u16*)take((size_t)MPAD*INC*2);   // packed fragment layout
    u16*  xlo  = (u16*)take((size_t)MPAD*INC*2);
    u16*  hhi  = (u16*)take((size_t)MPAD*CC*2);
    u16*  hlo  = (u16*)take((size_t)MPAD*CC*2);
    u16* whl1 = (u16*)take(256*128*2);  u16* wll1 = (u16*)take(256*128*2);
    u16* whr1 = (u16*)take(256*128*2);  u16* wlr1 = (u16*)take(256*128*2);
    u16* whres= (u16*)take(64*128*2);   u16* wlres= (u16*)take(64*128*2);
    u16* whl2 = (u16*)take(256*64*2);   u16* wll2 = (u16*)take(256*64*2);
    u16* whr2 = (u16*)take(256*64*2);   u16* wlr2 = (u16*)take(256*64*2);
    // zeroed region: 4 partial-stat buffers (64x64 each) + deg
    char* zreg  = take(4*64*64*4 + (size_t)NN*4);
    float* ps1  = (float*)zreg;
    float* pq1  = ps1 + 4096;
    float* ps2  = ps1 + 8192;
    float* pq2  = ps1 + 12288;
    int* deg    = (int*)(zreg + 4*64*64*4);
    int* rowptr = (int*)take((size_t)(NN+1)*4);
    int* iscan  = (int*)take((size_t)NN*4);
    int* cursor = (int*)take((size_t)NN*4);
    int* csr_src= (int*)take((size_t)ETOT*4);
    int* part   = (int*)take(64*4);

    hipMemsetAsync(zreg, 0, 4*64*64*4 + (size_t)NN*4, stream);

    // fused setup: x split (packed) | weight conv (packed) | degree count
    k_setup<<<5104, 256, 0, stream>>>(x, ei, Wl1, Wr1, Wres, Wl2, Wr2,
                                      xhi, xlo,
                                      whl1, wll1, whr1, wlr1, whres, wlres,
                                      whl2, wll2, whr2, wlr2, deg);

    // CSR build
    k_scanA<<<49, 256, 0, stream>>>(deg, iscan, part);
    k_scanC<<<196, 256, 0, stream>>>(iscan, part, deg, rowptr, cursor);
    k_fill<<<(ETOT+255)/256, 256, 0, stream>>>(ei, cursor, csr_src);

    // layer 1
    k_gemm1<<<1800, 256, 0, stream>>>(xhi, xlo, whl1, wll1, whr1, wlr1, whres, wlres,
                                      bl1, br1, bres, xl, xr, xres);
    k_gat<<<NN/4, 256, 0, stream>>>(xl, xr, csr_src, rowptr, att1, bias1, hraw, ps1, pq1);
    k_post1<<<(NN*16+255)/256, 256, 0, stream>>>(hraw, xres, ps1, pq1, g1, b1, h16, hhi, hlo);

    // layer 2
    k_gemm2<<<1600, 256, 0, stream>>>(hhi, hlo, whl2, wll2, whr2, wlr2, bl2, br2, xl, xr);
    k_gat<<<NN/4, 256, 0, stream>>>(xl, xr, csr_src, rowptr, att2, bias2, hraw, ps2, pq2);
    k_post2<<<(NN*16+255)/256, 256, 0, stream>>>(hraw, h16, ps2, pq2, g2, b2, z16);

    // scores
    k_score<<<(ELI_N*16+255)/256, 256, 0, stream>>>(z16, eli, out);
}

// Round 15
// 238.223 us; speedup vs baseline: 1.8616x; 1.0431x over previous
//
#include <hip/hip_runtime.h>
#include <math.h>

#define NN 50000
#define EE 400000
#define ETOT 450000
#define INC 128
#define CC 64
#define HC 256
#define ELI_N 200000
#define MPAD 50176   // 196*256; 3136 row-blocks of 16

typedef unsigned short u16;
typedef __attribute__((ext_vector_type(8))) short short8v;
typedef __attribute__((ext_vector_type(8))) unsigned short u16x8;
typedef __attribute__((ext_vector_type(4))) float f32x4;
typedef __attribute__((ext_vector_type(4))) unsigned short u16x4;
typedef __attribute__((ext_vector_type(4))) _Float16 h16x4;
typedef __attribute__((ext_vector_type(2))) _Float16 h16x2;

__device__ __forceinline__ u16 f2b(float v){
    unsigned u = __float_as_uint(v);
    u = (u + 0x7fffu + ((u >> 16) & 1u)) >> 16;   // RNE
    return (u16)u;
}
__device__ __forceinline__ float b2f(u16 h){
    return __uint_as_float(((unsigned)h) << 16);
}
__device__ __forceinline__ u16 f2h(float v){
    _Float16 h = (_Float16)v; u16 r; __builtin_memcpy(&r, &h, 2); return r;
}
__device__ __forceinline__ float h2f(u16 h){
    _Float16 x; __builtin_memcpy(&x, &h, 2); return (float)x;
}
__device__ __forceinline__ f32x4 h2f4(u16x4 r){
    f32x4 o; o[0]=h2f(r[0]); o[1]=h2f(r[1]); o[2]=h2f(r[2]); o[3]=h2f(r[3]); return o;
}

// ---------------- fused setup: splitX (packed) | convW (packed) | edge count ----------------
__global__ void k_setup(const float* __restrict__ x, const int* __restrict__ ei,
                        const float* __restrict__ Wl1, const float* __restrict__ Wr1,
                        const float* __restrict__ Wres, const float* __restrict__ Wl2,
                        const float* __restrict__ Wr2,
                        u16* __restrict__ xhi, u16* __restrict__ xlo,
                        u16* __restrict__ hl1, u16* __restrict__ ll1,
                        u16* __restrict__ hr1, u16* __restrict__ lr1,
                        u16* __restrict__ hres, u16* __restrict__ lres,
                        u16* __restrict__ hl2, u16* __restrict__ ll2,
                        u16* __restrict__ hr2, u16* __restrict__ lr2,
                        int* __restrict__ deg){
    int gid = blockIdx.x*256 + threadIdx.x;
    if (gid < 800000){
        int row = gid >> 4;
        int k0  = (gid & 15) * 8;
        const float* ap = x + (size_t)row*128 + k0;
        float4 v0 = *(const float4*)ap;
        float4 v1 = *(const float4*)(ap + 4);
        float vv[8] = {v0.x, v0.y, v0.z, v0.w, v1.x, v1.y, v1.z, v1.w};
        u16x8 h8, l8;
        #pragma unroll
        for (int j = 0; j < 8; j++){
            u16 h = f2b(vv[j]);
            h8[j] = h;
            l8[j] = f2b(vv[j] - b2f(h));
        }
        size_t blk = (size_t)(row >> 4)*4 + (k0 >> 5);
        size_t addr = blk*512 + (size_t)((row & 15) + 16*((k0 >> 3) & 3))*8;
        *(u16x8*)(xhi + addr) = h8;
        *(u16x8*)(xlo + addr) = l8;
    } else if (gid < 906496){
        int g = gid - 800000;
        const float* src; u16* dh; u16* dl; int K, N, idx;
        if      (g <  32768){ src=Wl1;  dh=hl1;  dl=ll1;  K=128; N=256; idx=g; }
        else if (g <  65536){ src=Wr1;  dh=hr1;  dl=lr1;  K=128; N=256; idx=g-32768; }
        else if (g <  73728){ src=Wres; dh=hres; dl=lres; K=128; N=64;  idx=g-65536; }
        else if (g <  90112){ src=Wl2;  dh=hl2;  dl=ll2;  K=64;  N=256; idx=g-73728; }
        else                { src=Wr2;  dh=hr2;  dl=lr2;  K=64;  N=256; idx=g-90112; }
        int k = idx / N, n = idx - k*N;
        float v = src[idx];
        u16 h = f2b(v);
        size_t blk = (size_t)(n >> 4)*(K >> 5) + (k >> 5);
        size_t addr = blk*512 + (size_t)((n & 15) + 16*((k >> 3) & 3))*8 + (k & 7);
        dh[addr] = h;
        dl[addr] = f2b(v - b2f(h));
    } else if (gid < 1306496){
        int e = gid - 906496;
        atomicAdd(&deg[ei[EE + e]], 1);
    }
}

// ---------------- CSR build ----------------
__global__ void k_scanA(const int* __restrict__ deg, int* __restrict__ iscan, int* __restrict__ part){
    __shared__ int sh[256];
    int tid = threadIdx.x;
    int base = blockIdx.x*1024 + tid*4;
    int v[4]; int t = 0;
    #pragma unroll
    for (int i = 0; i < 4; i++){ int idx = base + i; v[i] = (idx < NN) ? deg[idx]+1 : 0; t += v[i]; }
    sh[tid] = t; __syncthreads();
    for (int off = 1; off < 256; off <<= 1){
        int u = (tid >= off) ? sh[tid - off] : 0;
        __syncthreads();
        sh[tid] += u;
        __syncthreads();
    }
    int incl = sh[tid];
    int run = incl - t;
    #pragma unroll
    for (int i = 0; i < 4; i++){
        run += v[i];
        int idx = base + i;
        if (idx < NN) iscan[idx] = run;
    }
    if (tid == 255) part[blockIdx.x] = incl;
}

__global__ void k_scanC(const int* __restrict__ iscan, const int* __restrict__ part,
                        const int* __restrict__ deg, int* __restrict__ rowptr, int* __restrict__ cursor){
    int chunk = blockIdx.x >> 2;
    int ps = 0;
    for (int j = 0; j < chunk; j++) ps += part[j];
    int i = blockIdx.x*256 + threadIdx.x;
    if (i < NN){
        int v = iscan[i] + ps;          // rowptr[i+1]
        rowptr[i+1] = v;
        cursor[i] = v - (deg[i]+1);     // rowptr[i]
    }
    if (i == 0) rowptr[0] = 0;
}

__global__ void k_fill(const int* __restrict__ ei, int* __restrict__ cursor, int* __restrict__ csr_src){
    int idx = blockIdx.x*256 + threadIdx.x;
    if (idx >= ETOT) return;
    int s, d;
    if (idx < EE){ s = ei[idx]; d = ei[EE + idx]; }
    else         { s = idx - EE; d = s; }
    int pos = atomicAdd(&cursor[d], 1);
    csr_src[pos] = s;
}

#define LSTR 80   // LDS row stride in u16 (160B)

// ---------------- layer-1 GEMM, packed operands; LDS-staged coalesced fp16 epilogue --------
__global__ __launch_bounds__(256) void k_gemm1(const u16* __restrict__ Ahi, const u16* __restrict__ Alo,
        const u16* __restrict__ Whl1, const u16* __restrict__ Wll1,
        const u16* __restrict__ Whr1, const u16* __restrict__ Wlr1,
        const u16* __restrict__ Whres,const u16* __restrict__ Wlres,
        const float* __restrict__ bl1, const float* __restrict__ br1, const float* __restrict__ bres,
        u16* __restrict__ xl, u16* __restrict__ xr, u16* __restrict__ xres)
{
    __shared__ u16 stg[4][64*LSTR];
    int b = blockIdx.x;
    int c = b & 7;
    int k = b >> 3;
    int tile = k % 9;
    int sx = c + 8*(k/9);
    if (sx >= 196) return;
    int wid = threadIdx.x >> 6, lane = threadIdx.x & 63;
    const u16 *Bh, *Bl; const float* bias; u16* Cout; int n0, N;
    if (tile < 4)      { Bh=Whl1;  Bl=Wll1;  bias=bl1;  Cout=xl;   n0=tile*64;     N=256; }
    else if (tile < 8) { Bh=Whr1;  Bl=Wlr1;  bias=br1;  Cout=xr;   n0=(tile-4)*64; N=256; }
    else               { Bh=Whres; Bl=Wlres; bias=bres; Cout=xres; n0=0;           N=64;  }
    int rm0 = (sx*4 + wid) * 64;
    int rblk0 = rm0 >> 4;
    int nblk0 = n0 >> 4;
    int lr = lane & 15;
    f32x4 acc[4][4] = {};
    #pragma unroll
    for (int ks = 0; ks < 4; ks++){
        short8v ah[4], al[4], bh[4], blo[4];
        #pragma unroll
        for (int mf = 0; mf < 4; mf++){
            size_t addr = ((size_t)(rblk0 + mf)*4 + ks)*512 + (size_t)lane*8;
            ah[mf] = *(const short8v*)(Ahi + addr);
            al[mf] = *(const short8v*)(Alo + addr);
        }
        #pragma unroll
        for (int nf = 0; nf < 4; nf++){
            size_t addr = ((size_t)(nblk0 + nf)*4 + ks)*512 + (size_t)lane*8;
            bh[nf]  = *(const short8v*)(Bh + addr);
            blo[nf] = *(const short8v*)(Bl + addr);
        }
        #pragma unroll
        for (int mf = 0; mf < 4; mf++)
            #pragma unroll
            for (int nf = 0; nf < 4; nf++){
                acc[mf][nf] = __builtin_amdgcn_mfma_f32_16x16x32_bf16(ah[mf], bh[nf],  acc[mf][nf], 0, 0, 0);
                acc[mf][nf] = __builtin_amdgcn_mfma_f32_16x16x32_bf16(al[mf], bh[nf],  acc[mf][nf], 0, 0, 0);
                acc[mf][nf] = __builtin_amdgcn_mfma_f32_16x16x32_bf16(ah[mf], blo[nf], acc[mf][nf], 0, 0, 0);
            }
    }
    int rbase = (lane >> 4) << 2;
    u16* my = &stg[wid][0];
    #pragma unroll
    for (int nf = 0; nf < 4; nf++){
        int col = nf*16 + lr;
        float bv = bias[n0 + col];
        #pragma unroll
        for (int mf = 0; mf < 4; mf++){
            #pragma unroll
            for (int r = 0; r < 4; r++){
                int row = mf*16 + rbase + r;
                my[row*LSTR + col] = f2h(acc[mf][nf][r] + bv);
            }
        }
    }
    __syncthreads();
    int rl = lane >> 3, cl = lane & 7;
    #pragma unroll
    for (int it = 0; it < 8; it++){
        int row = it*8 + rl;
        u16x8 v = *(u16x8*)&my[row*LSTR + cl*8];
        int grow = rm0 + row;
        if (grow < NN) *(u16x8*)(Cout + (size_t)grow*N + n0 + cl*8) = v;
    }
}

// ---------------- layer-2 GEMM, K=64; LDS-staged coalesced fp16 epilogue ----------------
__global__ __launch_bounds__(256) void k_gemm2(const u16* __restrict__ Ahi, const u16* __restrict__ Alo,
        const u16* __restrict__ Whl2, const u16* __restrict__ Wll2,
        const u16* __restrict__ Whr2, const u16* __restrict__ Wlr2,
        const float* __restrict__ bl2, const float* __restrict__ br2,
        u16* __restrict__ xl, u16* __restrict__ xr)
{
    __shared__ u16 stg[4][64*LSTR];
    int b = blockIdx.x;
    int c = b & 7;
    int k = b >> 3;
    int tile = k & 7;
    int sx = c + 8*(k >> 3);
    if (sx >= 196) return;
    int wid = threadIdx.x >> 6, lane = threadIdx.x & 63;
    const u16 *Bh, *Bl; const float* bias; u16* Cout;
    if (tile < 4){ Bh=Whl2; Bl=Wll2; bias=bl2; Cout=xl; }
    else         { Bh=Whr2; Bl=Wlr2; bias=br2; Cout=xr; }
    int n0 = (tile & 3)*64;
    int rm0 = (sx*4 + wid) * 64;
    int rblk0 = rm0 >> 4;
    int nblk0 = n0 >> 4;
    int lr = lane & 15;
    f32x4 acc[4][4] = {};
    #pragma unroll
    for (int ks = 0; ks < 2; ks++){
        short8v ah[4], al[4], bh[4], blo[4];
        #pragma unroll
        for (int mf = 0; mf < 4; mf++){
            size_t addr = ((size_t)(rblk0 + mf)*2 + ks)*512 + (size_t)lane*8;
            ah[mf] = *(const short8v*)(Ahi + addr);
            al[mf] = *(const short8v*)(Alo + addr);
        }
        #pragma unroll
        for (int nf = 0; nf < 4; nf++){
            size_t addr = ((size_t)(nblk0 + nf)*2 + ks)*512 + (size_t)lane*8;
            bh[nf]  = *(const short8v*)(Bh + addr);
            blo[nf] = *(const short8v*)(Bl + addr);
        }
        #pragma unroll
        for (int mf = 0; mf < 4; mf++)
            #pragma unroll
            for (int nf = 0; nf < 4; nf++){
                acc[mf][nf] = __builtin_amdgcn_mfma_f32_16x16x32_bf16(ah[mf], bh[nf],  acc[mf][nf], 0, 0, 0);
                acc[mf][nf] = __builtin_amdgcn_mfma_f32_16x16x32_bf16(al[mf], bh[nf],  acc[mf][nf], 0, 0, 0);
                acc[mf][nf] = __builtin_amdgcn_mfma_f32_16x16x32_bf16(ah[mf], blo[nf], acc[mf][nf], 0, 0, 0);
            }
    }
    int rbase = (lane >> 4) << 2;
    u16* my = &stg[wid][0];
    #pragma unroll
    for (int nf = 0; nf < 4; nf++){
        int col = nf*16 + lr;
        float bv = bias[n0 + col];
        #pragma unroll
        for (int mf = 0; mf < 4; mf++){
            #pragma unroll
            for (int r = 0; r < 4; r++){
                int row = mf*16 + rbase + r;
                my[row*LSTR + col] = f2h(acc[mf][nf][r] + bv);
            }
        }
    }
    __syncthreads();
    int rl = lane >> 3, cl = lane & 7;
    #pragma unroll
    for (int it = 0; it < 8; it++){
        int row = it*8 + rl;
        u16x8 v = *(u16x8*)&my[row*LSTR + cl*8];
        int grow = rm0 + row;
        if (grow < NN) *(u16x8*)(Cout + (size_t)grow*256 + n0 + cl*8) = v;
    }
}

// ---------------- fused GATv2 aggregation + BN partial stats (packed fp16 math) ------------
__global__ __launch_bounds__(256) void k_gat(const u16* __restrict__ xl, const u16* __restrict__ xr,
                                             const int* __restrict__ csr_src, const int* __restrict__ rowptr,
                                             const float* __restrict__ att, const float* __restrict__ bias,
                                             float* __restrict__ out,
                                             float* __restrict__ part_s, float* __restrict__ part_q)
{
    __shared__ float ls[4][64];
    __shared__ float lq[4][64];
    int wave = threadIdx.x >> 6, lane = threadIdx.x & 63;
    int node = blockIdx.x*4 + wave;
    int p0 = rowptr[node], p1 = rowptr[node+1];
    h16x4 xrh = *(const h16x4*)(xr + (size_t)node*HC + 4*lane);
    f32x4 attf = *(const f32x4*)(att + 4*lane);
    h16x4 atth;
    #pragma unroll
    for (int j = 0; j < 4; j++) atth[j] = (_Float16)attf[j];
    h16x2 alo = __builtin_shufflevector(atth, atth, 0, 1);
    h16x2 ahi = __builtin_shufflevector(atth, atth, 2, 3);
    float s = 0.f;
    f32x4 acc = {0.f, 0.f, 0.f, 0.f};
    int p = p0;
    for (; p + 4 <= p1; p += 4){
        int i0 = csr_src[p], i1 = csr_src[p+1], i2 = csr_src[p+2], i3 = csr_src[p+3];
        h16x4 x0 = *(const h16x4*)(xl + (size_t)i0*HC + 4*lane);
        h16x4 x1 = *(const h16x4*)(xl + (size_t)i1*HC + 4*lane);
        h16x4 x2 = *(const h16x4*)(xl + (size_t)i2*HC + 4*lane);
        h16x4 x3 = *(const h16x4*)(xl + (size_t)i3*HC + 4*lane);
        h16x4 e0 = x0 + xrh, e1 = x1 + xrh, e2 = x2 + xrh, e3 = x3 + xrh;
        h16x4 l0 = __builtin_elementwise_max(e0, e0 * (_Float16)0.2f);
        h16x4 l1 = __builtin_elementwise_max(e1, e1 * (_Float16)0.2f);
        h16x4 l2 = __builtin_elementwise_max(e2, e2 * (_Float16)0.2f);
        h16x4 l3 = __builtin_elementwise_max(e3, e3 * (_Float16)0.2f);
        float t0 = __builtin_amdgcn_fdot2(__builtin_shufflevector(l0, l0, 0, 1), alo, 0.f, false);
        float t1 = __builtin_amdgcn_fdot2(__builtin_shufflevector(l1, l1, 0, 1), alo, 0.f, false);
        float t2 = __builtin_amdgcn_fdot2(__builtin_shufflevector(l2, l2, 0, 1), alo, 0.f, false);
        float t3 = __builtin_amdgcn_fdot2(__builtin_shufflevector(l3, l3, 0, 1), alo, 0.f, false);
        t0 = __builtin_amdgcn_fdot2(__builtin_shufflevector(l0, l0, 2, 3), ahi, t0, false);
        t1 = __builtin_amdgcn_fdot2(__builtin_shufflevector(l1, l1, 2, 3), ahi, t1, false);
        t2 = __builtin_amdgcn_fdot2(__builtin_shufflevector(l2, l2, 2, 3), ahi, t2, false);
        t3 = __builtin_amdgcn_fdot2(__builtin_shufflevector(l3, l3, 2, 3), ahi, t3, false);
        #pragma unroll
        for (int off = 1; off < 16; off <<= 1){
            t0 += __shfl_xor(t0, off, 64);
            t1 += __shfl_xor(t1, off, 64);
            t2 += __shfl_xor(t2, off, 64);
            t3 += __shfl_xor(t3, off, 64);
        }
        float w0 = __expf(t0), w1 = __expf(t1), w2 = __expf(t2), w3 = __expf(t3);
        s += (w0 + w1) + (w2 + w3);
        f32x4 f0 = __builtin_convertvector(x0, f32x4);
        f32x4 f1 = __builtin_convertvector(x1, f32x4);
        f32x4 f2 = __builtin_convertvector(x2, f32x4);
        f32x4 f3 = __builtin_convertvector(x3, f32x4);
        acc = acc + f0*w0 + f1*w1 + f2*w2 + f3*w3;
    }
    for (; p < p1; p++){
        int i0 = csr_src[p];
        h16x4 x0 = *(const h16x4*)(xl + (size_t)i0*HC + 4*lane);
        h16x4 e0 = x0 + xrh;
        h16x4 l0 = __builtin_elementwise_max(e0, e0 * (_Float16)0.2f);
        float t0 = __builtin_amdgcn_fdot2(__builtin_shufflevector(l0, l0, 0, 1), alo, 0.f, false);
        t0 = __builtin_amdgcn_fdot2(__builtin_shufflevector(l0, l0, 2, 3), ahi, t0, false);
        #pragma unroll
        for (int off = 1; off < 16; off <<= 1) t0 += __shfl_xor(t0, off, 64);
        float w0 = __expf(t0);
        s += w0;
        acc = acc + __builtin_convertvector(x0, f32x4)*w0;
    }
    float inv = 1.f / s;
    f32x4 o = acc * inv;
    #pragma unroll
    for (int j = 0; j < 4; j++){ o[j] += __shfl_xor(o[j], 16, 64); o[j] += __shfl_xor(o[j], 32, 64); }
    if (lane < 16){
        f32x4 bv = *(const f32x4*)(bias + 4*lane);
        f32x4 res = o*0.25f + bv;
        *(f32x4*)(out + (size_t)node*CC + 4*lane) = res;
        #pragma unroll
        for (int j = 0; j < 4; j++){
            ls[wave][4*lane + j] = res[j];
            lq[wave][4*lane + j] = res[j]*res[j];
        }
    }
    __syncthreads();
    int tid = threadIdx.x;
    if (tid < 128){
        int c = tid & 63;
        if (tid < 64){
            float v = (ls[0][c] + ls[1][c]) + (ls[2][c] + ls[3][c]);
            atomicAdd(&part_s[(blockIdx.x & 63)*64 + c], v);
        } else {
            float v = (lq[0][c] + lq[1][c]) + (lq[2][c] + lq[3][c]);
            atomicAdd(&part_q[(blockIdx.x & 63)*64 + c], v);
        }
    }
}

// h = relu(bn(hraw) + xres); inline stat reduce; writes fp16 h-residual + packed bf16 hi/lo
__global__ __launch_bounds__(256) void k_post1(const float* __restrict__ hraw, const u16* __restrict__ xres,
                        const float* __restrict__ part_s, const float* __restrict__ part_q,
                        const float* __restrict__ g, const float* __restrict__ b,
                        u16* __restrict__ h16, u16* __restrict__ hhi, u16* __restrict__ hlo){
    __shared__ float red[128];
    int tid = threadIdx.x;
    if (tid < 128){
        const float* base = (tid < 64) ? part_s : part_q;
        int c = tid & 63;
        float sv = 0.f;
        for (int bb = 0; bb < 64; bb++) sv += base[bb*64 + c];
        red[tid] = sv;
    }
    __syncthreads();
    int i = blockIdx.x*256 + tid;   // float4 index
    if (i >= NN*16) return;
    float4 hv = ((const float4*)hraw)[i];
    f32x4 rp = h2f4(*(const u16x4*)(xres + (size_t)i*4));
    int row = i >> 4;
    int c0 = (i & 15) * 4;
    float hp[4] = {hv.x, hv.y, hv.z, hv.w};
    u16x4 h4, l4, hh4;
    const float invN = 1.f / (float)NN;
    #pragma unroll
    for (int k = 0; k < 4; k++){
        int c = c0 + k;
        float mean = red[c] * invN;
        float var  = red[64 + c] * invN - mean*mean;
        float rstd = rsqrtf(var + 1e-5f);
        float v = g[c]*(hp[k] - mean)*rstd + b[c] + rp[k];
        v = (v > 0.f) ? v : 0.f;
        hh4[k] = f2h(v);
        u16 h = f2b(v);
        h4[k] = h;
        l4[k] = f2b(v - b2f(h));
    }
    *(u16x4*)(h16 + (size_t)i*4) = hh4;
    size_t blk = (size_t)(row >> 4)*2 + (c0 >> 5);
    size_t addr = blk*512 + (size_t)((row & 15) + 16*((c0 >> 3) & 3))*8 + (c0 & 7);
    *(u16x4*)(hhi + addr) = h4;
    *(u16x4*)(hlo + addr) = l4;
}

// z = bn(h2raw) + h, fp16; inline stat reduce
__global__ __launch_bounds__(256) void k_post2(const float* __restrict__ hraw, const u16* __restrict__ h16,
                        const float* __restrict__ part_s, const float* __restrict__ part_q,
                        const float* __restrict__ g, const float* __restrict__ b,
                        u16* __restrict__ zout){
    __shared__ float red[128];
    int tid = threadIdx.x;
    if (tid < 128){
        const float* base = (tid < 64) ? part_s : part_q;
        int c = tid & 63;
        float sv = 0.f;
        for (int bb = 0; bb < 64; bb++) sv += base[bb*64 + c];
        red[tid] = sv;
    }
    __syncthreads();
    int i = blockIdx.x*256 + tid;
    if (i >= NN*16) return;
    float4 hv = ((const float4*)hraw)[i];
    f32x4 rp = h2f4(*(const u16x4*)(h16 + (size_t)i*4));
    int c0 = (i & 15) * 4;
    float hp[4] = {hv.x, hv.y, hv.z, hv.w};
    u16x4 res;
    const float invN = 1.f / (float)NN;
    #pragma unroll
    for (int k = 0; k < 4; k++){
        int c = c0 + k;
        float mean = red[c] * invN;
        float var  = red[64 + c] * invN - mean*mean;
        float rstd = rsqrtf(var + 1e-5f);
        res[k] = f2h(g[c]*(hp[k] - mean)*rstd + b[c] + rp[k]);
    }
    *(u16x4*)(zout + (size_t)i*4) = res;
}

// ---------------- link-prediction scores (fp16 z gather) ----------------
__global__ __launch_bounds__(256) void k_score(const u16* __restrict__ z, const int* __restrict__ eli,
                                               float* __restrict__ out){
    int t = blockIdx.x*256 + threadIdx.x;
    int i = t >> 4; int j = t & 15;
    if (i >= ELI_N) return;
    int a = eli[i], b = eli[ELI_N + i];
    f32x4 va = h2f4(*(const u16x4*)(z + (size_t)a*64 + j*4));
    f32x4 vb = h2f4(*(const u16x4*)(z + (size_t)b*64 + j*4));
    float s = va[0]*vb[0] + va[1]*vb[1] + va[2]*vb[2] + va[3]*vb[3];
    #pragma unroll
    for (int off = 8; off > 0; off >>= 1) s += __shfl_xor(s, off, 64);
    if (j == 0) out[i] = 1.f / (1.f + __expf(-s));
}

extern "C" void kernel_launch(void* const* d_in, const int* in_sizes, int n_in,
                              void* d_out, int out_size, void* d_ws, size_t ws_size,
                              hipStream_t stream) {
    const float* x    = (const float*)d_in[0];
    const int*   ei   = (const int*)  d_in[1];
    const int*   eli  = (const int*)  d_in[2];
    const float* Wl1  = (const float*)d_in[3];
    const float* bl1  = (const float*)d_in[4];
    const float* Wr1  = (const float*)d_in[5];
    const float* br1  = (const float*)d_in[6];
    const float* att1 = (const float*)d_in[7];
    const float* bias1= (const float*)d_in[8];
    const float* g1   = (const float*)d_in[9];
    const float* b1   = (const float*)d_in[10];
    const float* Wres = (const float*)d_in[11];
    const float* bres = (const float*)d_in[12];
    const float* Wl2  = (const float*)d_in[13];
    const float* bl2  = (const float*)d_in[14];
    const float* Wr2  = (const float*)d_in[15];
    const float* br2  = (const float*)d_in[16];
    const float* att2 = (const float*)d_in[17];
    const float* bias2= (const float*)d_in[18];
    const float* g2   = (const float*)d_in[19];
    const float* b2   = (const float*)d_in[20];
    float* out = (float*)d_out;

    char* w = (char*)d_ws;
    size_t o = 0;
    auto take = [&](size_t bytes)->char*{ char* p = w + o; o += (bytes + 255) & ~(size_t)255; return p; };
    u16*  xl   = (u16*) take((size_t)NN*HC*2);     // fp16 gather tables
    u16*  xr   = (u16*) take((size_t)NN*HC*2);
    u16*  xres = (u16*) take((size_t)NN*CC*2);     // fp16 residual
    float* hraw = (float*)take((size_t)NN*CC*4);
    u16*  h16  = (u16*) take((size_t)NN*CC*2);     // fp16 h residual
    u16*  z16  = (u16*) take((size_t)NN*CC*2);     // fp16 z for score
    u16*  xhi  = (u16*)take((size_t)MPAD*INC*2);   // packed fragment layout
    u16*  xlo  = (u16*)take((size_t)MPAD*INC*2);
    u16*  hhi  = (u16*)take((size_t)MPAD*CC*2);
    u16*  hlo  = (u16*)take((size_t)MPAD*CC*2);
    u16* whl1 = (u16*)take(256*128*2);  u16* wll1 = (u16*)take(256*128*2);
    u16* whr1 = (u16*)take(256*128*2);  u16* wlr1 = (u16*)take(256*128*2);
    u16* whres= (u16*)take(64*128*2);   u16* wlres= (u16*)take(64*128*2);
    u16* whl2 = (u16*)take(256*64*2);   u16* wll2 = (u16*)take(256*64*2);
    u16* whr2 = (u16*)take(256*64*2);   u16* wlr2 = (u16*)take(256*64*2);
    // zeroed region: 4 partial-stat buffers (64x64 each) + deg
    char* zreg  = take(4*64*64*4 + (size_t)NN*4);
    float* ps1  = (float*)zreg;
    float* pq1  = ps1 + 4096;
    float* ps2  = ps1 + 8192;
    float* pq2  = ps1 + 12288;
    int* deg    = (int*)(zreg + 4*64*64*4);
    int* rowptr = (int*)take((size_t)(NN+1)*4);
    int* iscan  = (int*)take((size_t)NN*4);
    int* cursor = (int*)take((size_t)NN*4);
    int* csr_src= (int*)take((size_t)ETOT*4);
    int* part   = (int*)take(64*4);

    hipMemsetAsync(zreg, 0, 4*64*64*4 + (size_t)NN*4, stream);

    // fused setup: x split (packed) | weight conv (packed) | degree count
    k_setup<<<5104, 256, 0, stream>>>(x, ei, Wl1, Wr1, Wres, Wl2, Wr2,
                                      xhi, xlo,
                                      whl1, wll1, whr1, wlr1, whres, wlres,
                                      whl2, wll2, whr2, wlr2, deg);

    // CSR build
    k_scanA<<<49, 256, 0, stream>>>(deg, iscan, part);
    k_scanC<<<196, 256, 0, stream>>>(iscan, part, deg, rowptr, cursor);
    k_fill<<<(ETOT+255)/256, 256, 0, stream>>>(ei, cursor, csr_src);

    // layer 1
    k_gemm1<<<1800, 256, 0, stream>>>(xhi, xlo, whl1, wll1, whr1, wlr1, whres, wlres,
                                      bl1, br1, bres, xl, xr, xres);
    k_gat<<<NN/4, 256, 0, stream>>>(xl, xr, csr_src, rowptr, att1, bias1, hraw, ps1, pq1);
    k_post1<<<(NN*16+255)/256, 256, 0, stream>>>(hraw, xres, ps1, pq1, g1, b1, h16, hhi, hlo);

    // layer 2
    k_gemm2<<<1600, 256, 0, stream>>>(hhi, hlo, whl2, wll2, whr2, wlr2, bl2, br2, xl, xr);
    k_gat<<<NN/4, 256, 0, stream>>>(xl, xr, csr_src, rowptr, att2, bias2, hraw, ps2, pq2);
    k_post2<<<(NN*16+255)/256, 256, 0, stream>>>(hraw, h16, ps2, pq2, g2, b2, z16);

    // scores
    k_score<<<(ELI_N*16+255)/256, 256, 0, stream>>>(z16, eli, out);
}

// Round 16
// 233.357 us; speedup vs baseline: 1.9004x; 1.0209x over previous
//
#include <hip/hip_runtime.h>
#include <math.h>

#define NN 50000
#define EE 400000
#define ETOT 450000
#define INC 128
#define CC 64
#define HC 256
#define ELI_N 200000
#define MPAD 50176   // 196*256; 3136 row-blocks of 16

typedef unsigned short u16;
typedef __attribute__((ext_vector_type(8))) short short8v;
typedef __attribute__((ext_vector_type(8))) unsigned short u16x8;
typedef __attribute__((ext_vector_type(4))) float f32x4;
typedef __attribute__((ext_vector_type(8))) float f32x8;
typedef __attribute__((ext_vector_type(4))) unsigned short u16x4;
typedef __attribute__((ext_vector_type(4))) _Float16 h16x4;
typedef __attribute__((ext_vector_type(2))) _Float16 h16x2;
typedef __attribute__((ext_vector_type(8))) _Float16 h16x8;

__device__ __forceinline__ u16 f2b(float v){
    unsigned u = __float_as_uint(v);
    u = (u + 0x7fffu + ((u >> 16) & 1u)) >> 16;   // RNE
    return (u16)u;
}
__device__ __forceinline__ float b2f(u16 h){
    return __uint_as_float(((unsigned)h) << 16);
}
__device__ __forceinline__ u16 f2h(float v){
    _Float16 h = (_Float16)v; u16 r; __builtin_memcpy(&r, &h, 2); return r;
}
__device__ __forceinline__ float h2f(u16 h){
    _Float16 x; __builtin_memcpy(&x, &h, 2); return (float)x;
}
__device__ __forceinline__ f32x4 h2f4(u16x4 r){
    f32x4 o; o[0]=h2f(r[0]); o[1]=h2f(r[1]); o[2]=h2f(r[2]); o[3]=h2f(r[3]); return o;
}

// ---------------- fused setup: splitX (packed) | convW (packed) | edge count ----------------
__global__ void k_setup(const float* __restrict__ x, const int* __restrict__ ei,
                        const float* __restrict__ Wl1, const float* __restrict__ Wr1,
                        const float* __restrict__ Wres, const float* __restrict__ Wl2,
                        const float* __restrict__ Wr2,
                        u16* __restrict__ xhi, u16* __restrict__ xlo,
                        u16* __restrict__ hl1, u16* __restrict__ ll1,
                        u16* __restrict__ hr1, u16* __restrict__ lr1,
                        u16* __restrict__ hres, u16* __restrict__ lres,
                        u16* __restrict__ hl2, u16* __restrict__ ll2,
                        u16* __restrict__ hr2, u16* __restrict__ lr2,
                        int* __restrict__ deg){
    int gid = blockIdx.x*256 + threadIdx.x;
    if (gid < 800000){
        int row = gid >> 4;
        int k0  = (gid & 15) * 8;
        const float* ap = x + (size_t)row*128 + k0;
        float4 v0 = *(const float4*)ap;
        float4 v1 = *(const float4*)(ap + 4);
        float vv[8] = {v0.x, v0.y, v0.z, v0.w, v1.x, v1.y, v1.z, v1.w};
        u16x8 h8, l8;
        #pragma unroll
        for (int j = 0; j < 8; j++){
            u16 h = f2b(vv[j]);
            h8[j] = h;
            l8[j] = f2b(vv[j] - b2f(h));
        }
        size_t blk = (size_t)(row >> 4)*4 + (k0 >> 5);
        size_t addr = blk*512 + (size_t)((row & 15) + 16*((k0 >> 3) & 3))*8;
        *(u16x8*)(xhi + addr) = h8;
        *(u16x8*)(xlo + addr) = l8;
    } else if (gid < 906496){
        int g = gid - 800000;
        const float* src; u16* dh; u16* dl; int K, N, idx;
        if      (g <  32768){ src=Wl1;  dh=hl1;  dl=ll1;  K=128; N=256; idx=g; }
        else if (g <  65536){ src=Wr1;  dh=hr1;  dl=lr1;  K=128; N=256; idx=g-32768; }
        else if (g <  73728){ src=Wres; dh=hres; dl=lres; K=128; N=64;  idx=g-65536; }
        else if (g <  90112){ src=Wl2;  dh=hl2;  dl=ll2;  K=64;  N=256; idx=g-73728; }
        else                { src=Wr2;  dh=hr2;  dl=lr2;  K=64;  N=256; idx=g-90112; }
        int k = idx / N, n = idx - k*N;
        float v = src[idx];
        u16 h = f2b(v);
        size_t blk = (size_t)(n >> 4)*(K >> 5) + (k >> 5);
        size_t addr = blk*512 + (size_t)((n & 15) + 16*((k >> 3) & 3))*8 + (k & 7);
        dh[addr] = h;
        dl[addr] = f2b(v - b2f(h));
    } else if (gid < 1306496){
        int e = gid - 906496;
        atomicAdd(&deg[ei[EE + e]], 1);
    }
}

// ---------------- CSR build ----------------
__global__ void k_scanA(const int* __restrict__ deg, int* __restrict__ iscan, int* __restrict__ part){
    __shared__ int sh[256];
    int tid = threadIdx.x;
    int base = blockIdx.x*1024 + tid*4;
    int v[4]; int t = 0;
    #pragma unroll
    for (int i = 0; i < 4; i++){ int idx = base + i; v[i] = (idx < NN) ? deg[idx]+1 : 0; t += v[i]; }
    sh[tid] = t; __syncthreads();
    for (int off = 1; off < 256; off <<= 1){
        int u = (tid >= off) ? sh[tid - off] : 0;
        __syncthreads();
        sh[tid] += u;
        __syncthreads();
    }
    int incl = sh[tid];
    int run = incl - t;
    #pragma unroll
    for (int i = 0; i < 4; i++){
        run += v[i];
        int idx = base + i;
        if (idx < NN) iscan[idx] = run;
    }
    if (tid == 255) part[blockIdx.x] = incl;
}

__global__ void k_scanC(const int* __restrict__ iscan, const int* __restrict__ part,
                        const int* __restrict__ deg, int* __restrict__ rowptr, int* __restrict__ cursor){
    int chunk = blockIdx.x >> 2;
    int ps = 0;
    for (int j = 0; j < chunk; j++) ps += part[j];
    int i = blockIdx.x*256 + threadIdx.x;
    if (i < NN){
        int v = iscan[i] + ps;          // rowptr[i+1]
        rowptr[i+1] = v;
        cursor[i] = v - (deg[i]+1);     // rowptr[i]
    }
    if (i == 0) rowptr[0] = 0;
}

__global__ void k_fill(const int* __restrict__ ei, int* __restrict__ cursor, int* __restrict__ csr_src){
    int idx = blockIdx.x*256 + threadIdx.x;
    if (idx >= ETOT) return;
    int s, d;
    if (idx < EE){ s = ei[idx]; d = ei[EE + idx]; }
    else         { s = idx - EE; d = s; }
    int pos = atomicAdd(&cursor[d], 1);
    csr_src[pos] = s;
}

#define LSTR 80   // LDS row stride in u16 (160B)

// ---------------- layer-1 GEMM, packed operands; LDS-staged coalesced fp16 epilogue --------
__global__ __launch_bounds__(256) void k_gemm1(const u16* __restrict__ Ahi, const u16* __restrict__ Alo,
        const u16* __restrict__ Whl1, const u16* __restrict__ Wll1,
        const u16* __restrict__ Whr1, const u16* __restrict__ Wlr1,
        const u16* __restrict__ Whres,const u16* __restrict__ Wlres,
        const float* __restrict__ bl1, const float* __restrict__ br1, const float* __restrict__ bres,
        u16* __restrict__ xl, u16* __restrict__ xr, u16* __restrict__ xres)
{
    __shared__ u16 stg[4][64*LSTR];
    int b = blockIdx.x;
    int c = b & 7;
    int k = b >> 3;
    int tile = k % 9;
    int sx = c + 8*(k/9);
    if (sx >= 196) return;
    int wid = threadIdx.x >> 6, lane = threadIdx.x & 63;
    const u16 *Bh, *Bl; const float* bias; u16* Cout; int n0, N;
    if (tile < 4)      { Bh=Whl1;  Bl=Wll1;  bias=bl1;  Cout=xl;   n0=tile*64;     N=256; }
    else if (tile < 8) { Bh=Whr1;  Bl=Wlr1;  bias=br1;  Cout=xr;   n0=(tile-4)*64; N=256; }
    else               { Bh=Whres; Bl=Wlres; bias=bres; Cout=xres; n0=0;           N=64;  }
    int rm0 = (sx*4 + wid) * 64;
    int rblk0 = rm0 >> 4;
    int nblk0 = n0 >> 4;
    int lr = lane & 15;
    f32x4 acc[4][4] = {};
    #pragma unroll
    for (int ks = 0; ks < 4; ks++){
        short8v ah[4], al[4], bh[4], blo[4];
        #pragma unroll
        for (int mf = 0; mf < 4; mf++){
            size_t addr = ((size_t)(rblk0 + mf)*4 + ks)*512 + (size_t)lane*8;
            ah[mf] = *(const short8v*)(Ahi + addr);
            al[mf] = *(const short8v*)(Alo + addr);
        }
        #pragma unroll
        for (int nf = 0; nf < 4; nf++){
            size_t addr = ((size_t)(nblk0 + nf)*4 + ks)*512 + (size_t)lane*8;
            bh[nf]  = *(const short8v*)(Bh + addr);
            blo[nf] = *(const short8v*)(Bl + addr);
        }
        #pragma unroll
        for (int mf = 0; mf < 4; mf++)
            #pragma unroll
            for (int nf = 0; nf < 4; nf++){
                acc[mf][nf] = __builtin_amdgcn_mfma_f32_16x16x32_bf16(ah[mf], bh[nf],  acc[mf][nf], 0, 0, 0);
                acc[mf][nf] = __builtin_amdgcn_mfma_f32_16x16x32_bf16(al[mf], bh[nf],  acc[mf][nf], 0, 0, 0);
                acc[mf][nf] = __builtin_amdgcn_mfma_f32_16x16x32_bf16(ah[mf], blo[nf], acc[mf][nf], 0, 0, 0);
            }
    }
    int rbase = (lane >> 4) << 2;
    u16* my = &stg[wid][0];
    #pragma unroll
    for (int nf = 0; nf < 4; nf++){
        int col = nf*16 + lr;
        float bv = bias[n0 + col];
        #pragma unroll
        for (int mf = 0; mf < 4; mf++){
            #pragma unroll
            for (int r = 0; r < 4; r++){
                int row = mf*16 + rbase + r;
                my[row*LSTR + col] = f2h(acc[mf][nf][r] + bv);
            }
        }
    }
    __syncthreads();
    int rl = lane >> 3, cl = lane & 7;
    #pragma unroll
    for (int it = 0; it < 8; it++){
        int row = it*8 + rl;
        u16x8 v = *(u16x8*)&my[row*LSTR + cl*8];
        int grow = rm0 + row;
        if (grow < NN) *(u16x8*)(Cout + (size_t)grow*N + n0 + cl*8) = v;
    }
}

// ---------------- layer-2 GEMM, K=64; LDS-staged coalesced fp16 epilogue ----------------
__global__ __launch_bounds__(256) void k_gemm2(const u16* __restrict__ Ahi, const u16* __restrict__ Alo,
        const u16* __restrict__ Whl2, const u16* __restrict__ Wll2,
        const u16* __restrict__ Whr2, const u16* __restrict__ Wlr2,
        const float* __restrict__ bl2, const float* __restrict__ br2,
        u16* __restrict__ xl, u16* __restrict__ xr)
{
    __shared__ u16 stg[4][64*LSTR];
    int b = blockIdx.x;
    int c = b & 7;
    int k = b >> 3;
    int tile = k & 7;
    int sx = c + 8*(k >> 3);
    if (sx >= 196) return;
    int wid = threadIdx.x >> 6, lane = threadIdx.x & 63;
    const u16 *Bh, *Bl; const float* bias; u16* Cout;
    if (tile < 4){ Bh=Whl2; Bl=Wll2; bias=bl2; Cout=xl; }
    else         { Bh=Whr2; Bl=Wlr2; bias=br2; Cout=xr; }
    int n0 = (tile & 3)*64;
    int rm0 = (sx*4 + wid) * 64;
    int rblk0 = rm0 >> 4;
    int nblk0 = n0 >> 4;
    int lr = lane & 15;
    f32x4 acc[4][4] = {};
    #pragma unroll
    for (int ks = 0; ks < 2; ks++){
        short8v ah[4], al[4], bh[4], blo[4];
        #pragma unroll
        for (int mf = 0; mf < 4; mf++){
            size_t addr = ((size_t)(rblk0 + mf)*2 + ks)*512 + (size_t)lane*8;
            ah[mf] = *(const short8v*)(Ahi + addr);
            al[mf] = *(const short8v*)(Alo + addr);
        }
        #pragma unroll
        for (int nf = 0; nf < 4; nf++){
            size_t addr = ((size_t)(nblk0 + nf)*2 + ks)*512 + (size_t)lane*8;
            bh[nf]  = *(const short8v*)(Bh + addr);
            blo[nf] = *(const short8v*)(Bl + addr);
        }
        #pragma unroll
        for (int mf = 0; mf < 4; mf++)
            #pragma unroll
            for (int nf = 0; nf < 4; nf++){
                acc[mf][nf] = __builtin_amdgcn_mfma_f32_16x16x32_bf16(ah[mf], bh[nf],  acc[mf][nf], 0, 0, 0);
                acc[mf][nf] = __builtin_amdgcn_mfma_f32_16x16x32_bf16(al[mf], bh[nf],  acc[mf][nf], 0, 0, 0);
                acc[mf][nf] = __builtin_amdgcn_mfma_f32_16x16x32_bf16(ah[mf], blo[nf], acc[mf][nf], 0, 0, 0);
            }
    }
    int rbase = (lane >> 4) << 2;
    u16* my = &stg[wid][0];
    #pragma unroll
    for (int nf = 0; nf < 4; nf++){
        int col = nf*16 + lr;
        float bv = bias[n0 + col];
        #pragma unroll
        for (int mf = 0; mf < 4; mf++){
            #pragma unroll
            for (int r = 0; r < 4; r++){
                int row = mf*16 + rbase + r;
                my[row*LSTR + col] = f2h(acc[mf][nf][r] + bv);
            }
        }
    }
    __syncthreads();
    int rl = lane >> 3, cl = lane & 7;
    #pragma unroll
    for (int it = 0; it < 8; it++){
        int row = it*8 + rl;
        u16x8 v = *(u16x8*)&my[row*LSTR + cl*8];
        int grow = rm0 + row;
        if (grow < NN) *(u16x8*)(Cout + (size_t)grow*256 + n0 + cl*8) = v;
    }
}

// ---------------- fused GATv2 aggregation + BN stats: half-wave edge parallelism -----------
// lane = (sub, q): sub = lane>>5 selects edge of pair; q = lane&31 covers channels 8q..8q+7
__global__ __launch_bounds__(256) void k_gat(const u16* __restrict__ xl, const u16* __restrict__ xr,
                                             const int* __restrict__ csr_src, const int* __restrict__ rowptr,
                                             const float* __restrict__ att, const float* __restrict__ bias,
                                             float* __restrict__ out,
                                             float* __restrict__ part_s, float* __restrict__ part_q)
{
    __shared__ float ls[4][64];
    __shared__ float lq[4][64];
    int wave = threadIdx.x >> 6, lane = threadIdx.x & 63;
    int node = blockIdx.x*4 + wave;
    int p0 = rowptr[node], p1 = rowptr[node+1];
    int sub = lane >> 5;
    int q   = lane & 31;
    h16x8 xrh = *(const h16x8*)(xr + (size_t)node*HC + 8*q);
    f32x4 a0 = *(const f32x4*)(att + 8*q);
    f32x4 a1 = *(const f32x4*)(att + 8*q + 4);
    h16x2 aa0, aa1, aa2, aa3;
    aa0[0]=(_Float16)a0[0]; aa0[1]=(_Float16)a0[1];
    aa1[0]=(_Float16)a0[2]; aa1[1]=(_Float16)a0[3];
    aa2[0]=(_Float16)a1[0]; aa2[1]=(_Float16)a1[1];
    aa3[0]=(_Float16)a1[2]; aa3[1]=(_Float16)a1[3];
    float s = 0.f;
    f32x8 acc = {0.f,0.f,0.f,0.f,0.f,0.f,0.f,0.f};
    int p = p0;
    for (; p + 4 <= p1; p += 4){
        int ia = csr_src[p + sub];
        int ib = csr_src[p + 2 + sub];
        h16x8 xa = *(const h16x8*)(xl + (size_t)ia*HC + 8*q);
        h16x8 xb = *(const h16x8*)(xl + (size_t)ib*HC + 8*q);
        h16x8 ea = xa + xrh, eb = xb + xrh;
        h16x8 la = __builtin_elementwise_max(ea, ea * (_Float16)0.2f);
        h16x8 lb = __builtin_elementwise_max(eb, eb * (_Float16)0.2f);
        float ta = __builtin_amdgcn_fdot2(__builtin_shufflevector(la,la,0,1), aa0, 0.f, false);
        float tb = __builtin_amdgcn_fdot2(__builtin_shufflevector(lb,lb,0,1), aa0, 0.f, false);
        ta = __builtin_amdgcn_fdot2(__builtin_shufflevector(la,la,2,3), aa1, ta, false);
        tb = __builtin_amdgcn_fdot2(__builtin_shufflevector(lb,lb,2,3), aa1, tb, false);
        ta = __builtin_amdgcn_fdot2(__builtin_shufflevector(la,la,4,5), aa2, ta, false);
        tb = __builtin_amdgcn_fdot2(__builtin_shufflevector(lb,lb,4,5), aa2, tb, false);
        ta = __builtin_amdgcn_fdot2(__builtin_shufflevector(la,la,6,7), aa3, ta, false);
        tb = __builtin_amdgcn_fdot2(__builtin_shufflevector(lb,lb,6,7), aa3, tb, false);
        #pragma unroll
        for (int off = 1; off < 8; off <<= 1){
            ta += __shfl_xor(ta, off, 64);
            tb += __shfl_xor(tb, off, 64);
        }
        float wa = __expf(ta), wb = __expf(tb);
        s += wa + wb;
        f32x8 fa = __builtin_convertvector(xa, f32x8);
        f32x8 fb = __builtin_convertvector(xb, f32x8);
        acc = acc + fa*wa + fb*wb;
    }
    for (; p < p1; p += 2){
        int idx = p + sub;
        bool ok = idx < p1;
        int ia = csr_src[ok ? idx : p];
        h16x8 xa = *(const h16x8*)(xl + (size_t)ia*HC + 8*q);
        h16x8 ea = xa + xrh;
        h16x8 la = __builtin_elementwise_max(ea, ea * (_Float16)0.2f);
        float ta = __builtin_amdgcn_fdot2(__builtin_shufflevector(la,la,0,1), aa0, 0.f, false);
        ta = __builtin_amdgcn_fdot2(__builtin_shufflevector(la,la,2,3), aa1, ta, false);
        ta = __builtin_amdgcn_fdot2(__builtin_shufflevector(la,la,4,5), aa2, ta, false);
        ta = __builtin_amdgcn_fdot2(__builtin_shufflevector(la,la,6,7), aa3, ta, false);
        #pragma unroll
        for (int off = 1; off < 8; off <<= 1) ta += __shfl_xor(ta, off, 64);
        float wa = ok ? __expf(ta) : 0.f;
        s += wa;
        acc = acc + __builtin_convertvector(xa, f32x8)*wa;
    }
    // merge the two half-waves
    s += __shfl_xor(s, 32, 64);
    #pragma unroll
    for (int j = 0; j < 8; j++) acc[j] += __shfl_xor(acc[j], 32, 64);
    float inv = 1.f / s;
    f32x8 o = acc * inv;
    // head mean: heads live at q-offsets 8 and 16
    #pragma unroll
    for (int j = 0; j < 8; j++){ o[j] += __shfl_xor(o[j], 8, 64); o[j] += __shfl_xor(o[j], 16, 64); }
    if (lane < 8){
        float bb[8];
        #pragma unroll
        for (int j = 0; j < 8; j++) bb[j] = o[j]*0.25f + bias[8*lane + j];
        *(float4*)(out + (size_t)node*CC + 8*lane)     = make_float4(bb[0],bb[1],bb[2],bb[3]);
        *(float4*)(out + (size_t)node*CC + 8*lane + 4) = make_float4(bb[4],bb[5],bb[6],bb[7]);
        #pragma unroll
        for (int j = 0; j < 8; j++){
            ls[wave][8*lane + j] = bb[j];
            lq[wave][8*lane + j] = bb[j]*bb[j];
        }
    }
    __syncthreads();
    int tid = threadIdx.x;
    if (tid < 128){
        int c = tid & 63;
        if (tid < 64){
            float v = (ls[0][c] + ls[1][c]) + (ls[2][c] + ls[3][c]);
            atomicAdd(&part_s[(blockIdx.x & 63)*64 + c], v);
        } else {
            float v = (lq[0][c] + lq[1][c]) + (lq[2][c] + lq[3][c]);
            atomicAdd(&part_q[(blockIdx.x & 63)*64 + c], v);
        }
    }
}

// h = relu(bn(hraw) + xres); inline stat reduce; writes fp16 h-residual + packed bf16 hi/lo
__global__ __launch_bounds__(256) void k_post1(const float* __restrict__ hraw, const u16* __restrict__ xres,
                        const float* __restrict__ part_s, const float* __restrict__ part_q,
                        const float* __restrict__ g, const float* __restrict__ b,
                        u16* __restrict__ h16, u16* __restrict__ hhi, u16* __restrict__ hlo){
    __shared__ float red[128];
    int tid = threadIdx.x;
    if (tid < 128){
        const float* base = (tid < 64) ? part_s : part_q;
        int c = tid & 63;
        float sv = 0.f;
        for (int bb = 0; bb < 64; bb++) sv += base[bb*64 + c];
        red[tid] = sv;
    }
    __syncthreads();
    int i = blockIdx.x*256 + tid;   // float4 index
    if (i >= NN*16) return;
    float4 hv = ((const float4*)hraw)[i];
    f32x4 rp = h2f4(*(const u16x4*)(xres + (size_t)i*4));
    int row = i >> 4;
    int c0 = (i & 15) * 4;
    float hp[4] = {hv.x, hv.y, hv.z, hv.w};
    u16x4 h4, l4, hh4;
    const float invN = 1.f / (float)NN;
    #pragma unroll
    for (int k = 0; k < 4; k++){
        int c = c0 + k;
        float mean = red[c] * invN;
        float var  = red[64 + c] * invN - mean*mean;
        float rstd = rsqrtf(var + 1e-5f);
        float v = g[c]*(hp[k] - mean)*rstd + b[c] + rp[k];
        v = (v > 0.f) ? v : 0.f;
        hh4[k] = f2h(v);
        u16 h = f2b(v);
        h4[k] = h;
        l4[k] = f2b(v - b2f(h));
    }
    *(u16x4*)(h16 + (size_t)i*4) = hh4;
    size_t blk = (size_t)(row >> 4)*2 + (c0 >> 5);
    size_t addr = blk*512 + (size_t)((row & 15) + 16*((c0 >> 3) & 3))*8 + (c0 & 7);
    *(u16x4*)(hhi + addr) = h4;
    *(u16x4*)(hlo + addr) = l4;
}

// z = bn(h2raw) + h, fp16; inline stat reduce
__global__ __launch_bounds__(256) void k_post2(const float* __restrict__ hraw, const u16* __restrict__ h16,
                        const float* __restrict__ part_s, const float* __restrict__ part_q,
                        const float* __restrict__ g, const float* __restrict__ b,
                        u16* __restrict__ zout){
    __shared__ float red[128];
    int tid = threadIdx.x;
    if (tid < 128){
        const float* base = (tid < 64) ? part_s : part_q;
        int c = tid & 63;
        float sv = 0.f;
        for (int bb = 0; bb < 64; bb++) sv += base[bb*64 + c];
        red[tid] = sv;
    }
    __syncthreads();
    int i = blockIdx.x*256 + tid;
    if (i >= NN*16) return;
    float4 hv = ((const float4*)hraw)[i];
    f32x4 rp = h2f4(*(const u16x4*)(h16 + (size_t)i*4));
    int c0 = (i & 15) * 4;
    float hp[4] = {hv.x, hv.y, hv.z, hv.w};
    u16x4 res;
    const float invN = 1.f / (float)NN;
    #pragma unroll
    for (int k = 0; k < 4; k++){
        int c = c0 + k;
        float mean = red[c] * invN;
        float var  = red[64 + c] * invN - mean*mean;
        float rstd = rsqrtf(var + 1e-5f);
        res[k] = f2h(g[c]*(hp[k] - mean)*rstd + b[c] + rp[k]);
    }
    *(u16x4*)(zout + (size_t)i*4) = res;
}

// ---------------- link-prediction scores (fp16 z gather) ----------------
__global__ __launch_bounds__(256) void k_score(const u16* __restrict__ z, const int* __restrict__ eli,
                                               float* __restrict__ out){
    int t = blockIdx.x*256 + threadIdx.x;
    int i = t >> 4; int j = t & 15;
    if (i >= ELI_N) return;
    int a = eli[i], b = eli[ELI_N + i];
    f32x4 va = h2f4(*(const u16x4*)(z + (size_t)a*64 + j*4));
    f32x4 vb = h2f4(*(const u16x4*)(z + (size_t)b*64 + j*4));
    float s = va[0]*vb[0] + va[1]*vb[1] + va[2]*vb[2] + va[3]*vb[3];
    #pragma unroll
    for (int off = 8; off > 0; off >>= 1) s += __shfl_xor(s, off, 64);
    if (j == 0) out[i] = 1.f / (1.f + __expf(-s));
}

extern "C" void kernel_launch(void* const* d_in, const int* in_sizes, int n_in,
                              void* d_out, int out_size, void* d_ws, size_t ws_size,
                              hipStream_t stream) {
    const float* x    = (const float*)d_in[0];
    const int*   ei   = (const int*)  d_in[1];
    const int*   eli  = (const int*)  d_in[2];
    const float* Wl1  = (const float*)d_in[3];
    const float* bl1  = (const float*)d_in[4];
    const float* Wr1  = (const float*)d_in[5];
    const float* br1  = (const float*)d_in[6];
    const float* att1 = (const float*)d_in[7];
    const float* bias1= (const float*)d_in[8];
    const float* g1   = (const float*)d_in[9];
    const float* b1   = (const float*)d_in[10];
    const float* Wres = (const float*)d_in[11];
    const float* bres = (const float*)d_in[12];
    const float* Wl2  = (const float*)d_in[13];
    const float* bl2  = (const float*)d_in[14];
    const float* Wr2  = (const float*)d_in[15];
    const float* br2  = (const float*)d_in[16];
    const float* att2 = (const float*)d_in[17];
    const float* bias2= (const float*)d_in[18];
    const float* g2   = (const float*)d_in[19];
    const float* b2   = (const float*)d_in[20];
    float* out = (float*)d_out;

    char* w = (char*)d_ws;
    size_t o = 0;
    auto take = [&](size_t bytes)->char*{ char* p = w + o; o += (bytes + 255) & ~(size_t)255; return p; };
    u16*  xl   = (u16*) take((size_t)NN*HC*2);     // fp16 gather tables
    u16*  xr   = (u16*) take((size_t)NN*HC*2);
    u16*  xres = (u16*) take((size_t)NN*CC*2);     // fp16 residual
    float* hraw = (float*)take((size_t)NN*CC*4);
    u16*  h16  = (u16*) take((size_t)NN*CC*2);     // fp16 h residual
    u16*  z16  = (u16*) take((size_t)NN*CC*2);     // fp16 z for score
    u16*  xhi  = (u16*)take((size_t)MPAD*INC*2);   // packed fragment layout
    u16*  xlo  = (u16*)take((size_t)MPAD*INC*2);
    u16*  hhi  = (u16*)take((size_t)MPAD*CC*2);
    u16*  hlo  = (u16*)take((size_t)MPAD*CC*2);
    u16* whl1 = (u16*)take(256*128*2);  u16* wll1 = (u16*)take(256*128*2);
    u16* whr1 = (u16*)take(256*128*2);  u16* wlr1 = (u16*)take(256*128*2);
    u16* whres= (u16*)take(64*128*2);   u16* wlres= (u16*)take(64*128*2);
    u16* whl2 = (u16*)take(256*64*2);   u16* wll2 = (u16*)take(256*64*2);
    u16* whr2 = (u16*)take(256*64*2);   u16* wlr2 = (u16*)take(256*64*2);
    // zeroed region: 4 partial-stat buffers (64x64 each) + deg
    char* zreg  = take(4*64*64*4 + (size_t)NN*4);
    float* ps1  = (float*)zreg;
    float* pq1  = ps1 + 4096;
    float* ps2  = ps1 + 8192;
    float* pq2  = ps1 + 12288;
    int* deg    = (int*)(zreg + 4*64*64*4);
    int* rowptr = (int*)take((size_t)(NN+1)*4);
    int* iscan  = (int*)take((size_t)NN*4);
    int* cursor = (int*)take((size_t)NN*4);
    int* csr_src= (int*)take((size_t)ETOT*4);
    int* part   = (int*)take(64*4);

    hipMemsetAsync(zreg, 0, 4*64*64*4 + (size_t)NN*4, stream);

    // fused setup: x split (packed) | weight conv (packed) | degree count
    k_setup<<<5104, 256, 0, stream>>>(x, ei, Wl1, Wr1, Wres, Wl2, Wr2,
                                      xhi, xlo,
                                      whl1, wll1, whr1, wlr1, whres, wlres,
                                      whl2, wll2, whr2, wlr2, deg);

    // CSR build
    k_scanA<<<49, 256, 0, stream>>>(deg, iscan, part);
    k_scanC<<<196, 256, 0, stream>>>(iscan, part, deg, rowptr, cursor);
    k_fill<<<(ETOT+255)/256, 256, 0, stream>>>(ei, cursor, csr_src);

    // layer 1
    k_gemm1<<<1800, 256, 0, stream>>>(xhi, xlo, whl1, wll1, whr1, wlr1, whres, wlres,
                                      bl1, br1, bres, xl, xr, xres);
    k_gat<<<NN/4, 256, 0, stream>>>(xl, xr, csr_src, rowptr, att1, bias1, hraw, ps1, pq1);
    k_post1<<<(NN*16+255)/256, 256, 0, stream>>>(hraw, xres, ps1, pq1, g1, b1, h16, hhi, hlo);

    // layer 2
    k_gemm2<<<1600, 256, 0, stream>>>(hhi, hlo, whl2, wll2, whr2, wlr2, bl2, br2, xl, xr);
    k_gat<<<NN/4, 256, 0, stream>>>(xl, xr, csr_src, rowptr, att2, bias2, hraw, ps2, pq2);
    k_post2<<<(NN*16+255)/256, 256, 0, stream>>>(hraw, h16, ps2, pq2, g2, b2, z16);

    // scores
    k_score<<<(ELI_N*16+255)/256, 256, 0, stream>>>(z16, eli, out);
}

// Round 18
// 233.351 us; speedup vs baseline: 1.9004x; 1.0000x over previous
//
#include <hip/hip_runtime.h>
#include <math.h>

#define NN 50000
#define EE 400000
#define ETOT 450000
#define INC 128
#define CC 64
#define HC 256
#define ELI_N 200000
#define MPAD 50176   // 196*256; 3136 row-blocks of 16

typedef unsigned short u16;
typedef __attribute__((ext_vector_type(8))) short short8v;
typedef __attribute__((ext_vector_type(8))) unsigned short u16x8;
typedef __attribute__((ext_vector_type(4))) float f32x4;
typedef __attribute__((ext_vector_type(8))) float f32x8;
typedef __attribute__((ext_vector_type(4))) unsigned short u16x4;
typedef __attribute__((ext_vector_type(4))) _Float16 h16x4;
typedef __attribute__((ext_vector_type(2))) _Float16 h16x2;
typedef __attribute__((ext_vector_type(8))) _Float16 h16x8;

__device__ __forceinline__ u16 f2b(float v){
    unsigned u = __float_as_uint(v);
    u = (u + 0x7fffu + ((u >> 16) & 1u)) >> 16;   // RNE
    return (u16)u;
}
__device__ __forceinline__ float b2f(u16 h){
    return __uint_as_float(((unsigned)h) << 16);
}
__device__ __forceinline__ u16 f2h(float v){
    _Float16 h = (_Float16)v; u16 r; __builtin_memcpy(&r, &h, 2); return r;
}
__device__ __forceinline__ float h2f(u16 h){
    _Float16 x; __builtin_memcpy(&x, &h, 2); return (float)x;
}
__device__ __forceinline__ f32x4 h2f4(u16x4 r){
    f32x4 o; o[0]=h2f(r[0]); o[1]=h2f(r[1]); o[2]=h2f(r[2]); o[3]=h2f(r[3]); return o;
}

// ---------------- fused setup: splitX (packed) | convW (packed) | edge count ----------------
__global__ void k_setup(const float* __restrict__ x, const int* __restrict__ ei,
                        const float* __restrict__ Wl1, const float* __restrict__ Wr1,
                        const float* __restrict__ Wres, const float* __restrict__ Wl2,
                        const float* __restrict__ Wr2,
                        u16* __restrict__ xhi, u16* __restrict__ xlo,
                        u16* __restrict__ hl1, u16* __restrict__ ll1,
                        u16* __restrict__ hr1, u16* __restrict__ lr1,
                        u16* __restrict__ hres, u16* __restrict__ lres,
                        u16* __restrict__ hl2, u16* __restrict__ ll2,
                        u16* __restrict__ hr2, u16* __restrict__ lr2,
                        int* __restrict__ deg){
    int gid = blockIdx.x*256 + threadIdx.x;
    if (gid < 800000){
        int row = gid >> 4;
        int k0  = (gid & 15) * 8;
        const float* ap = x + (size_t)row*128 + k0;
        float4 v0 = *(const float4*)ap;
        float4 v1 = *(const float4*)(ap + 4);
        float vv[8] = {v0.x, v0.y, v0.z, v0.w, v1.x, v1.y, v1.z, v1.w};
        u16x8 h8, l8;
        #pragma unroll
        for (int j = 0; j < 8; j++){
            u16 h = f2b(vv[j]);
            h8[j] = h;
            l8[j] = f2b(vv[j] - b2f(h));
        }
        size_t blk = (size_t)(row >> 4)*4 + (k0 >> 5);
        size_t addr = blk*512 + (size_t)((row & 15) + 16*((k0 >> 3) & 3))*8;
        *(u16x8*)(xhi + addr) = h8;
        *(u16x8*)(xlo + addr) = l8;
    } else if (gid < 906496){
        int g = gid - 800000;
        const float* src; u16* dh; u16* dl; int K, N, idx;
        if      (g <  32768){ src=Wl1;  dh=hl1;  dl=ll1;  K=128; N=256; idx=g; }
        else if (g <  65536){ src=Wr1;  dh=hr1;  dl=lr1;  K=128; N=256; idx=g-32768; }
        else if (g <  73728){ src=Wres; dh=hres; dl=lres; K=128; N=64;  idx=g-65536; }
        else if (g <  90112){ src=Wl2;  dh=hl2;  dl=ll2;  K=64;  N=256; idx=g-73728; }
        else                { src=Wr2;  dh=hr2;  dl=lr2;  K=64;  N=256; idx=g-90112; }
        int k = idx / N, n = idx - k*N;
        float v = src[idx];
        u16 h = f2b(v);
        size_t blk = (size_t)(n >> 4)*(K >> 5) + (k >> 5);
        size_t addr = blk*512 + (size_t)((n & 15) + 16*((k >> 3) & 3))*8 + (k & 7);
        dh[addr] = h;
        dl[addr] = f2b(v - b2f(h));
    } else if (gid < 1306496){
        int e = gid - 906496;
        atomicAdd(&deg[ei[EE + e]], 1);
    }
}

// ---------------- CSR build ----------------
__global__ void k_scanA(const int* __restrict__ deg, int* __restrict__ iscan, int* __restrict__ part){
    __shared__ int sh[256];
    int tid = threadIdx.x;
    int base = blockIdx.x*1024 + tid*4;
    int v[4]; int t = 0;
    #pragma unroll
    for (int i = 0; i < 4; i++){ int idx = base + i; v[i] = (idx < NN) ? deg[idx]+1 : 0; t += v[i]; }
    sh[tid] = t; __syncthreads();
    for (int off = 1; off < 256; off <<= 1){
        int u = (tid >= off) ? sh[tid - off] : 0;
        __syncthreads();
        sh[tid] += u;
        __syncthreads();
    }
    int incl = sh[tid];
    int run = incl - t;
    #pragma unroll
    for (int i = 0; i < 4; i++){
        run += v[i];
        int idx = base + i;
        if (idx < NN) iscan[idx] = run;
    }
    if (tid == 255) part[blockIdx.x] = incl;
}

__global__ void k_scanC(const int* __restrict__ iscan, const int* __restrict__ part,
                        const int* __restrict__ deg, int* __restrict__ rowptr, int* __restrict__ cursor){
    int chunk = blockIdx.x >> 2;
    int ps = 0;
    for (int j = 0; j < chunk; j++) ps += part[j];
    int i = blockIdx.x*256 + threadIdx.x;
    if (i < NN){
        int v = iscan[i] + ps;          // rowptr[i+1]
        rowptr[i+1] = v;
        cursor[i] = v - (deg[i]+1);     // rowptr[i]
    }
    if (i == 0) rowptr[0] = 0;
}

__global__ void k_fill(const int* __restrict__ ei, int* __restrict__ cursor, int* __restrict__ csr_src){
    int idx = blockIdx.x*256 + threadIdx.x;
    if (idx >= ETOT) return;
    int s, d;
    if (idx < EE){ s = ei[idx]; d = ei[EE + idx]; }
    else         { s = idx - EE; d = s; }
    int pos = atomicAdd(&cursor[d], 1);
    csr_src[pos] = s;
}

#define LSTR 80   // LDS row stride in u16 (160B)

// ---------------- layer-1 GEMM, packed operands; LDS-staged coalesced fp16 epilogue --------
__global__ __launch_bounds__(256) void k_gemm1(const u16* __restrict__ Ahi, const u16* __restrict__ Alo,
        const u16* __restrict__ Whl1, const u16* __restrict__ Wll1,
        const u16* __restrict__ Whr1, const u16* __restrict__ Wlr1,
        const u16* __restrict__ Whres,const u16* __restrict__ Wlres,
        const float* __restrict__ bl1, const float* __restrict__ br1, const float* __restrict__ bres,
        u16* __restrict__ xl, u16* __restrict__ xr, u16* __restrict__ xres)
{
    __shared__ u16 stg[4][64*LSTR];
    int b = blockIdx.x;
    int c = b & 7;
    int k = b >> 3;
    int tile = k % 9;
    int sx = c + 8*(k/9);
    if (sx >= 196) return;
    int wid = threadIdx.x >> 6, lane = threadIdx.x & 63;
    const u16 *Bh, *Bl; const float* bias; u16* Cout; int n0, N;
    if (tile < 4)      { Bh=Whl1;  Bl=Wll1;  bias=bl1;  Cout=xl;   n0=tile*64;     N=256; }
    else if (tile < 8) { Bh=Whr1;  Bl=Wlr1;  bias=br1;  Cout=xr;   n0=(tile-4)*64; N=256; }
    else               { Bh=Whres; Bl=Wlres; bias=bres; Cout=xres; n0=0;           N=64;  }
    int rm0 = (sx*4 + wid) * 64;
    int rblk0 = rm0 >> 4;
    int nblk0 = n0 >> 4;
    int lr = lane & 15;
    f32x4 acc[4][4] = {};
    #pragma unroll
    for (int ks = 0; ks < 4; ks++){
        short8v ah[4], al[4], bh[4], blo[4];
        #pragma unroll
        for (int mf = 0; mf < 4; mf++){
            size_t addr = ((size_t)(rblk0 + mf)*4 + ks)*512 + (size_t)lane*8;
            ah[mf] = *(const short8v*)(Ahi + addr);
            al[mf] = *(const short8v*)(Alo + addr);
        }
        #pragma unroll
        for (int nf = 0; nf < 4; nf++){
            size_t addr = ((size_t)(nblk0 + nf)*4 + ks)*512 + (size_t)lane*8;
            bh[nf]  = *(const short8v*)(Bh + addr);
            blo[nf] = *(const short8v*)(Bl + addr);
        }
        #pragma unroll
        for (int mf = 0; mf < 4; mf++)
            #pragma unroll
            for (int nf = 0; nf < 4; nf++){
                acc[mf][nf] = __builtin_amdgcn_mfma_f32_16x16x32_bf16(ah[mf], bh[nf],  acc[mf][nf], 0, 0, 0);
                acc[mf][nf] = __builtin_amdgcn_mfma_f32_16x16x32_bf16(al[mf], bh[nf],  acc[mf][nf], 0, 0, 0);
                acc[mf][nf] = __builtin_amdgcn_mfma_f32_16x16x32_bf16(ah[mf], blo[nf], acc[mf][nf], 0, 0, 0);
            }
    }
    int rbase = (lane >> 4) << 2;
    u16* my = &stg[wid][0];
    #pragma unroll
    for (int nf = 0; nf < 4; nf++){
        int col = nf*16 + lr;
        float bv = bias[n0 + col];
        #pragma unroll
        for (int mf = 0; mf < 4; mf++){
            #pragma unroll
            for (int r = 0; r < 4; r++){
                int row = mf*16 + rbase + r;
                my[row*LSTR + col] = f2h(acc[mf][nf][r] + bv);
            }
        }
    }
    __syncthreads();
    int rl = lane >> 3, cl = lane & 7;
    #pragma unroll
    for (int it = 0; it < 8; it++){
        int row = it*8 + rl;
        u16x8 v = *(u16x8*)&my[row*LSTR + cl*8];
        int grow = rm0 + row;
        if (grow < NN) *(u16x8*)(Cout + (size_t)grow*N + n0 + cl*8) = v;
    }
}

// ---------------- layer-2 GEMM, K=64; LDS-staged coalesced fp16 epilogue ----------------
__global__ __launch_bounds__(256) void k_gemm2(const u16* __restrict__ Ahi, const u16* __restrict__ Alo,
        const u16* __restrict__ Whl2, const u16* __restrict__ Wll2,
        const u16* __restrict__ Whr2, const u16* __restrict__ Wlr2,
        const float* __restrict__ bl2, const float* __restrict__ br2,
        u16* __restrict__ xl, u16* __restrict__ xr)
{
    __shared__ u16 stg[4][64*LSTR];
    int b = blockIdx.x;
    int c = b & 7;
    int k = b >> 3;
    int tile = k & 7;
    int sx = c + 8*(k >> 3);
    if (sx >= 196) return;
    int wid = threadIdx.x >> 6, lane = threadIdx.x & 63;
    const u16 *Bh, *Bl; const float* bias; u16* Cout;
    if (tile < 4){ Bh=Whl2; Bl=Wll2; bias=bl2; Cout=xl; }
    else         { Bh=Whr2; Bl=Wlr2; bias=br2; Cout=xr; }
    int n0 = (tile & 3)*64;
    int rm0 = (sx*4 + wid) * 64;
    int rblk0 = rm0 >> 4;
    int nblk0 = n0 >> 4;
    int lr = lane & 15;
    f32x4 acc[4][4] = {};
    #pragma unroll
    for (int ks = 0; ks < 2; ks++){
        short8v ah[4], al[4], bh[4], blo[4];
        #pragma unroll
        for (int mf = 0; mf < 4; mf++){
            size_t addr = ((size_t)(rblk0 + mf)*2 + ks)*512 + (size_t)lane*8;
            ah[mf] = *(const short8v*)(Ahi + addr);
            al[mf] = *(const short8v*)(Alo + addr);
        }
        #pragma unroll
        for (int nf = 0; nf < 4; nf++){
            size_t addr = ((size_t)(nblk0 + nf)*2 + ks)*512 + (size_t)lane*8;
            bh[nf]  = *(const short8v*)(Bh + addr);
            blo[nf] = *(const short8v*)(Bl + addr);
        }
        #pragma unroll
        for (int mf = 0; mf < 4; mf++)
            #pragma unroll
            for (int nf = 0; nf < 4; nf++){
                acc[mf][nf] = __builtin_amdgcn_mfma_f32_16x16x32_bf16(ah[mf], bh[nf],  acc[mf][nf], 0, 0, 0);
                acc[mf][nf] = __builtin_amdgcn_mfma_f32_16x16x32_bf16(al[mf], bh[nf],  acc[mf][nf], 0, 0, 0);
                acc[mf][nf] = __builtin_amdgcn_mfma_f32_16x16x32_bf16(ah[mf], blo[nf], acc[mf][nf], 0, 0, 0);
            }
    }
    int rbase = (lane >> 4) << 2;
    u16* my = &stg[wid][0];
    #pragma unroll
    for (int nf = 0; nf < 4; nf++){
        int col = nf*16 + lr;
        float bv = bias[n0 + col];
        #pragma unroll
        for (int mf = 0; mf < 4; mf++){
            #pragma unroll
            for (int r = 0; r < 4; r++){
                int row = mf*16 + rbase + r;
                my[row*LSTR + col] = f2h(acc[mf][nf][r] + bv);
            }
        }
    }
    __syncthreads();
    int rl = lane >> 3, cl = lane & 7;
    #pragma unroll
    for (int it = 0; it < 8; it++){
        int row = it*8 + rl;
        u16x8 v = *(u16x8*)&my[row*LSTR + cl*8];
        int grow = rm0 + row;
        if (grow < NN) *(u16x8*)(Cout + (size_t)grow*256 + n0 + cl*8) = v;
    }
}

// ---------------- fused GATv2 aggregation + BN stats: half-wave edge parallelism -----------
// lane = (sub, q): sub = lane>>5 selects edge of pair; q = lane&31 covers channels 8q..8q+7
__global__ __launch_bounds__(256) void k_gat(const u16* __restrict__ xl, const u16* __restrict__ xr,
                                             const int* __restrict__ csr_src, const int* __restrict__ rowptr,
                                             const float* __restrict__ att, const float* __restrict__ bias,
                                             float* __restrict__ out,
                                             float* __restrict__ part_s, float* __restrict__ part_q)
{
    __shared__ float ls[4][64];
    __shared__ float lq[4][64];
    int wave = threadIdx.x >> 6, lane = threadIdx.x & 63;
    int node = blockIdx.x*4 + wave;
    int p0 = rowptr[node], p1 = rowptr[node+1];
    int sub = lane >> 5;
    int q   = lane & 31;
    h16x8 xrh = *(const h16x8*)(xr + (size_t)node*HC + 8*q);
    f32x4 a0 = *(const f32x4*)(att + 8*q);
    f32x4 a1 = *(const f32x4*)(att + 8*q + 4);
    h16x2 aa0, aa1, aa2, aa3;
    aa0[0]=(_Float16)a0[0]; aa0[1]=(_Float16)a0[1];
    aa1[0]=(_Float16)a0[2]; aa1[1]=(_Float16)a0[3];
    aa2[0]=(_Float16)a1[0]; aa2[1]=(_Float16)a1[1];
    aa3[0]=(_Float16)a1[2]; aa3[1]=(_Float16)a1[3];
    float s = 0.f;
    f32x8 acc = {0.f,0.f,0.f,0.f,0.f,0.f,0.f,0.f};
    int p = p0;
    for (; p + 4 <= p1; p += 4){
        int ia = csr_src[p + sub];
        int ib = csr_src[p + 2 + sub];
        h16x8 xa = *(const h16x8*)(xl + (size_t)ia*HC + 8*q);
        h16x8 xb = *(const h16x8*)(xl + (size_t)ib*HC + 8*q);
        h16x8 ea = xa + xrh, eb = xb + xrh;
        h16x8 la = __builtin_elementwise_max(ea, ea * (_Float16)0.2f);
        h16x8 lb = __builtin_elementwise_max(eb, eb * (_Float16)0.2f);
        float ta = __builtin_amdgcn_fdot2(__builtin_shufflevector(la,la,0,1), aa0, 0.f, false);
        float tb = __builtin_amdgcn_fdot2(__builtin_shufflevector(lb,lb,0,1), aa0, 0.f, false);
        ta = __builtin_amdgcn_fdot2(__builtin_shufflevector(la,la,2,3), aa1, ta, false);
        tb = __builtin_amdgcn_fdot2(__builtin_shufflevector(lb,lb,2,3), aa1, tb, false);
        ta = __builtin_amdgcn_fdot2(__builtin_shufflevector(la,la,4,5), aa2, ta, false);
        tb = __builtin_amdgcn_fdot2(__builtin_shufflevector(lb,lb,4,5), aa2, tb, false);
        ta = __builtin_amdgcn_fdot2(__builtin_shufflevector(la,la,6,7), aa3, ta, false);
        tb = __builtin_amdgcn_fdot2(__builtin_shufflevector(lb,lb,6,7), aa3, tb, false);
        #pragma unroll
        for (int off = 1; off < 8; off <<= 1){
            ta += __shfl_xor(ta, off, 64);
            tb += __shfl_xor(tb, off, 64);
        }
        float wa = __expf(ta), wb = __expf(tb);
        s += wa + wb;
        f32x8 fa = __builtin_convertvector(xa, f32x8);
        f32x8 fb = __builtin_convertvector(xb, f32x8);
        acc = acc + fa*wa + fb*wb;
    }
    for (; p < p1; p += 2){
        int idx = p + sub;
        bool ok = idx < p1;
        int ia = csr_src[ok ? idx : p];
        h16x8 xa = *(const h16x8*)(xl + (size_t)ia*HC + 8*q);
        h16x8 ea = xa + xrh;
        h16x8 la = __builtin_elementwise_max(ea, ea * (_Float16)0.2f);
        float ta = __builtin_amdgcn_fdot2(__builtin_shufflevector(la,la,0,1), aa0, 0.f, false);
        ta = __builtin_amdgcn_fdot2(__builtin_shufflevector(la,la,2,3), aa1, ta, false);
        ta = __builtin_amdgcn_fdot2(__builtin_shufflevector(la,la,4,5), aa2, ta, false);
        ta = __builtin_amdgcn_fdot2(__builtin_shufflevector(la,la,6,7), aa3, ta, false);
        #pragma unroll
        for (int off = 1; off < 8; off <<= 1) ta += __shfl_xor(ta, off, 64);
        float wa = ok ? __expf(ta) : 0.f;
        s += wa;
        acc = acc + __builtin_convertvector(xa, f32x8)*wa;
    }
    // merge the two half-waves
    s += __shfl_xor(s, 32, 64);
    #pragma unroll
    for (int j = 0; j < 8; j++) acc[j] += __shfl_xor(acc[j], 32, 64);
    float inv = 1.f / s;
    f32x8 o = acc * inv;
    // head mean: heads live at q-offsets 8 and 16
    #pragma unroll
    for (int j = 0; j < 8; j++){ o[j] += __shfl_xor(o[j], 8, 64); o[j] += __shfl_xor(o[j], 16, 64); }
    if (lane < 8){
        float bb[8];
        #pragma unroll
        for (int j = 0; j < 8; j++) bb[j] = o[j]*0.25f + bias[8*lane + j];
        *(float4*)(out + (size_t)node*CC + 8*lane)     = make_float4(bb[0],bb[1],bb[2],bb[3]);
        *(float4*)(out + (size_t)node*CC + 8*lane + 4) = make_float4(bb[4],bb[5],bb[6],bb[7]);
        #pragma unroll
        for (int j = 0; j < 8; j++){
            ls[wave][8*lane + j] = bb[j];
            lq[wave][8*lane + j] = bb[j]*bb[j];
        }
    }
    __syncthreads();
    int tid = threadIdx.x;
    if (tid < 128){
        int c = tid & 63;
        if (tid < 64){
            float v = (ls[0][c] + ls[1][c]) + (ls[2][c] + ls[3][c]);
            atomicAdd(&part_s[(blockIdx.x & 63)*64 + c], v);
        } else {
            float v = (lq[0][c] + lq[1][c]) + (lq[2][c] + lq[3][c]);
            atomicAdd(&part_q[(blockIdx.x & 63)*64 + c], v);
        }
    }
}

// h = relu(bn(hraw) + xres); inline stat reduce; writes fp16 h-residual + packed bf16 hi/lo
__global__ __launch_bounds__(256) void k_post1(const float* __restrict__ hraw, const u16* __restrict__ xres,
                        const float* __restrict__ part_s, const float* __restrict__ part_q,
                        const float* __restrict__ g, const float* __restrict__ b,
                        u16* __restrict__ h16, u16* __restrict__ hhi, u16* __restrict__ hlo){
    __shared__ float red[128];
    int tid = threadIdx.x;
    if (tid < 128){
        const float* base = (tid < 64) ? part_s : part_q;
        int c = tid & 63;
        float sv = 0.f;
        for (int bb = 0; bb < 64; bb++) sv += base[bb*64 + c];
        red[tid] = sv;
    }
    __syncthreads();
    int i = blockIdx.x*256 + tid;   // float4 index
    if (i >= NN*16) return;
    float4 hv = ((const float4*)hraw)[i];
    f32x4 rp = h2f4(*(const u16x4*)(xres + (size_t)i*4));
    int row = i >> 4;
    int c0 = (i & 15) * 4;
    float hp[4] = {hv.x, hv.y, hv.z, hv.w};
    u16x4 h4, l4, hh4;
    const float invN = 1.f / (float)NN;
    #pragma unroll
    for (int k = 0; k < 4; k++){
        int c = c0 + k;
        float mean = red[c] * invN;
        float var  = red[64 + c] * invN - mean*mean;
        float rstd = rsqrtf(var + 1e-5f);
        float v = g[c]*(hp[k] - mean)*rstd + b[c] + rp[k];
        v = (v > 0.f) ? v : 0.f;
        hh4[k] = f2h(v);
        u16 h = f2b(v);
        h4[k] = h;
        l4[k] = f2b(v - b2f(h));
    }
    *(u16x4*)(h16 + (size_t)i*4) = hh4;
    size_t blk = (size_t)(row >> 4)*2 + (c0 >> 5);
    size_t addr = blk*512 + (size_t)((row & 15) + 16*((c0 >> 3) & 3))*8 + (c0 & 7);
    *(u16x4*)(hhi + addr) = h4;
    *(u16x4*)(hlo + addr) = l4;
}

// z = bn(h2raw) + h, fp16; inline stat reduce
__global__ __launch_bounds__(256) void k_post2(const float* __restrict__ hraw, const u16* __restrict__ h16,
                        const float* __restrict__ part_s, const float* __restrict__ part_q,
                        const float* __restrict__ g, const float* __restrict__ b,
                        u16* __restrict__ zout){
    __shared__ float red[128];
    int tid = threadIdx.x;
    if (tid < 128){
        const float* base = (tid < 64) ? part_s : part_q;
        int c = tid & 63;
        float sv = 0.f;
        for (int bb = 0; bb < 64; bb++) sv += base[bb*64 + c];
        red[tid] = sv;
    }
    __syncthreads();
    int i = blockIdx.x*256 + tid;
    if (i >= NN*16) return;
    float4 hv = ((const float4*)hraw)[i];
    f32x4 rp = h2f4(*(const u16x4*)(h16 + (size_t)i*4));
    int c0 = (i & 15) * 4;
    float hp[4] = {hv.x, hv.y, hv.z, hv.w};
    u16x4 res;
    const float invN = 1.f / (float)NN;
    #pragma unroll
    for (int k = 0; k < 4; k++){
        int c = c0 + k;
        float mean = red[c] * invN;
        float var  = red[64 + c] * invN - mean*mean;
        float rstd = rsqrtf(var + 1e-5f);
        res[k] = f2h(g[c]*(hp[k] - mean)*rstd + b[c] + rp[k]);
    }
    *(u16x4*)(zout + (size_t)i*4) = res;
}

// ---------------- link-prediction scores (fp16 z gather) ----------------
__global__ __launch_bounds__(256) void k_score(const u16* __restrict__ z, const int* __restrict__ eli,
                                               float* __restrict__ out){
    int t = blockIdx.x*256 + threadIdx.x;
    int i = t >> 4; int j = t & 15;
    if (i >= ELI_N) return;
    int a = eli[i], b = eli[ELI_N + i];
    f32x4 va = h2f4(*(const u16x4*)(z + (size_t)a*64 + j*4));
    f32x4 vb = h2f4(*(const u16x4*)(z + (size_t)b*64 + j*4));
    float s = va[0]*vb[0] + va[1]*vb[1] + va[2]*vb[2] + va[3]*vb[3];
    #pragma unroll
    for (int off = 8; off > 0; off >>= 1) s += __shfl_xor(s, off, 64);
    if (j == 0) out[i] = 1.f / (1.f + __expf(-s));
}

extern "C" void kernel_launch(void* const* d_in, const int* in_sizes, int n_in,
                              void* d_out, int out_size, void* d_ws, size_t ws_size,
                              hipStream_t stream) {
    const float* x    = (const float*)d_in[0];
    const int*   ei   = (const int*)  d_in[1];
    const int*   eli  = (const int*)  d_in[2];
    const float* Wl1  = (const float*)d_in[3];
    const float* bl1  = (const float*)d_in[4];
    const float* Wr1  = (const float*)d_in[5];
    const float* br1  = (const float*)d_in[6];
    const float* att1 = (const float*)d_in[7];
    const float* bias1= (const float*)d_in[8];
    const float* g1   = (const float*)d_in[9];
    const float* b1   = (const float*)d_in[10];
    const float* Wres = (const float*)d_in[11];
    const float* bres = (const float*)d_in[12];
    const float* Wl2  = (const float*)d_in[13];
    const float* bl2  = (const float*)d_in[14];
    const float* Wr2  = (const float*)d_in[15];
    const float* br2  = (const float*)d_in[16];
    const float* att2 = (const float*)d_in[17];
    const float* bias2= (const float*)d_in[18];
    const float* g2   = (const float*)d_in[19];
    const float* b2   = (const float*)d_in[20];
    float* out = (float*)d_out;

    char* w = (char*)d_ws;
    size_t o = 0;
    auto take = [&](size_t bytes)->char*{ char* p = w + o; o += (bytes + 255) & ~(size_t)255; return p; };
    u16*  xl   = (u16*) take((size_t)NN*HC*2);     // fp16 gather tables
    u16*  xr   = (u16*) take((size_t)NN*HC*2);
    u16*  xres = (u16*) take((size_t)NN*CC*2);     // fp16 residual
    float* hraw = (float*)take((size_t)NN*CC*4);
    u16*  h16  = (u16*) take((size_t)NN*CC*2);     // fp16 h residual
    u16*  z16  = (u16*) take((size_t)NN*CC*2);     // fp16 z for score
    u16*  xhi  = (u16*)take((size_t)MPAD*INC*2);   // packed fragment layout
    u16*  xlo  = (u16*)take((size_t)MPAD*INC*2);
    u16*  hhi  = (u16*)take((size_t)MPAD*CC*2);
    u16*  hlo  = (u16*)take((size_t)MPAD*CC*2);
    u16* whl1 = (u16*)take(256*128*2);  u16* wll1 = (u16*)take(256*128*2);
    u16* whr1 = (u16*)take(256*128*2);  u16* wlr1 = (u16*)take(256*128*2);
    u16* whres= (u16*)take(64*128*2);   u16* wlres= (u16*)take(64*128*2);
    u16* whl2 = (u16*)take(256*64*2);   u16* wll2 = (u16*)take(256*64*2);
    u16* whr2 = (u16*)take(256*64*2);   u16* wlr2 = (u16*)take(256*64*2);
    // zeroed region: 4 partial-stat buffers (64x64 each) + deg
    char* zreg  = take(4*64*64*4 + (size_t)NN*4);
    float* ps1  = (float*)zreg;
    float* pq1  = ps1 + 4096;
    float* ps2  = ps1 + 8192;
    float* pq2  = ps1 + 12288;
    int* deg    = (int*)(zreg + 4*64*64*4);
    int* rowptr = (int*)take((size_t)(NN+1)*4);
    int* iscan  = (int*)take((size_t)NN*4);
    int* cursor = (int*)take((size_t)NN*4);
    int* csr_src= (int*)take((size_t)ETOT*4);
    int* part   = (int*)take(64*4);

    hipMemsetAsync(zreg, 0, 4*64*64*4 + (size_t)NN*4, stream);

    // fused setup: x split (packed) | weight conv (packed) | degree count
    k_setup<<<5104, 256, 0, stream>>>(x, ei, Wl1, Wr1, Wres, Wl2, Wr2,
                                      xhi, xlo,
                                      whl1, wll1, whr1, wlr1, whres, wlres,
                                      whl2, wll2, whr2, wlr2, deg);

    // CSR build
    k_scanA<<<49, 256, 0, stream>>>(deg, iscan, part);
    k_scanC<<<196, 256, 0, stream>>>(iscan, part, deg, rowptr, cursor);
    k_fill<<<(ETOT+255)/256, 256, 0, stream>>>(ei, cursor, csr_src);

    // layer 1
    k_gemm1<<<1800, 256, 0, stream>>>(xhi, xlo, whl1, wll1, whr1, wlr1, whres, wlres,
                                      bl1, br1, bres, xl, xr, xres);
    k_gat<<<NN/4, 256, 0, stream>>>(xl, xr, csr_src, rowptr, att1, bias1, hraw, ps1, pq1);
    k_post1<<<(NN*16+255)/256, 256, 0, stream>>>(hraw, xres, ps1, pq1, g1, b1, h16, hhi, hlo);

    // layer 2
    k_gemm2<<<1600, 256, 0, stream>>>(hhi, hlo, whl2, wll2, whr2, wlr2, bl2, br2, xl, xr);
    k_gat<<<NN/4, 256, 0, stream>>>(xl, xr, csr_src, rowptr, att2, bias2, hraw, ps2, pq2);
    k_post2<<<(NN*16+255)/256, 256, 0, stream>>>(hraw, h16, ps2, pq2, g2, b2, z16);

    // scores
    k_score<<<(ELI_N*16+255)/256, 256, 0, stream>>>(z16, eli, out);
}